// Round 1
// baseline (2305.224 us; speedup 1.0000x reference)
//
#include <hip/hip_runtime.h>

#define NBATCH 4
#define NPTS   4096
#define KNNK   32
#define C1D    128
#define CD     256

// ---------------- helpers ----------------

__device__ __forceinline__ float block_sum256(float v, float* red) {
    #pragma unroll
    for (int o = 32; o; o >>= 1) v += __shfl_down(v, o);
    __syncthreads();
    if ((threadIdx.x & 63) == 0) red[threadIdx.x >> 6] = v;
    __syncthreads();
    return red[0] + red[1] + red[2] + red[3];
}

__device__ __forceinline__ unsigned rotl32(unsigned x, unsigned r) {
    return (x << r) | (x >> (32u - r));
}

// XLA f32 erf_inv (Giles polynomial)
__device__ float erfinv_f(float x) {
    float w = -log1pf(-x * x);
    float p;
    if (w < 5.0f) {
        w -= 2.5f;
        p = 2.81022636e-08f;
        p = fmaf(p, w, 3.43273939e-07f);
        p = fmaf(p, w, -3.5233877e-06f);
        p = fmaf(p, w, -4.39150654e-06f);
        p = fmaf(p, w, 0.00021858087f);
        p = fmaf(p, w, -0.00125372503f);
        p = fmaf(p, w, -0.00417768164f);
        p = fmaf(p, w, 0.246640727f);
        p = fmaf(p, w, 1.50140941f);
    } else {
        w = sqrtf(w) - 3.0f;
        p = -0.000200214257f;
        p = fmaf(p, w, 0.000100950558f);
        p = fmaf(p, w, 0.00134934322f);
        p = fmaf(p, w, -0.00367342844f);
        p = fmaf(p, w, 0.00573950773f);
        p = fmaf(p, w, -0.0076224613f);
        p = fmaf(p, w, 0.00943887047f);
        p = fmaf(p, w, 1.00167406f);
        p = fmaf(p, w, 2.83297682f);
    }
    return p * x;
}

__device__ __forceinline__ float bits_to_normal(unsigned bits) {
    unsigned fb = (bits >> 9) | 0x3f800000u;
    float f = __uint_as_float(fb) - 1.0f;
    const float lo = -0.99999994f;           // nextafterf(-1,0)
    float u = fmaf(f, 2.0f, lo);             // f*(hi-lo)+lo, hi-lo rounds to 2.0f
    u = fmaxf(u, lo);
    return 1.41421356237f * erfinv_f(u);
}

// ---------------- kernels ----------------

// x [B,3,N] -> xyz [B,N,3], sq [B,N]
__global__ void prep_kernel(const float* __restrict__ x, float* __restrict__ xyz,
                            float* __restrict__ sq) {
    int gid = blockIdx.x * 256 + threadIdx.x;
    if (gid >= NBATCH * NPTS) return;
    int b = gid >> 12, n = gid & (NPTS - 1);
    float a0 = x[(b * 3 + 0) * NPTS + n];
    float a1 = x[(b * 3 + 1) * NPTS + n];
    float a2 = x[(b * 3 + 2) * NPTS + n];
    xyz[gid * 3 + 0] = a0; xyz[gid * 3 + 1] = a1; xyz[gid * 3 + 2] = a2;
    sq[gid] = a0 * a0 + a1 * a1 + a2 * a2;
}

// JAX threefry2x32, key(42) -> slots = mu + sigma * normal
__global__ void slots_init_kernel(const float* __restrict__ mu, const float* __restrict__ sg,
                                  float* __restrict__ slots) {
    int j = blockIdx.x * 256 + threadIdx.x;
    if (j >= 2048) return;
    unsigned ks0 = 0u, ks1 = 42u, ks2 = 0u ^ 42u ^ 0x1BD11BDAu;
    unsigned x0 = (unsigned)j + ks0;
    unsigned x1 = (unsigned)(j + 2048) + ks1;
    #define RND(r) { x0 += x1; x1 = rotl32(x1, r); x1 ^= x0; }
    RND(13u) RND(15u) RND(26u) RND(6u);  x0 += ks1; x1 += ks2 + 1u;
    RND(17u) RND(29u) RND(16u) RND(24u); x0 += ks2; x1 += ks0 + 2u;
    RND(13u) RND(15u) RND(26u) RND(6u);  x0 += ks0; x1 += ks1 + 3u;
    RND(17u) RND(29u) RND(16u) RND(24u); x0 += ks1; x1 += ks2 + 4u;
    RND(13u) RND(15u) RND(26u) RND(6u);  x0 += ks2; x1 += ks0 + 5u;
    #undef RND
    int c0 = j & 255, c1 = (j + 2048) & 255;
    slots[j]        = mu[c0] + sg[c0] * bits_to_normal(x0);
    slots[j + 2048] = mu[c1] + sg[c1] * bits_to_normal(x1);
}

// one block per point: dist to all 4096 in LDS, 32 rounds of stable argmin
__global__ __launch_bounds__(256) void knn_kernel(const float* __restrict__ xyz,
                                                  const float* __restrict__ sq,
                                                  int* __restrict__ knn_idx) {
    int pid = blockIdx.x;
    int b = pid >> 12, n = pid & (NPTS - 1);
    __shared__ float dist[NPTS];
    __shared__ float rv[4];
    __shared__ int   ri[4];
    const float* xb = xyz + (size_t)b * NPTS * 3;
    const float* sb = sq + (size_t)b * NPTS;
    float px = xb[n * 3], py = xb[n * 3 + 1], pz = xb[n * 3 + 2];
    float sn = sb[n];
    for (int m = threadIdx.x; m < NPTS; m += 256) {
        float dx = xb[m * 3], dy = xb[m * 3 + 1], dz = xb[m * 3 + 2];
        float dot = px * dx + py * dy + pz * dz;
        dist[m] = sn + sb[m] - 2.0f * dot;
    }
    __syncthreads();
    int* out = knn_idx + (size_t)pid * KNNK;
    for (int s = 0; s < KNNK; ++s) {
        float bv = 1e30f; int bi = 2147483647;
        for (int m = threadIdx.x; m < NPTS; m += 256) {
            float v = dist[m];
            if (v < bv) { bv = v; bi = m; }
        }
        #pragma unroll
        for (int o = 32; o; o >>= 1) {
            float ov = __shfl_down(bv, o); int oi = __shfl_down(bi, o);
            if (ov < bv || (ov == bv && oi < bi)) { bv = ov; bi = oi; }
        }
        int lane = threadIdx.x & 63, w = threadIdx.x >> 6;
        if (lane == 0) { rv[w] = bv; ri[w] = bi; }
        __syncthreads();
        if (threadIdx.x == 0) {
            float fv = rv[0]; int fi = ri[0];
            #pragma unroll
            for (int w2 = 1; w2 < 4; ++w2)
                if (rv[w2] < fv || (rv[w2] == fv && ri[w2] < fi)) { fv = rv[w2]; fi = ri[w2]; }
            out[s] = fi;
            dist[fi] = 1e30f;
        }
        __syncthreads();
    }
}

// conv1: feats are all-ones -> h = [1, rel]; out = relu(max_k (W1[0]+b1+rel.W1[1:4]))
__global__ __launch_bounds__(128) void conv1_kernel(const float* __restrict__ xyz,
                                                    const int* __restrict__ knn_idx,
                                                    const float* __restrict__ W1,
                                                    const float* __restrict__ b1,
                                                    float* __restrict__ f1) {
    int pid = blockIdx.x;
    int b = pid >> 12, n = pid & (NPTS - 1);
    int d = threadIdx.x;
    const float* xb = xyz + (size_t)b * NPTS * 3;
    float w0 = W1[d], wx = W1[C1D + d], wy = W1[2 * C1D + d], wz = W1[3 * C1D + d];
    float bb = b1[d];
    float px = xb[n * 3], py = xb[n * 3 + 1], pz = xb[n * 3 + 2];
    const int* idx = knn_idx + (size_t)pid * KNNK;
    float m = -1e30f;
    for (int k = 0; k < KNNK; ++k) {
        int j = idx[k];
        float rx = xb[j * 3] - px, ry = xb[j * 3 + 1] - py, rz = xb[j * 3 + 2] - pz;
        float v = w0 + bb + rx * wx + ry * wy + rz * wz;
        m = fmaxf(m, v);
    }
    f1[(size_t)pid * C1D + d] = fmaxf(m, 0.0f);
}

// conv2 + LayerNorm fused: out inp [B,N,C]
__global__ __launch_bounds__(256) void conv2ln_kernel(const float* __restrict__ xyz,
                                                      const float* __restrict__ f1,
                                                      const int* __restrict__ knn_idx,
                                                      const float* __restrict__ W2,
                                                      const float* __restrict__ b2,
                                                      const float* __restrict__ g_in,
                                                      const float* __restrict__ b_in,
                                                      float* __restrict__ inp) {
    int pid = blockIdx.x;
    int b = pid >> 12, n = pid & (NPTS - 1);
    int tid = threadIdx.x;
    __shared__ float h[131 * 36];   // h[c*36 + k]
    __shared__ float red[4];
    const int* idx = knn_idx + (size_t)pid * KNNK;
    {
        int c = tid & 127, half = tid >> 7;
        for (int kb = 0; kb < 16; ++kb) {
            int k = kb * 2 + half;
            int j = idx[k];
            h[c * 36 + k] = f1[((size_t)b * NPTS + j) * C1D + c];
        }
    }
    const float* xb = xyz + (size_t)b * NPTS * 3;
    if (tid < 96) {
        int k = tid & 31, comp = tid >> 5;
        int j = idx[k];
        h[(128 + comp) * 36 + k] = xb[j * 3 + comp] - xb[n * 3 + comp];
    }
    __syncthreads();
    int d = tid;
    float acc[32];
    #pragma unroll
    for (int k = 0; k < 32; ++k) acc[k] = 0.0f;
    for (int c = 0; c < 131; ++c) {
        float w = W2[c * CD + d];
        const float4* hp = (const float4*)&h[c * 36];
        #pragma unroll
        for (int k4 = 0; k4 < 8; ++k4) {
            float4 hv = hp[k4];
            acc[k4 * 4 + 0] += hv.x * w;
            acc[k4 * 4 + 1] += hv.y * w;
            acc[k4 * 4 + 2] += hv.z * w;
            acc[k4 * 4 + 3] += hv.w * w;
        }
    }
    float bb = b2[d];
    float m = -1e30f;
    #pragma unroll
    for (int k = 0; k < 32; ++k) m = fmaxf(m, acc[k] + bb);
    float v = fmaxf(m, 0.0f);
    float s = block_sum256(v, red);
    float mean = s * (1.0f / 256.0f);
    float s2 = block_sum256(v * v, red);
    float var = s2 * (1.0f / 256.0f) - mean * mean;
    float iv = (v - mean) * rsqrtf(var + 1e-5f) * g_in[d] + b_in[d];
    inp[(size_t)pid * CD + d] = iv;
}

// kk = inp @ Wk, vv = inp @ Wv ; 16 points per block to amortize weight reads
__global__ __launch_bounds__(256) void kv_kernel(const float* __restrict__ inp,
                                                 const float* __restrict__ Wk,
                                                 const float* __restrict__ Wv,
                                                 float* __restrict__ kk,
                                                 float* __restrict__ vv) {
    int base = blockIdx.x * 16;
    int d = threadIdx.x;
    __shared__ float t[CD * 16];    // t[c*16+p]
    for (int p = 0; p < 16; ++p) t[d * 16 + p] = inp[((size_t)base + p) * CD + d];
    __syncthreads();
    float ka[16], va[16];
    #pragma unroll
    for (int p = 0; p < 16; ++p) { ka[p] = 0.0f; va[p] = 0.0f; }
    for (int c = 0; c < CD; ++c) {
        float wk = Wk[c * CD + d], wv = Wv[c * CD + d];
        const float4* tp = (const float4*)&t[c * 16];
        #pragma unroll
        for (int q4 = 0; q4 < 4; ++q4) {
            float4 x = tp[q4];
            ka[q4 * 4 + 0] += x.x * wk; va[q4 * 4 + 0] += x.x * wv;
            ka[q4 * 4 + 1] += x.y * wk; va[q4 * 4 + 1] += x.y * wv;
            ka[q4 * 4 + 2] += x.z * wk; va[q4 * 4 + 2] += x.z * wv;
            ka[q4 * 4 + 3] += x.w * wk; va[q4 * 4 + 3] += x.w * wv;
        }
    }
    for (int p = 0; p < 16; ++p) {
        kk[((size_t)base + p) * CD + d] = ka[p];
        vv[((size_t)base + p) * CD + d] = va[p];
    }
}

// q = LN(slots) @ Wq, one block per row (b,k); block 0 zeroes attn_sum
__global__ __launch_bounds__(256) void slotq_kernel(const float* __restrict__ slots,
                                                    const float* __restrict__ g_sl,
                                                    const float* __restrict__ b_sl,
                                                    const float* __restrict__ Wq,
                                                    float* __restrict__ q,
                                                    float* __restrict__ asum) {
    int row = blockIdx.x;
    int d = threadIdx.x;
    __shared__ float sl[CD];
    __shared__ float red[4];
    float v = slots[row * CD + d];
    float s = block_sum256(v, red);
    float mean = s * (1.0f / 256.0f);
    float s2 = block_sum256(v * v, red);
    float var = s2 * (1.0f / 256.0f) - mean * mean;
    float ln = (v - mean) * rsqrtf(var + 1e-5f) * g_sl[d] + b_sl[d];
    sl[d] = ln;
    __syncthreads();
    float acc = 0.0f;
    const float4* sp = (const float4*)sl;
    for (int c4 = 0; c4 < 64; ++c4) {
        float4 x = sp[c4];
        int cb = c4 * 4;
        acc += x.x * Wq[cb * CD + d] + x.y * Wq[(cb + 1) * CD + d]
             + x.z * Wq[(cb + 2) * CD + d] + x.w * Wq[(cb + 3) * CD + d];
    }
    q[row * CD + d] = acc;
    if (row == 0 && d < 16) asum[d] = 0.0f;
}

// logits -> softmax over slots -> attn [B,4,N]; atomic per-slot sums over n
__global__ __launch_bounds__(256) void attn_kernel(const float* __restrict__ q,
                                                   const float* __restrict__ kk,
                                                   float* __restrict__ attn,
                                                   float* __restrict__ asum) {
    int b = blockIdx.x >> 4;
    int nb = blockIdx.x & 15;
    int n = nb * 256 + threadIdx.x;
    __shared__ float qs[4 * CD];
    __shared__ float redk[16];
    for (int i = threadIdx.x; i < 4 * CD; i += 256) qs[i] = q[b * 4 * CD + i];
    __syncthreads();
    const float4* kp = (const float4*)(kk + ((size_t)b * NPTS + n) * CD);
    const float4* q0 = (const float4*)(qs);
    const float4* q1 = (const float4*)(qs + CD);
    const float4* q2 = (const float4*)(qs + 2 * CD);
    const float4* q3 = (const float4*)(qs + 3 * CD);
    float a0 = 0, a1 = 0, a2 = 0, a3 = 0;
    for (int c4 = 0; c4 < 64; ++c4) {
        float4 kv = kp[c4];
        float4 x;
        x = q0[c4]; a0 += kv.x * x.x + kv.y * x.y + kv.z * x.z + kv.w * x.w;
        x = q1[c4]; a1 += kv.x * x.x + kv.y * x.y + kv.z * x.z + kv.w * x.w;
        x = q2[c4]; a2 += kv.x * x.x + kv.y * x.y + kv.z * x.z + kv.w * x.w;
        x = q3[c4]; a3 += kv.x * x.x + kv.y * x.y + kv.z * x.z + kv.w * x.w;
    }
    const float scale = 0.0625f;   // 256^-0.5
    float l0 = scale * a0, l1 = scale * a1, l2 = scale * a2, l3 = scale * a3;
    float mx = fmaxf(fmaxf(l0, l1), fmaxf(l2, l3));
    float e0 = expf(l0 - mx), e1 = expf(l1 - mx), e2 = expf(l2 - mx), e3 = expf(l3 - mx);
    float inv = 1.0f / (e0 + e1 + e2 + e3);
    e0 *= inv; e1 *= inv; e2 *= inv; e3 *= inv;
    attn[((size_t)b * 4 + 0) * NPTS + n] = e0;
    attn[((size_t)b * 4 + 1) * NPTS + n] = e1;
    attn[((size_t)b * 4 + 2) * NPTS + n] = e2;
    attn[((size_t)b * 4 + 3) * NPTS + n] = e3;
    float as[4] = {e0, e1, e2, e3};
    #pragma unroll
    for (int k = 0; k < 4; ++k) {
        float v = as[k];
        #pragma unroll
        for (int o = 32; o; o >>= 1) v += __shfl_down(v, o);
        if ((threadIdx.x & 63) == 0) redk[(threadIdx.x >> 6) * 4 + k] = v;
    }
    __syncthreads();
    if (threadIdx.x < 4) {
        float s = redk[threadIdx.x] + redk[4 + threadIdx.x] + redk[8 + threadIdx.x] + redk[12 + threadIdx.x];
        atomicAdd(&asum[b * 4 + threadIdx.x], s);
    }
}

// partial sums of attn*vv over 256-point chunks (deterministic, no atomics)
__global__ __launch_bounds__(256) void updp_kernel(const float* __restrict__ attn,
                                                   const float* __restrict__ vv,
                                                   float* __restrict__ updp) {
    int row = blockIdx.x >> 4, chunk = blockIdx.x & 15;
    int b = row >> 2;
    int d = threadIdx.x;
    const float* arow = attn + (size_t)row * NPTS + chunk * 256;
    const float* vb = vv + ((size_t)b * NPTS + chunk * 256) * CD;
    float acc = 0.0f;
    for (int n = 0; n < 256; ++n) acc += arow[n] * vb[(size_t)n * CD + d];
    updp[((size_t)row * 16 + chunk) * CD + d] = acc;
}

// GRU + LN_ff + MLP residual, one block per row (b,k), slots updated in place
__global__ __launch_bounds__(256) void gru_mlp_kernel(const float* __restrict__ updp,
                                                      const float* __restrict__ asum,
                                                      float* __restrict__ slots,
                                                      const float* __restrict__ W_ih,
                                                      const float* __restrict__ W_hh,
                                                      const float* __restrict__ b_ih,
                                                      const float* __restrict__ b_hh,
                                                      const float* __restrict__ g_ff,
                                                      const float* __restrict__ b_ff,
                                                      const float* __restrict__ Wm1,
                                                      const float* __restrict__ bm1,
                                                      const float* __restrict__ Wm2,
                                                      const float* __restrict__ bm2) {
    int row = blockIdx.x;
    int d = threadIdx.x;
    __shared__ float su[CD], sp[CD], sh[CD];
    __shared__ float red[4];
    float f = 1.0f / (asum[row] + 1e-8f);
    float u = 0.0f;
    for (int p = 0; p < 16; ++p) u += updp[((size_t)row * 16 + p) * CD + d];
    u *= f;
    float prev = slots[row * CD + d];
    su[d] = u; sp[d] = prev;
    __syncthreads();
    float gir = b_ih[d], giz = b_ih[CD + d], gin = b_ih[2 * CD + d];
    float ghr = b_hh[d], ghz = b_hh[CD + d], ghn = b_hh[2 * CD + d];
    for (int c = 0; c < CD; ++c) {
        float uc = su[c], pc = sp[c];
        const float* wi = W_ih + c * 3 * CD;
        const float* wh = W_hh + c * 3 * CD;
        gir += uc * wi[d]; giz += uc * wi[CD + d]; gin += uc * wi[2 * CD + d];
        ghr += pc * wh[d]; ghz += pc * wh[CD + d]; ghn += pc * wh[2 * CD + d];
    }
    float r = 1.0f / (1.0f + expf(-(gir + ghr)));
    float z = 1.0f / (1.0f + expf(-(giz + ghz)));
    float nn = tanhf(gin + r * ghn);
    float sNew = (1.0f - z) * nn + z * prev;
    float s = block_sum256(sNew, red);
    float mean = s * (1.0f / 256.0f);
    float s2 = block_sum256(sNew * sNew, red);
    float var = s2 * (1.0f / 256.0f) - mean * mean;
    float h = (sNew - mean) * rsqrtf(var + 1e-5f) * g_ff[d] + b_ff[d];
    __syncthreads();
    sh[d] = h;
    __syncthreads();
    float y = bm1[d];
    {
        const float4* hp = (const float4*)sh;
        for (int c4 = 0; c4 < 64; ++c4) {
            float4 x = hp[c4];
            int cb = c4 * 4;
            y += x.x * Wm1[cb * CD + d] + x.y * Wm1[(cb + 1) * CD + d]
               + x.z * Wm1[(cb + 2) * CD + d] + x.w * Wm1[(cb + 3) * CD + d];
        }
    }
    y = fmaxf(y, 0.0f);
    __syncthreads();
    sh[d] = y;
    __syncthreads();
    float o = bm2[d];
    {
        const float4* hp = (const float4*)sh;
        for (int c4 = 0; c4 < 64; ++c4) {
            float4 x = hp[c4];
            int cb = c4 * 4;
            o += x.x * Wm2[cb * CD + d] + x.y * Wm2[(cb + 1) * CD + d]
               + x.z * Wm2[(cb + 2) * CD + d] + x.w * Wm2[(cb + 3) * CD + d];
        }
    }
    slots[row * CD + d] = sNew + o;
}

// recon head: two (linear+BN+relu) + final linear -> slot_pts [B,384,3]
__global__ __launch_bounds__(320) void recon_kernel(const float* __restrict__ slots,
                                                    const float* __restrict__ Wr1, const float* __restrict__ br1,
                                                    const float* __restrict__ g1, const float* __restrict__ be1,
                                                    const float* __restrict__ Wr2, const float* __restrict__ br2,
                                                    const float* __restrict__ g2, const float* __restrict__ be2,
                                                    const float* __restrict__ Wr3, const float* __restrict__ br3,
                                                    float* __restrict__ spts) {
    __shared__ float sl[16 * CD];
    __shared__ float h1[16 * CD];
    __shared__ float h2[16 * CD];
    int d = threadIdx.x;
    if (d < CD) for (int r = 0; r < 16; ++r) sl[r * CD + d] = slots[r * CD + d];
    __syncthreads();
    if (d < CD) {
        float t[16];
        for (int r = 0; r < 16; ++r) {
            float acc = br1[d];
            const float4* sp = (const float4*)(sl + r * CD);
            for (int c4 = 0; c4 < 64; ++c4) {
                float4 x = sp[c4];
                int cb = c4 * 4;
                acc += x.x * Wr1[cb * CD + d] + x.y * Wr1[(cb + 1) * CD + d]
                     + x.z * Wr1[(cb + 2) * CD + d] + x.w * Wr1[(cb + 3) * CD + d];
            }
            t[r] = acc;
        }
        float mean = 0.0f;
        for (int r = 0; r < 16; ++r) mean += t[r];
        mean *= (1.0f / 16.0f);
        float var = 0.0f;
        for (int r = 0; r < 16; ++r) { float dd = t[r] - mean; var += dd * dd; }
        var *= (1.0f / 16.0f);
        float inv = rsqrtf(var + 1e-5f);
        for (int r = 0; r < 16; ++r)
            h1[r * CD + d] = fmaxf(0.0f, (t[r] - mean) * inv * g1[d] + be1[d]);
    }
    __syncthreads();
    if (d < CD) {
        float t[16];
        for (int r = 0; r < 16; ++r) {
            float acc = br2[d];
            const float4* sp = (const float4*)(h1 + r * CD);
            for (int c4 = 0; c4 < 64; ++c4) {
                float4 x = sp[c4];
                int cb = c4 * 4;
                acc += x.x * Wr2[cb * CD + d] + x.y * Wr2[(cb + 1) * CD + d]
                     + x.z * Wr2[(cb + 2) * CD + d] + x.w * Wr2[(cb + 3) * CD + d];
            }
            t[r] = acc;
        }
        float mean = 0.0f;
        for (int r = 0; r < 16; ++r) mean += t[r];
        mean *= (1.0f / 16.0f);
        float var = 0.0f;
        for (int r = 0; r < 16; ++r) { float dd = t[r] - mean; var += dd * dd; }
        var *= (1.0f / 16.0f);
        float inv = rsqrtf(var + 1e-5f);
        for (int r = 0; r < 16; ++r)
            h2[r * CD + d] = fmaxf(0.0f, (t[r] - mean) * inv * g2[d] + be2[d]);
    }
    __syncthreads();
    if (d < 288) {
        for (int r = 0; r < 16; ++r) {
            float acc = br3[d];
            const float4* sp = (const float4*)(h2 + r * CD);
            for (int c4 = 0; c4 < 64; ++c4) {
                float4 x = sp[c4];
                int cb = c4 * 4;
                acc += x.x * Wr3[cb * 288 + d] + x.y * Wr3[(cb + 1) * 288 + d]
                     + x.z * Wr3[(cb + 2) * 288 + d] + x.w * Wr3[(cb + 3) * 288 + d];
            }
            spts[r * 288 + d] = acc;
        }
    }
}

// farthest point sampling: one block per batch, 384 pts, 128 selections
__global__ __launch_bounds__(128) void fps_kernel(const float* __restrict__ spts,
                                                  int* __restrict__ fidx,
                                                  float* __restrict__ lacc) {
    int b = blockIdx.x;
    int t = threadIdx.x;
    const float* pts = spts + (size_t)b * 384 * 3;
    __shared__ float rv[2];
    __shared__ int ri[2];
    __shared__ int bidx;
    int* out = fidx + b * 128;
    if (t == 0) out[0] = 0;
    if (b == 0 && t == 0) lacc[0] = 0.0f;
    float x0 = pts[t * 3], y0 = pts[t * 3 + 1], z0 = pts[t * 3 + 2];
    float x1 = pts[(t + 128) * 3], y1 = pts[(t + 128) * 3 + 1], z1 = pts[(t + 128) * 3 + 2];
    float x2 = pts[(t + 256) * 3], y2 = pts[(t + 256) * 3 + 1], z2 = pts[(t + 256) * 3 + 2];
    float d0 = 1e10f, d1 = 1e10f, d2 = 1e10f;
    float lx = pts[0], ly = pts[1], lz = pts[2];
    for (int s = 1; s < 128; ++s) {
        float dx, dy, dz;
        dx = x0 - lx; dy = y0 - ly; dz = z0 - lz; d0 = fminf(d0, dx * dx + dy * dy + dz * dz);
        dx = x1 - lx; dy = y1 - ly; dz = z1 - lz; d1 = fminf(d1, dx * dx + dy * dy + dz * dz);
        dx = x2 - lx; dy = y2 - ly; dz = z2 - lz; d2 = fminf(d2, dx * dx + dy * dy + dz * dz);
        float bv = d0; int bi = t;
        if (d1 > bv) { bv = d1; bi = t + 128; }
        if (d2 > bv) { bv = d2; bi = t + 256; }
        #pragma unroll
        for (int o = 32; o; o >>= 1) {
            float ov = __shfl_down(bv, o); int oi = __shfl_down(bi, o);
            if (ov > bv || (ov == bv && oi < bi)) { bv = ov; bi = oi; }
        }
        int lane = t & 63, w = t >> 6;
        if (lane == 0) { rv[w] = bv; ri[w] = bi; }
        __syncthreads();
        if (t == 0) {
            float fv = rv[0]; int fi = ri[0];
            if (rv[1] > fv || (rv[1] == fv && ri[1] < fi)) { fv = rv[1]; fi = ri[1]; }
            out[s] = fi;
            bidx = fi;
        }
        __syncthreads();
        int ni = bidx;
        lx = pts[ni * 3]; ly = pts[ni * 3 + 1]; lz = pts[ni * 3 + 2];
    }
}

// chamfer(ds, xyz), accumulate (mean d1 + mean d2) per batch
__global__ __launch_bounds__(256) void chamfer_kernel(const float* __restrict__ spts,
                                                      const int* __restrict__ fidx,
                                                      const float* __restrict__ xyz,
                                                      float* __restrict__ lacc) {
    int b = blockIdx.x;
    int t = threadIdx.x;
    __shared__ float ds[128 * 3];
    __shared__ float red[4];
    const float* pts = spts + (size_t)b * 384 * 3;
    if (t < 128) {
        int j = fidx[b * 128 + t];
        ds[t * 3] = pts[j * 3]; ds[t * 3 + 1] = pts[j * 3 + 1]; ds[t * 3 + 2] = pts[j * 3 + 2];
    }
    __syncthreads();
    const float* xb = xyz + (size_t)b * NPTS * 3;
    float sum2 = 0.0f;
    for (int n = t; n < NPTS; n += 256) {
        float px = xb[n * 3], py = xb[n * 3 + 1], pz = xb[n * 3 + 2];
        float mn = 1e30f;
        for (int j = 0; j < 128; ++j) {
            float dx = ds[j * 3] - px, dy = ds[j * 3 + 1] - py, dz = ds[j * 3 + 2] - pz;
            mn = fminf(mn, dx * dx + dy * dy + dz * dz);
        }
        sum2 += mn;
    }
    float sum1 = 0.0f;
    if (t < 128) {
        float px = ds[t * 3], py = ds[t * 3 + 1], pz = ds[t * 3 + 2];
        float mn = 1e30f;
        for (int n = 0; n < NPTS; ++n) {
            float dx = xb[n * 3] - px, dy = xb[n * 3 + 1] - py, dz = xb[n * 3 + 2] - pz;
            mn = fminf(mn, dx * dx + dy * dy + dz * dz);
        }
        sum1 = mn;
    }
    float total = block_sum256(sum2 * (1.0f / 4096.0f) + sum1 * (1.0f / 128.0f), red);
    if (t == 0) atomicAdd(lacc, total);
}

// write loss + attn_out [B,N,K]
__global__ void finalize_kernel(const float* __restrict__ attn,
                                const float* __restrict__ lacc,
                                float* __restrict__ out) {
    int gid = blockIdx.x * 256 + threadIdx.x;
    if (gid >= NBATCH * NPTS) return;
    int b = gid >> 12, n = gid & (NPTS - 1);
    float r0 = attn[((size_t)b * 4 + 0) * NPTS + n];
    float r1 = attn[((size_t)b * 4 + 1) * NPTS + n];
    float r2 = attn[((size_t)b * 4 + 2) * NPTS + n];
    float r3 = attn[((size_t)b * 4 + 3) * NPTS + n];
    out[1 + gid * 4 + 0] = r0;
    out[1 + gid * 4 + 1] = r1;
    out[1 + gid * 4 + 2] = r2;
    out[1 + gid * 4 + 3] = r3;
    if (gid == 0) out[0] = lacc[0] * 0.25f;
}

// ---------------- launch ----------------

extern "C" void kernel_launch(void* const* d_in, const int* in_sizes, int n_in,
                              void* d_out, int out_size, void* d_ws, size_t ws_size,
                              hipStream_t stream) {
    (void)in_sizes; (void)n_in; (void)out_size; (void)ws_size;
    const float* x    = (const float*)d_in[0];
    const float* W1   = (const float*)d_in[2];
    const float* b1   = (const float*)d_in[3];
    const float* W2   = (const float*)d_in[4];
    const float* b2   = (const float*)d_in[5];
    const float* mu   = (const float*)d_in[6];
    const float* sg   = (const float*)d_in[7];
    const float* g_in = (const float*)d_in[8];
    const float* b_in = (const float*)d_in[9];
    const float* g_sl = (const float*)d_in[10];
    const float* b_sl = (const float*)d_in[11];
    const float* g_ff = (const float*)d_in[12];
    const float* b_ff = (const float*)d_in[13];
    const float* Wq   = (const float*)d_in[14];
    const float* Wk   = (const float*)d_in[15];
    const float* Wv   = (const float*)d_in[16];
    const float* W_ih = (const float*)d_in[17];
    const float* W_hh = (const float*)d_in[18];
    const float* b_ih = (const float*)d_in[19];
    const float* b_hh = (const float*)d_in[20];
    const float* Wm1  = (const float*)d_in[21];
    const float* bm1  = (const float*)d_in[22];
    const float* Wm2  = (const float*)d_in[23];
    const float* bm2  = (const float*)d_in[24];
    const float* Wr1  = (const float*)d_in[25];
    const float* br1  = (const float*)d_in[26];
    const float* g1   = (const float*)d_in[27];
    const float* be1  = (const float*)d_in[28];
    const float* Wr2  = (const float*)d_in[29];
    const float* br2  = (const float*)d_in[30];
    const float* g2   = (const float*)d_in[31];
    const float* be2  = (const float*)d_in[32];
    const float* Wr3  = (const float*)d_in[33];
    const float* br3  = (const float*)d_in[34];

    float* ws    = (float*)d_ws;
    float* xyz   = ws;                               // 49152
    float* sq    = xyz + 49152;                      // 16384
    int*   knn   = (int*)(sq + 16384);               // 524288 ints
    float* f1    = (float*)(knn + 524288);           // 2097152
    float* inp   = f1 + 2097152;                     // 4194304
    float* kkb   = inp + 4194304;                    // 4194304
    float* vvb   = kkb + 4194304;                    // 4194304
    float* slots = vvb + 4194304;                    // 4096
    float* qb    = slots + 4096;                     // 4096
    float* attn  = qb + 4096;                        // 65536
    float* asum  = attn + 65536;                     // 16
    float* updp  = asum + 16;                        // 65536
    float* spts  = updp + 65536;                     // 4608
    int*   fidx  = (int*)(spts + 4608);              // 512
    float* lacc  = (float*)(fidx + 512);             // 1

    prep_kernel<<<64, 256, 0, stream>>>(x, xyz, sq);
    slots_init_kernel<<<8, 256, 0, stream>>>(mu, sg, slots);
    knn_kernel<<<NBATCH * NPTS, 256, 0, stream>>>(xyz, sq, knn);
    conv1_kernel<<<NBATCH * NPTS, 128, 0, stream>>>(xyz, knn, W1, b1, f1);
    conv2ln_kernel<<<NBATCH * NPTS, 256, 0, stream>>>(xyz, f1, knn, W2, b2, g_in, b_in, inp);
    kv_kernel<<<NBATCH * NPTS / 16, 256, 0, stream>>>(inp, Wk, Wv, kkb, vvb);

    for (int it = 0; it < 3; ++it) {
        slotq_kernel<<<16, 256, 0, stream>>>(slots, g_sl, b_sl, Wq, qb, asum);
        attn_kernel<<<64, 256, 0, stream>>>(qb, kkb, attn, asum);
        updp_kernel<<<256, 256, 0, stream>>>(attn, vvb, updp);
        gru_mlp_kernel<<<16, 256, 0, stream>>>(updp, asum, slots, W_ih, W_hh, b_ih, b_hh,
                                               g_ff, b_ff, Wm1, bm1, Wm2, bm2);
    }

    recon_kernel<<<1, 320, 0, stream>>>(slots, Wr1, br1, g1, be1, Wr2, br2, g2, be2, Wr3, br3, spts);
    fps_kernel<<<4, 128, 0, stream>>>(spts, fidx, lacc);
    chamfer_kernel<<<4, 256, 0, stream>>>(spts, fidx, xyz, lacc);
    finalize_kernel<<<64, 256, 0, stream>>>(attn, lacc, (float*)d_out);
}

// Round 2
// 2086.060 us; speedup vs baseline: 1.1051x; 1.1051x over previous
//
#include <hip/hip_runtime.h>

#define NBATCH 4
#define NPTS   4096
#define KNNK   32
#define C1D    128
#define CD     256

// ---------------- helpers ----------------

__device__ __forceinline__ float block_sum256(float v, float* red) {
    #pragma unroll
    for (int o = 32; o; o >>= 1) v += __shfl_down(v, o);
    __syncthreads();
    if ((threadIdx.x & 63) == 0) red[threadIdx.x >> 6] = v;
    __syncthreads();
    return red[0] + red[1] + red[2] + red[3];
}

__device__ __forceinline__ unsigned rotl32(unsigned x, unsigned r) {
    return (x << r) | (x >> (32u - r));
}

// XLA f32 erf_inv (Giles polynomial)
__device__ float erfinv_f(float x) {
    float w = -log1pf(-x * x);
    float p;
    if (w < 5.0f) {
        w -= 2.5f;
        p = 2.81022636e-08f;
        p = fmaf(p, w, 3.43273939e-07f);
        p = fmaf(p, w, -3.5233877e-06f);
        p = fmaf(p, w, -4.39150654e-06f);
        p = fmaf(p, w, 0.00021858087f);
        p = fmaf(p, w, -0.00125372503f);
        p = fmaf(p, w, -0.00417768164f);
        p = fmaf(p, w, 0.246640727f);
        p = fmaf(p, w, 1.50140941f);
    } else {
        w = sqrtf(w) - 3.0f;
        p = -0.000200214257f;
        p = fmaf(p, w, 0.000100950558f);
        p = fmaf(p, w, 0.00134934322f);
        p = fmaf(p, w, -0.00367342844f);
        p = fmaf(p, w, 0.00573950773f);
        p = fmaf(p, w, -0.0076224613f);
        p = fmaf(p, w, 0.00943887047f);
        p = fmaf(p, w, 1.00167406f);
        p = fmaf(p, w, 2.83297682f);
    }
    return p * x;
}

__device__ __forceinline__ float bits_to_normal(unsigned bits) {
    unsigned fb = (bits >> 9) | 0x3f800000u;
    float f = __uint_as_float(fb) - 1.0f;
    const float lo = -0.99999994f;           // nextafterf(-1,0)
    float u = fmaf(f, 2.0f, lo);             // f*(hi-lo)+lo, hi-lo rounds to 2.0f
    u = fmaxf(u, lo);
    return 1.41421356237f * erfinv_f(u);
}

// ---------------- kernels ----------------

// x [B,3,N] -> xyz [B,N,3], sq [B,N]
__global__ void prep_kernel(const float* __restrict__ x, float* __restrict__ xyz,
                            float* __restrict__ sq) {
    int gid = blockIdx.x * 256 + threadIdx.x;
    if (gid >= NBATCH * NPTS) return;
    int b = gid >> 12, n = gid & (NPTS - 1);
    float a0 = x[(b * 3 + 0) * NPTS + n];
    float a1 = x[(b * 3 + 1) * NPTS + n];
    float a2 = x[(b * 3 + 2) * NPTS + n];
    xyz[gid * 3 + 0] = a0; xyz[gid * 3 + 1] = a1; xyz[gid * 3 + 2] = a2;
    sq[gid] = a0 * a0 + a1 * a1 + a2 * a2;
}

// JAX threefry2x32, key(42) -> slots = mu + sigma * normal
__global__ void slots_init_kernel(const float* __restrict__ mu, const float* __restrict__ sg,
                                  float* __restrict__ slots) {
    int j = blockIdx.x * 256 + threadIdx.x;
    if (j >= 2048) return;
    unsigned ks0 = 0u, ks1 = 42u, ks2 = 0u ^ 42u ^ 0x1BD11BDAu;
    unsigned x0 = (unsigned)j + ks0;
    unsigned x1 = (unsigned)(j + 2048) + ks1;
    #define RND(r) { x0 += x1; x1 = rotl32(x1, r); x1 ^= x0; }
    RND(13u) RND(15u) RND(26u) RND(6u);  x0 += ks1; x1 += ks2 + 1u;
    RND(17u) RND(29u) RND(16u) RND(24u); x0 += ks2; x1 += ks0 + 2u;
    RND(13u) RND(15u) RND(26u) RND(6u);  x0 += ks0; x1 += ks1 + 3u;
    RND(17u) RND(29u) RND(16u) RND(24u); x0 += ks1; x1 += ks2 + 4u;
    RND(13u) RND(15u) RND(26u) RND(6u);  x0 += ks2; x1 += ks0 + 5u;
    #undef RND
    int c0 = j & 255, c1 = (j + 2048) & 255;
    slots[j]        = mu[c0] + sg[c0] * bits_to_normal(x0);
    slots[j + 2048] = mu[c1] + sg[c1] * bits_to_normal(x1);
}

// one block per query point; 16 dists per thread held in REGISTERS.
// Per round: block argmin over cached per-thread mins; only the winning
// thread invalidates + rescans its 16. Stable smallest-index tie-break
// matches lax.top_k.
__global__ __launch_bounds__(256) void knn_kernel(const float* __restrict__ xyz,
                                                  const float* __restrict__ sq,
                                                  int* __restrict__ knn_idx) {
    int pid = blockIdx.x;
    int b = pid >> 12, n = pid & (NPTS - 1);
    int tid = threadIdx.x;
    __shared__ float swv[4];
    __shared__ int   swi[4];
    const float* xb = xyz + (size_t)b * NPTS * 3;
    const float* sb = sq + (size_t)b * NPTS;
    float px = xb[n * 3], py = xb[n * 3 + 1], pz = xb[n * 3 + 2];
    float sn = sb[n];
    float dist[16];
    #pragma unroll 4
    for (int i = 0; i < 16; ++i) {
        int m = tid + i * 256;
        float dx = xb[m * 3], dy = xb[m * 3 + 1], dz = xb[m * 3 + 2];
        float dot = px * dx + py * dy + pz * dz;
        dist[i] = sn + sb[m] - 2.0f * dot;
    }
    // local cached min (smallest index on ties via ascending scan + strict <)
    float minv = 1e30f; int minm = 2147483647;
    #pragma unroll
    for (int i = 0; i < 16; ++i)
        if (dist[i] < minv) { minv = dist[i]; minm = tid + i * 256; }

    int* out = knn_idx + (size_t)pid * KNNK;
    for (int s = 0; s < KNNK; ++s) {
        float bv = minv; int bi = minm;
        #pragma unroll
        for (int o = 32; o; o >>= 1) {
            float ov = __shfl_down(bv, o); int oi = __shfl_down(bi, o);
            if (ov < bv || (ov == bv && oi < bi)) { bv = ov; bi = oi; }
        }
        int lane = tid & 63, w = tid >> 6;
        if (lane == 0) { swv[w] = bv; swi[w] = bi; }
        __syncthreads();
        float fv = swv[0]; int fi = swi[0];
        #pragma unroll
        for (int w2 = 1; w2 < 4; ++w2) {
            float v2 = swv[w2]; int i2 = swi[w2];
            if (v2 < fv || (v2 == fv && i2 < fi)) { fv = v2; fi = i2; }
        }
        if (tid == 0) out[s] = fi;
        // owner invalidates and rescans its 16
        if ((fi & 255) == tid) {
            int slot = fi >> 8;
            #pragma unroll
            for (int i = 0; i < 16; ++i)
                if (i == slot) dist[i] = 1e30f;
            minv = 1e30f; minm = 2147483647;
            #pragma unroll
            for (int i = 0; i < 16; ++i)
                if (dist[i] < minv) { minv = dist[i]; minm = tid + i * 256; }
        }
        __syncthreads();
    }
}

// conv1: feats are all-ones -> h = [1, rel]; out = relu(max_k (W1[0]+b1+rel.W1[1:4]))
__global__ __launch_bounds__(128) void conv1_kernel(const float* __restrict__ xyz,
                                                    const int* __restrict__ knn_idx,
                                                    const float* __restrict__ W1,
                                                    const float* __restrict__ b1,
                                                    float* __restrict__ f1) {
    int pid = blockIdx.x;
    int b = pid >> 12, n = pid & (NPTS - 1);
    int d = threadIdx.x;
    const float* xb = xyz + (size_t)b * NPTS * 3;
    float w0 = W1[d], wx = W1[C1D + d], wy = W1[2 * C1D + d], wz = W1[3 * C1D + d];
    float bb = b1[d];
    float px = xb[n * 3], py = xb[n * 3 + 1], pz = xb[n * 3 + 2];
    const int* idx = knn_idx + (size_t)pid * KNNK;
    float m = -1e30f;
    for (int k = 0; k < KNNK; ++k) {
        int j = idx[k];
        float rx = xb[j * 3] - px, ry = xb[j * 3 + 1] - py, rz = xb[j * 3 + 2] - pz;
        float v = w0 + bb + rx * wx + ry * wy + rz * wz;
        m = fmaxf(m, v);
    }
    f1[(size_t)pid * C1D + d] = fmaxf(m, 0.0f);
}

// conv2 + LayerNorm fused, 2D register tiling:
// thread = (kq, dq): 4 k-rows x 8 d-cols, 32 accumulators.
// Per c: one float4 LDS read of h (8 distinct addrs/wave, conflict-free) +
// 32B of W2 from global (same-address merged across kq within the wave).
__global__ __launch_bounds__(256) void conv2ln_kernel(const float* __restrict__ xyz,
                                                      const float* __restrict__ f1,
                                                      const int* __restrict__ knn_idx,
                                                      const float* __restrict__ W2,
                                                      const float* __restrict__ b2,
                                                      const float* __restrict__ g_in,
                                                      const float* __restrict__ b_in,
                                                      float* __restrict__ inp) {
    int pid = blockIdx.x;
    int b = pid >> 12, n = pid & (NPTS - 1);
    int tid = threadIdx.x;
    __shared__ float h[131 * 36];   // h[c*36 + k]
    __shared__ float colmax[CD];
    __shared__ float red[4];
    const int* idx = knn_idx + (size_t)pid * KNNK;
    const float* f1b = f1 + (size_t)b * NPTS * C1D;
    {
        int c = tid & 127, parity = tid >> 7;
        for (int kb = 0; kb < 16; ++kb) {
            int k = kb * 2 + parity;
            h[c * 36 + k] = f1b[(size_t)idx[k] * C1D + c];
        }
    }
    const float* xb = xyz + (size_t)b * NPTS * 3;
    if (tid < 96) {
        int k = tid & 31, comp = tid >> 5;
        int j = idx[k];
        h[(128 + comp) * 36 + k] = xb[j * 3 + comp] - xb[n * 3 + comp];
    }
    __syncthreads();

    int kq4 = (tid & 7) * 4;     // 4 k-rows starting here
    int dq8 = (tid >> 3) * 8;    // 8 d-cols starting here
    float acc[4][8];
    #pragma unroll
    for (int i = 0; i < 4; ++i)
        #pragma unroll
        for (int j = 0; j < 8; ++j) acc[i][j] = 0.0f;

    for (int c = 0; c < 131; ++c) {
        float4 hv = *(const float4*)&h[c * 36 + kq4];
        const float4* wr = (const float4*)(W2 + c * CD + dq8);
        float4 wa = wr[0], wb4 = wr[1];
        float wj[8] = {wa.x, wa.y, wa.z, wa.w, wb4.x, wb4.y, wb4.z, wb4.w};
        float hi[4] = {hv.x, hv.y, hv.z, hv.w};
        #pragma unroll
        for (int i = 0; i < 4; ++i)
            #pragma unroll
            for (int j = 0; j < 8; ++j)
                acc[i][j] = fmaf(hi[i], wj[j], acc[i][j]);
    }

    // max over the 4 local k-rows, then across the 8 kq lanes
    float m8[8];
    #pragma unroll
    for (int j = 0; j < 8; ++j)
        m8[j] = fmaxf(fmaxf(acc[0][j], acc[1][j]), fmaxf(acc[2][j], acc[3][j]));
    #pragma unroll
    for (int o = 1; o < 8; o <<= 1)
        #pragma unroll
        for (int j = 0; j < 8; ++j)
            m8[j] = fmaxf(m8[j], __shfl_xor(m8[j], o));
    if ((tid & 7) == 0) {
        #pragma unroll
        for (int j = 0; j < 8; ++j) colmax[dq8 + j] = m8[j];
    }
    __syncthreads();

    int d = tid;
    float v = fmaxf(colmax[d] + b2[d], 0.0f);
    float s = block_sum256(v, red);
    float mean = s * (1.0f / 256.0f);
    float s2 = block_sum256(v * v, red);
    float var = s2 * (1.0f / 256.0f) - mean * mean;
    float iv = (v - mean) * rsqrtf(var + 1e-5f) * g_in[d] + b_in[d];
    inp[(size_t)pid * CD + d] = iv;
}

// kk = inp @ Wk, vv = inp @ Wv ; 16 points per block to amortize weight reads
__global__ __launch_bounds__(256) void kv_kernel(const float* __restrict__ inp,
                                                 const float* __restrict__ Wk,
                                                 const float* __restrict__ Wv,
                                                 float* __restrict__ kk,
                                                 float* __restrict__ vv) {
    int base = blockIdx.x * 16;
    int d = threadIdx.x;
    __shared__ float t[CD * 16];    // t[c*16+p]
    for (int p = 0; p < 16; ++p) t[d * 16 + p] = inp[((size_t)base + p) * CD + d];
    __syncthreads();
    float ka[16], va[16];
    #pragma unroll
    for (int p = 0; p < 16; ++p) { ka[p] = 0.0f; va[p] = 0.0f; }
    for (int c = 0; c < CD; ++c) {
        float wk = Wk[c * CD + d], wv = Wv[c * CD + d];
        const float4* tp = (const float4*)&t[c * 16];
        #pragma unroll
        for (int q4 = 0; q4 < 4; ++q4) {
            float4 x = tp[q4];
            ka[q4 * 4 + 0] += x.x * wk; va[q4 * 4 + 0] += x.x * wv;
            ka[q4 * 4 + 1] += x.y * wk; va[q4 * 4 + 1] += x.y * wv;
            ka[q4 * 4 + 2] += x.z * wk; va[q4 * 4 + 2] += x.z * wv;
            ka[q4 * 4 + 3] += x.w * wk; va[q4 * 4 + 3] += x.w * wv;
        }
    }
    for (int p = 0; p < 16; ++p) {
        kk[((size_t)base + p) * CD + d] = ka[p];
        vv[((size_t)base + p) * CD + d] = va[p];
    }
}

// q = LN(slots) @ Wq, one block per row (b,k); block 0 zeroes attn_sum
__global__ __launch_bounds__(256) void slotq_kernel(const float* __restrict__ slots,
                                                    const float* __restrict__ g_sl,
                                                    const float* __restrict__ b_sl,
                                                    const float* __restrict__ Wq,
                                                    float* __restrict__ q,
                                                    float* __restrict__ asum) {
    int row = blockIdx.x;
    int d = threadIdx.x;
    __shared__ float sl[CD];
    __shared__ float red[4];
    float v = slots[row * CD + d];
    float s = block_sum256(v, red);
    float mean = s * (1.0f / 256.0f);
    float s2 = block_sum256(v * v, red);
    float var = s2 * (1.0f / 256.0f) - mean * mean;
    float ln = (v - mean) * rsqrtf(var + 1e-5f) * g_sl[d] + b_sl[d];
    sl[d] = ln;
    __syncthreads();
    float acc = 0.0f;
    const float4* sp = (const float4*)sl;
    for (int c4 = 0; c4 < 64; ++c4) {
        float4 x = sp[c4];
        int cb = c4 * 4;
        acc += x.x * Wq[cb * CD + d] + x.y * Wq[(cb + 1) * CD + d]
             + x.z * Wq[(cb + 2) * CD + d] + x.w * Wq[(cb + 3) * CD + d];
    }
    q[row * CD + d] = acc;
    if (row == 0 && d < 16) asum[d] = 0.0f;
}

// logits -> softmax over slots -> attn [B,4,N]; atomic per-slot sums over n
__global__ __launch_bounds__(256) void attn_kernel(const float* __restrict__ q,
                                                   const float* __restrict__ kk,
                                                   float* __restrict__ attn,
                                                   float* __restrict__ asum) {
    int b = blockIdx.x >> 4;
    int nb = blockIdx.x & 15;
    int n = nb * 256 + threadIdx.x;
    __shared__ float qs[4 * CD];
    __shared__ float redk[16];
    for (int i = threadIdx.x; i < 4 * CD; i += 256) qs[i] = q[b * 4 * CD + i];
    __syncthreads();
    const float4* kp = (const float4*)(kk + ((size_t)b * NPTS + n) * CD);
    const float4* q0 = (const float4*)(qs);
    const float4* q1 = (const float4*)(qs + CD);
    const float4* q2 = (const float4*)(qs + 2 * CD);
    const float4* q3 = (const float4*)(qs + 3 * CD);
    float a0 = 0, a1 = 0, a2 = 0, a3 = 0;
    for (int c4 = 0; c4 < 64; ++c4) {
        float4 kv = kp[c4];
        float4 x;
        x = q0[c4]; a0 += kv.x * x.x + kv.y * x.y + kv.z * x.z + kv.w * x.w;
        x = q1[c4]; a1 += kv.x * x.x + kv.y * x.y + kv.z * x.z + kv.w * x.w;
        x = q2[c4]; a2 += kv.x * x.x + kv.y * x.y + kv.z * x.z + kv.w * x.w;
        x = q3[c4]; a3 += kv.x * x.x + kv.y * x.y + kv.z * x.z + kv.w * x.w;
    }
    const float scale = 0.0625f;   // 256^-0.5
    float l0 = scale * a0, l1 = scale * a1, l2 = scale * a2, l3 = scale * a3;
    float mx = fmaxf(fmaxf(l0, l1), fmaxf(l2, l3));
    float e0 = expf(l0 - mx), e1 = expf(l1 - mx), e2 = expf(l2 - mx), e3 = expf(l3 - mx);
    float inv = 1.0f / (e0 + e1 + e2 + e3);
    e0 *= inv; e1 *= inv; e2 *= inv; e3 *= inv;
    attn[((size_t)b * 4 + 0) * NPTS + n] = e0;
    attn[((size_t)b * 4 + 1) * NPTS + n] = e1;
    attn[((size_t)b * 4 + 2) * NPTS + n] = e2;
    attn[((size_t)b * 4 + 3) * NPTS + n] = e3;
    float as[4] = {e0, e1, e2, e3};
    #pragma unroll
    for (int k = 0; k < 4; ++k) {
        float v = as[k];
        #pragma unroll
        for (int o = 32; o; o >>= 1) v += __shfl_down(v, o);
        if ((threadIdx.x & 63) == 0) redk[(threadIdx.x >> 6) * 4 + k] = v;
    }
    __syncthreads();
    if (threadIdx.x < 4) {
        float s = redk[threadIdx.x] + redk[4 + threadIdx.x] + redk[8 + threadIdx.x] + redk[12 + threadIdx.x];
        atomicAdd(&asum[b * 4 + threadIdx.x], s);
    }
}

// partial sums of attn*vv over 256-point chunks (deterministic, no atomics)
__global__ __launch_bounds__(256) void updp_kernel(const float* __restrict__ attn,
                                                   const float* __restrict__ vv,
                                                   float* __restrict__ updp) {
    int row = blockIdx.x >> 4, chunk = blockIdx.x & 15;
    int b = row >> 2;
    int d = threadIdx.x;
    const float* arow = attn + (size_t)row * NPTS + chunk * 256;
    const float* vb = vv + ((size_t)b * NPTS + chunk * 256) * CD;
    float acc = 0.0f;
    for (int n = 0; n < 256; ++n) acc += arow[n] * vb[(size_t)n * CD + d];
    updp[((size_t)row * 16 + chunk) * CD + d] = acc;
}

// GRU + LN_ff + MLP residual, one block per row (b,k), slots updated in place
__global__ __launch_bounds__(256) void gru_mlp_kernel(const float* __restrict__ updp,
                                                      const float* __restrict__ asum,
                                                      float* __restrict__ slots,
                                                      const float* __restrict__ W_ih,
                                                      const float* __restrict__ W_hh,
                                                      const float* __restrict__ b_ih,
                                                      const float* __restrict__ b_hh,
                                                      const float* __restrict__ g_ff,
                                                      const float* __restrict__ b_ff,
                                                      const float* __restrict__ Wm1,
                                                      const float* __restrict__ bm1,
                                                      const float* __restrict__ Wm2,
                                                      const float* __restrict__ bm2) {
    int row = blockIdx.x;
    int d = threadIdx.x;
    __shared__ float su[CD], sp[CD], sh[CD];
    __shared__ float red[4];
    float f = 1.0f / (asum[row] + 1e-8f);
    float u = 0.0f;
    for (int p = 0; p < 16; ++p) u += updp[((size_t)row * 16 + p) * CD + d];
    u *= f;
    float prev = slots[row * CD + d];
    su[d] = u; sp[d] = prev;
    __syncthreads();
    float gir = b_ih[d], giz = b_ih[CD + d], gin = b_ih[2 * CD + d];
    float ghr = b_hh[d], ghz = b_hh[CD + d], ghn = b_hh[2 * CD + d];
    for (int c = 0; c < CD; ++c) {
        float uc = su[c], pc = sp[c];
        const float* wi = W_ih + c * 3 * CD;
        const float* wh = W_hh + c * 3 * CD;
        gir += uc * wi[d]; giz += uc * wi[CD + d]; gin += uc * wi[2 * CD + d];
        ghr += pc * wh[d]; ghz += pc * wh[CD + d]; ghn += pc * wh[2 * CD + d];
    }
    float r = 1.0f / (1.0f + expf(-(gir + ghr)));
    float z = 1.0f / (1.0f + expf(-(giz + ghz)));
    float nn = tanhf(gin + r * ghn);
    float sNew = (1.0f - z) * nn + z * prev;
    float s = block_sum256(sNew, red);
    float mean = s * (1.0f / 256.0f);
    float s2 = block_sum256(sNew * sNew, red);
    float var = s2 * (1.0f / 256.0f) - mean * mean;
    float h = (sNew - mean) * rsqrtf(var + 1e-5f) * g_ff[d] + b_ff[d];
    __syncthreads();
    sh[d] = h;
    __syncthreads();
    float y = bm1[d];
    {
        const float4* hp = (const float4*)sh;
        for (int c4 = 0; c4 < 64; ++c4) {
            float4 x = hp[c4];
            int cb = c4 * 4;
            y += x.x * Wm1[cb * CD + d] + x.y * Wm1[(cb + 1) * CD + d]
               + x.z * Wm1[(cb + 2) * CD + d] + x.w * Wm1[(cb + 3) * CD + d];
        }
    }
    y = fmaxf(y, 0.0f);
    __syncthreads();
    sh[d] = y;
    __syncthreads();
    float o = bm2[d];
    {
        const float4* hp = (const float4*)sh;
        for (int c4 = 0; c4 < 64; ++c4) {
            float4 x = hp[c4];
            int cb = c4 * 4;
            o += x.x * Wm2[cb * CD + d] + x.y * Wm2[(cb + 1) * CD + d]
               + x.z * Wm2[(cb + 2) * CD + d] + x.w * Wm2[(cb + 3) * CD + d];
        }
    }
    slots[row * CD + d] = sNew + o;
}

// recon head: two (linear+BN+relu) + final linear -> slot_pts [B,384,3]
__global__ __launch_bounds__(320) void recon_kernel(const float* __restrict__ slots,
                                                    const float* __restrict__ Wr1, const float* __restrict__ br1,
                                                    const float* __restrict__ g1, const float* __restrict__ be1,
                                                    const float* __restrict__ Wr2, const float* __restrict__ br2,
                                                    const float* __restrict__ g2, const float* __restrict__ be2,
                                                    const float* __restrict__ Wr3, const float* __restrict__ br3,
                                                    float* __restrict__ spts) {
    __shared__ float sl[16 * CD];
    __shared__ float h1[16 * CD];
    __shared__ float h2[16 * CD];
    int d = threadIdx.x;
    if (d < CD) for (int r = 0; r < 16; ++r) sl[r * CD + d] = slots[r * CD + d];
    __syncthreads();
    if (d < CD) {
        float t[16];
        for (int r = 0; r < 16; ++r) {
            float acc = br1[d];
            const float4* sp = (const float4*)(sl + r * CD);
            for (int c4 = 0; c4 < 64; ++c4) {
                float4 x = sp[c4];
                int cb = c4 * 4;
                acc += x.x * Wr1[cb * CD + d] + x.y * Wr1[(cb + 1) * CD + d]
                     + x.z * Wr1[(cb + 2) * CD + d] + x.w * Wr1[(cb + 3) * CD + d];
            }
            t[r] = acc;
        }
        float mean = 0.0f;
        for (int r = 0; r < 16; ++r) mean += t[r];
        mean *= (1.0f / 16.0f);
        float var = 0.0f;
        for (int r = 0; r < 16; ++r) { float dd = t[r] - mean; var += dd * dd; }
        var *= (1.0f / 16.0f);
        float inv = rsqrtf(var + 1e-5f);
        for (int r = 0; r < 16; ++r)
            h1[r * CD + d] = fmaxf(0.0f, (t[r] - mean) * inv * g1[d] + be1[d]);
    }
    __syncthreads();
    if (d < CD) {
        float t[16];
        for (int r = 0; r < 16; ++r) {
            float acc = br2[d];
            const float4* sp = (const float4*)(h1 + r * CD);
            for (int c4 = 0; c4 < 64; ++c4) {
                float4 x = sp[c4];
                int cb = c4 * 4;
                acc += x.x * Wr2[cb * CD + d] + x.y * Wr2[(cb + 1) * CD + d]
                     + x.z * Wr2[(cb + 2) * CD + d] + x.w * Wr2[(cb + 3) * CD + d];
            }
            t[r] = acc;
        }
        float mean = 0.0f;
        for (int r = 0; r < 16; ++r) mean += t[r];
        mean *= (1.0f / 16.0f);
        float var = 0.0f;
        for (int r = 0; r < 16; ++r) { float dd = t[r] - mean; var += dd * dd; }
        var *= (1.0f / 16.0f);
        float inv = rsqrtf(var + 1e-5f);
        for (int r = 0; r < 16; ++r)
            h2[r * CD + d] = fmaxf(0.0f, (t[r] - mean) * inv * g2[d] + be2[d]);
    }
    __syncthreads();
    if (d < 288) {
        for (int r = 0; r < 16; ++r) {
            float acc = br3[d];
            const float4* sp = (const float4*)(h2 + r * CD);
            for (int c4 = 0; c4 < 64; ++c4) {
                float4 x = sp[c4];
                int cb = c4 * 4;
                acc += x.x * Wr3[cb * 288 + d] + x.y * Wr3[(cb + 1) * 288 + d]
                     + x.z * Wr3[(cb + 2) * 288 + d] + x.w * Wr3[(cb + 3) * 288 + d];
            }
            spts[r * 288 + d] = acc;
        }
    }
}

// farthest point sampling: one block per batch, 384 pts, 128 selections
__global__ __launch_bounds__(128) void fps_kernel(const float* __restrict__ spts,
                                                  int* __restrict__ fidx,
                                                  float* __restrict__ lacc) {
    int b = blockIdx.x;
    int t = threadIdx.x;
    const float* pts = spts + (size_t)b * 384 * 3;
    __shared__ float rv[2];
    __shared__ int ri[2];
    __shared__ int bidx;
    int* out = fidx + b * 128;
    if (t == 0) out[0] = 0;
    if (b == 0 && t == 0) lacc[0] = 0.0f;
    float x0 = pts[t * 3], y0 = pts[t * 3 + 1], z0 = pts[t * 3 + 2];
    float x1 = pts[(t + 128) * 3], y1 = pts[(t + 128) * 3 + 1], z1 = pts[(t + 128) * 3 + 2];
    float x2 = pts[(t + 256) * 3], y2 = pts[(t + 256) * 3 + 1], z2 = pts[(t + 256) * 3 + 2];
    float d0 = 1e10f, d1 = 1e10f, d2 = 1e10f;
    float lx = pts[0], ly = pts[1], lz = pts[2];
    for (int s = 1; s < 128; ++s) {
        float dx, dy, dz;
        dx = x0 - lx; dy = y0 - ly; dz = z0 - lz; d0 = fminf(d0, dx * dx + dy * dy + dz * dz);
        dx = x1 - lx; dy = y1 - ly; dz = z1 - lz; d1 = fminf(d1, dx * dx + dy * dy + dz * dz);
        dx = x2 - lx; dy = y2 - ly; dz = z2 - lz; d2 = fminf(d2, dx * dx + dy * dy + dz * dz);
        float bv = d0; int bi = t;
        if (d1 > bv) { bv = d1; bi = t + 128; }
        if (d2 > bv) { bv = d2; bi = t + 256; }
        #pragma unroll
        for (int o = 32; o; o >>= 1) {
            float ov = __shfl_down(bv, o); int oi = __shfl_down(bi, o);
            if (ov > bv || (ov == bv && oi < bi)) { bv = ov; bi = oi; }
        }
        int lane = t & 63, w = t >> 6;
        if (lane == 0) { rv[w] = bv; ri[w] = bi; }
        __syncthreads();
        if (t == 0) {
            float fv = rv[0]; int fi = ri[0];
            if (rv[1] > fv || (rv[1] == fv && ri[1] < fi)) { fv = rv[1]; fi = ri[1]; }
            out[s] = fi;
            bidx = fi;
        }
        __syncthreads();
        int ni = bidx;
        lx = pts[ni * 3]; ly = pts[ni * 3 + 1]; lz = pts[ni * 3 + 2];
    }
}

// chamfer(ds, xyz), accumulate (mean d1 + mean d2) per batch
__global__ __launch_bounds__(256) void chamfer_kernel(const float* __restrict__ spts,
                                                      const int* __restrict__ fidx,
                                                      const float* __restrict__ xyz,
                                                      float* __restrict__ lacc) {
    int b = blockIdx.x;
    int t = threadIdx.x;
    __shared__ float ds[128 * 3];
    __shared__ float red[4];
    const float* pts = spts + (size_t)b * 384 * 3;
    if (t < 128) {
        int j = fidx[b * 128 + t];
        ds[t * 3] = pts[j * 3]; ds[t * 3 + 1] = pts[j * 3 + 1]; ds[t * 3 + 2] = pts[j * 3 + 2];
    }
    __syncthreads();
    const float* xb = xyz + (size_t)b * NPTS * 3;
    float sum2 = 0.0f;
    for (int n = t; n < NPTS; n += 256) {
        float px = xb[n * 3], py = xb[n * 3 + 1], pz = xb[n * 3 + 2];
        float mn = 1e30f;
        for (int j = 0; j < 128; ++j) {
            float dx = ds[j * 3] - px, dy = ds[j * 3 + 1] - py, dz = ds[j * 3 + 2] - pz;
            mn = fminf(mn, dx * dx + dy * dy + dz * dz);
        }
        sum2 += mn;
    }
    float sum1 = 0.0f;
    if (t < 128) {
        float px = ds[t * 3], py = ds[t * 3 + 1], pz = ds[t * 3 + 2];
        float mn = 1e30f;
        for (int n = 0; n < NPTS; ++n) {
            float dx = xb[n * 3] - px, dy = xb[n * 3 + 1] - py, dz = xb[n * 3 + 2] - pz;
            mn = fminf(mn, dx * dx + dy * dy + dz * dz);
        }
        sum1 = mn;
    }
    float total = block_sum256(sum2 * (1.0f / 4096.0f) + sum1 * (1.0f / 128.0f), red);
    if (t == 0) atomicAdd(lacc, total);
}

// write loss + attn_out [B,N,K]
__global__ void finalize_kernel(const float* __restrict__ attn,
                                const float* __restrict__ lacc,
                                float* __restrict__ out) {
    int gid = blockIdx.x * 256 + threadIdx.x;
    if (gid >= NBATCH * NPTS) return;
    int b = gid >> 12, n = gid & (NPTS - 1);
    float r0 = attn[((size_t)b * 4 + 0) * NPTS + n];
    float r1 = attn[((size_t)b * 4 + 1) * NPTS + n];
    float r2 = attn[((size_t)b * 4 + 2) * NPTS + n];
    float r3 = attn[((size_t)b * 4 + 3) * NPTS + n];
    out[1 + gid * 4 + 0] = r0;
    out[1 + gid * 4 + 1] = r1;
    out[1 + gid * 4 + 2] = r2;
    out[1 + gid * 4 + 3] = r3;
    if (gid == 0) out[0] = lacc[0] * 0.25f;
}

// ---------------- launch ----------------

extern "C" void kernel_launch(void* const* d_in, const int* in_sizes, int n_in,
                              void* d_out, int out_size, void* d_ws, size_t ws_size,
                              hipStream_t stream) {
    (void)in_sizes; (void)n_in; (void)out_size; (void)ws_size;
    const float* x    = (const float*)d_in[0];
    const float* W1   = (const float*)d_in[2];
    const float* b1   = (const float*)d_in[3];
    const float* W2   = (const float*)d_in[4];
    const float* b2   = (const float*)d_in[5];
    const float* mu   = (const float*)d_in[6];
    const float* sg   = (const float*)d_in[7];
    const float* g_in = (const float*)d_in[8];
    const float* b_in = (const float*)d_in[9];
    const float* g_sl = (const float*)d_in[10];
    const float* b_sl = (const float*)d_in[11];
    const float* g_ff = (const float*)d_in[12];
    const float* b_ff = (const float*)d_in[13];
    const float* Wq   = (const float*)d_in[14];
    const float* Wk   = (const float*)d_in[15];
    const float* Wv   = (const float*)d_in[16];
    const float* W_ih = (const float*)d_in[17];
    const float* W_hh = (const float*)d_in[18];
    const float* b_ih = (const float*)d_in[19];
    const float* b_hh = (const float*)d_in[20];
    const float* Wm1  = (const float*)d_in[21];
    const float* bm1  = (const float*)d_in[22];
    const float* Wm2  = (const float*)d_in[23];
    const float* bm2  = (const float*)d_in[24];
    const float* Wr1  = (const float*)d_in[25];
    const float* br1  = (const float*)d_in[26];
    const float* g1   = (const float*)d_in[27];
    const float* be1  = (const float*)d_in[28];
    const float* Wr2  = (const float*)d_in[29];
    const float* br2  = (const float*)d_in[30];
    const float* g2   = (const float*)d_in[31];
    const float* be2  = (const float*)d_in[32];
    const float* Wr3  = (const float*)d_in[33];
    const float* br3  = (const float*)d_in[34];

    float* ws    = (float*)d_ws;
    float* xyz   = ws;                               // 49152
    float* sq    = xyz + 49152;                      // 16384
    int*   knn   = (int*)(sq + 16384);               // 524288 ints
    float* f1    = (float*)(knn + 524288);           // 2097152
    float* inp   = f1 + 2097152;                     // 4194304
    float* kkb   = inp + 4194304;                    // 4194304
    float* vvb   = kkb + 4194304;                    // 4194304
    float* slots = vvb + 4194304;                    // 4096
    float* qb    = slots + 4096;                     // 4096
    float* attn  = qb + 4096;                        // 65536
    float* asum  = attn + 65536;                     // 16
    float* updp  = asum + 16;                        // 65536
    float* spts  = updp + 65536;                     // 4608
    int*   fidx  = (int*)(spts + 4608);              // 512
    float* lacc  = (float*)(fidx + 512);             // 1

    prep_kernel<<<64, 256, 0, stream>>>(x, xyz, sq);
    slots_init_kernel<<<8, 256, 0, stream>>>(mu, sg, slots);
    knn_kernel<<<NBATCH * NPTS, 256, 0, stream>>>(xyz, sq, knn);
    conv1_kernel<<<NBATCH * NPTS, 128, 0, stream>>>(xyz, knn, W1, b1, f1);
    conv2ln_kernel<<<NBATCH * NPTS, 256, 0, stream>>>(xyz, f1, knn, W2, b2, g_in, b_in, inp);
    kv_kernel<<<NBATCH * NPTS / 16, 256, 0, stream>>>(inp, Wk, Wv, kkb, vvb);

    for (int it = 0; it < 3; ++it) {
        slotq_kernel<<<16, 256, 0, stream>>>(slots, g_sl, b_sl, Wq, qb, asum);
        attn_kernel<<<64, 256, 0, stream>>>(qb, kkb, attn, asum);
        updp_kernel<<<256, 256, 0, stream>>>(attn, vvb, updp);
        gru_mlp_kernel<<<16, 256, 0, stream>>>(updp, asum, slots, W_ih, W_hh, b_ih, b_hh,
                                               g_ff, b_ff, Wm1, bm1, Wm2, bm2);
    }

    recon_kernel<<<1, 320, 0, stream>>>(slots, Wr1, br1, g1, be1, Wr2, br2, g2, be2, Wr3, br3, spts);
    fps_kernel<<<4, 128, 0, stream>>>(spts, fidx, lacc);
    chamfer_kernel<<<4, 256, 0, stream>>>(spts, fidx, xyz, lacc);
    finalize_kernel<<<64, 256, 0, stream>>>(attn, lacc, (float*)d_out);
}

// Round 3
// 1630.957 us; speedup vs baseline: 1.4134x; 1.2790x over previous
//
#include <hip/hip_runtime.h>

#define NBATCH 4
#define NPTS   4096
#define KNNK   32
#define C1D    128
#define CD     256
#define KPAD   160   // conv2 K padded (131 -> 160, 5 mfma K-steps of 32)
#define ASTR   168   // LDS A row stride in halves (bank-conflict-free-ish)

typedef _Float16 v8h __attribute__((ext_vector_type(8)));
typedef float    v4f __attribute__((ext_vector_type(4)));

// ---------------- helpers ----------------

__device__ __forceinline__ float block_sum256(float v, float* red) {
    #pragma unroll
    for (int o = 32; o; o >>= 1) v += __shfl_down(v, o);
    __syncthreads();
    if ((threadIdx.x & 63) == 0) red[threadIdx.x >> 6] = v;
    __syncthreads();
    return red[0] + red[1] + red[2] + red[3];
}

__device__ __forceinline__ unsigned rotl32(unsigned x, unsigned r) {
    return (x << r) | (x >> (32u - r));
}

// XLA f32 erf_inv (Giles polynomial)
__device__ float erfinv_f(float x) {
    float w = -log1pf(-x * x);
    float p;
    if (w < 5.0f) {
        w -= 2.5f;
        p = 2.81022636e-08f;
        p = fmaf(p, w, 3.43273939e-07f);
        p = fmaf(p, w, -3.5233877e-06f);
        p = fmaf(p, w, -4.39150654e-06f);
        p = fmaf(p, w, 0.00021858087f);
        p = fmaf(p, w, -0.00125372503f);
        p = fmaf(p, w, -0.00417768164f);
        p = fmaf(p, w, 0.246640727f);
        p = fmaf(p, w, 1.50140941f);
    } else {
        w = sqrtf(w) - 3.0f;
        p = -0.000200214257f;
        p = fmaf(p, w, 0.000100950558f);
        p = fmaf(p, w, 0.00134934322f);
        p = fmaf(p, w, -0.00367342844f);
        p = fmaf(p, w, 0.00573950773f);
        p = fmaf(p, w, -0.0076224613f);
        p = fmaf(p, w, 0.00943887047f);
        p = fmaf(p, w, 1.00167406f);
        p = fmaf(p, w, 2.83297682f);
    }
    return p * x;
}

__device__ __forceinline__ float bits_to_normal(unsigned bits) {
    unsigned fb = (bits >> 9) | 0x3f800000u;
    float f = __uint_as_float(fb) - 1.0f;
    const float lo = -0.99999994f;           // nextafterf(-1,0)
    float u = fmaf(f, 2.0f, lo);
    u = fmaxf(u, lo);
    return 1.41421356237f * erfinv_f(u);
}

// ---------------- kernels ----------------

// x [B,3,N] -> xyz [B,N,3], sq [B,N]
__global__ void prep_kernel(const float* __restrict__ x, float* __restrict__ xyz,
                            float* __restrict__ sq) {
    int gid = blockIdx.x * 256 + threadIdx.x;
    if (gid >= NBATCH * NPTS) return;
    int b = gid >> 12, n = gid & (NPTS - 1);
    float a0 = x[(b * 3 + 0) * NPTS + n];
    float a1 = x[(b * 3 + 1) * NPTS + n];
    float a2 = x[(b * 3 + 2) * NPTS + n];
    xyz[gid * 3 + 0] = a0; xyz[gid * 3 + 1] = a1; xyz[gid * 3 + 2] = a2;
    sq[gid] = a0 * a0 + a1 * a1 + a2 * a2;
}

// JAX threefry2x32, key(42) -> slots = mu + sigma * normal
__global__ void slots_init_kernel(const float* __restrict__ mu, const float* __restrict__ sg,
                                  float* __restrict__ slots) {
    int j = blockIdx.x * 256 + threadIdx.x;
    if (j >= 2048) return;
    unsigned ks0 = 0u, ks1 = 42u, ks2 = 0u ^ 42u ^ 0x1BD11BDAu;
    unsigned x0 = (unsigned)j + ks0;
    unsigned x1 = (unsigned)(j + 2048) + ks1;
    #define RND(r) { x0 += x1; x1 = rotl32(x1, r); x1 ^= x0; }
    RND(13u) RND(15u) RND(26u) RND(6u);  x0 += ks1; x1 += ks2 + 1u;
    RND(17u) RND(29u) RND(16u) RND(24u); x0 += ks2; x1 += ks0 + 2u;
    RND(13u) RND(15u) RND(26u) RND(6u);  x0 += ks0; x1 += ks1 + 3u;
    RND(17u) RND(29u) RND(16u) RND(24u); x0 += ks1; x1 += ks2 + 4u;
    RND(13u) RND(15u) RND(26u) RND(6u);  x0 += ks2; x1 += ks0 + 5u;
    #undef RND
    int c0 = j & 255, c1 = (j + 2048) & 255;
    slots[j]        = mu[c0] + sg[c0] * bits_to_normal(x0);
    slots[j + 2048] = mu[c1] + sg[c1] * bits_to_normal(x1);
}

// one block per query point; 16 dists per thread held in registers
__global__ __launch_bounds__(256) void knn_kernel(const float* __restrict__ xyz,
                                                  const float* __restrict__ sq,
                                                  int* __restrict__ knn_idx) {
    int pid = blockIdx.x;
    int b = pid >> 12, n = pid & (NPTS - 1);
    int tid = threadIdx.x;
    __shared__ float swv[4];
    __shared__ int   swi[4];
    const float* xb = xyz + (size_t)b * NPTS * 3;
    const float* sb = sq + (size_t)b * NPTS;
    float px = xb[n * 3], py = xb[n * 3 + 1], pz = xb[n * 3 + 2];
    float sn = sb[n];
    float dist[16];
    #pragma unroll 4
    for (int i = 0; i < 16; ++i) {
        int m = tid + i * 256;
        float dx = xb[m * 3], dy = xb[m * 3 + 1], dz = xb[m * 3 + 2];
        float dot = px * dx + py * dy + pz * dz;
        dist[i] = sn + sb[m] - 2.0f * dot;
    }
    float minv = 1e30f; int minm = 2147483647;
    #pragma unroll
    for (int i = 0; i < 16; ++i)
        if (dist[i] < minv) { minv = dist[i]; minm = tid + i * 256; }

    int* out = knn_idx + (size_t)pid * KNNK;
    for (int s = 0; s < KNNK; ++s) {
        float bv = minv; int bi = minm;
        #pragma unroll
        for (int o = 32; o; o >>= 1) {
            float ov = __shfl_down(bv, o); int oi = __shfl_down(bi, o);
            if (ov < bv || (ov == bv && oi < bi)) { bv = ov; bi = oi; }
        }
        int lane = tid & 63, w = tid >> 6;
        if (lane == 0) { swv[w] = bv; swi[w] = bi; }
        __syncthreads();
        float fv = swv[0]; int fi = swi[0];
        #pragma unroll
        for (int w2 = 1; w2 < 4; ++w2) {
            float v2 = swv[w2]; int i2 = swi[w2];
            if (v2 < fv || (v2 == fv && i2 < fi)) { fv = v2; fi = i2; }
        }
        if (tid == 0) out[s] = fi;
        if ((fi & 255) == tid) {
            int slot = fi >> 8;
            #pragma unroll
            for (int i = 0; i < 16; ++i)
                if (i == slot) dist[i] = 1e30f;
            minv = 1e30f; minm = 2147483647;
            #pragma unroll
            for (int i = 0; i < 16; ++i)
                if (dist[i] < minv) { minv = dist[i]; minm = tid + i * 256; }
        }
        __syncthreads();
    }
}

// conv1 -> fp16 features for the MFMA conv2
__global__ __launch_bounds__(128) void conv1_kernel(const float* __restrict__ xyz,
                                                    const int* __restrict__ knn_idx,
                                                    const float* __restrict__ W1,
                                                    const float* __restrict__ b1,
                                                    _Float16* __restrict__ f1h) {
    int pid = blockIdx.x;
    int b = pid >> 12, n = pid & (NPTS - 1);
    int d = threadIdx.x;
    const float* xb = xyz + (size_t)b * NPTS * 3;
    float w0 = W1[d], wx = W1[C1D + d], wy = W1[2 * C1D + d], wz = W1[3 * C1D + d];
    float bb = b1[d];
    float px = xb[n * 3], py = xb[n * 3 + 1], pz = xb[n * 3 + 2];
    const int* idx = knn_idx + (size_t)pid * KNNK;
    float m = -1e30f;
    for (int k = 0; k < KNNK; ++k) {
        int j = idx[k];
        float rx = xb[j * 3] - px, ry = xb[j * 3 + 1] - py, rz = xb[j * 3 + 2] - pz;
        float v = w0 + bb + rx * wx + ry * wy + rz * wz;
        m = fmaxf(m, v);
    }
    f1h[(size_t)pid * C1D + d] = (_Float16)fmaxf(m, 0.0f);
}

// W2 [131+pad? stored 131x256 fp32] -> W2t [256][160] fp16 (transposed, zero-padded)
__global__ void w2t_kernel(const float* __restrict__ W2, _Float16* __restrict__ W2t) {
    int n = blockIdx.x;          // 0..255
    int k = threadIdx.x;         // 0..159
    W2t[n * KPAD + k] = (k < 131) ? (_Float16)W2[k * CD + n] : (_Float16)0.0f;
}

// conv2 via MFMA f16 (fp32 accumulate) + fused bias/relu/max-over-k/LayerNorm.
// Block = 2 points = 64 gathered neighbor rows x 256 cols, K padded to 160.
__global__ __launch_bounds__(256) void conv2_mfma_kernel(const float* __restrict__ xyz,
                                                         const _Float16* __restrict__ f1h,
                                                         const int* __restrict__ knn_idx,
                                                         const _Float16* __restrict__ W2t,
                                                         const float* __restrict__ b2,
                                                         const float* __restrict__ g_in,
                                                         const float* __restrict__ b_in,
                                                         float* __restrict__ inp) {
    __shared__ _Float16 A[64 * ASTR];
    __shared__ float colmax[2 * CD];
    __shared__ float red[4];
    int pid2 = blockIdx.x;
    int gp0 = pid2 * 2;
    int b = gp0 >> 12, n0 = gp0 & (NPTS - 1);
    int tid = threadIdx.x;
    const int* idx = knn_idx + (size_t)pid2 * 64;   // [2][32]
    const float* xb = xyz + (size_t)b * NPTS * 3;

    // ---- stage A: rows r = p*32+k hold [f1h(idx) fp16 | rel fp16 | zeros] ----
    {
        int r = tid & 63, seg = tid >> 6;   // 4 segs of 64B over 128 halves
        int j = idx[r];
        const uint4* s4 = (const uint4*)(f1h + ((size_t)b * NPTS + j) * C1D);
        uint4* d4 = (uint4*)&A[r * ASTR];
        #pragma unroll
        for (int i = 0; i < 4; ++i) d4[seg * 4 + i] = s4[seg * 4 + i];
        // zero halves 128..167 (20 uints)
        unsigned* z = (unsigned*)&A[r * ASTR + 128];
        for (int i = seg; i < 20; i += 4) z[i] = 0u;
        // rel overwrites halves 128..130 (same threads that zeroed those uints)
        int np_ = (r < 32) ? n0 : (n0 + 1);
        if (seg == 0) {
            A[r * ASTR + 128] = (_Float16)(xb[j * 3 + 0] - xb[np_ * 3 + 0]);
            A[r * ASTR + 129] = (_Float16)(xb[j * 3 + 1] - xb[np_ * 3 + 1]);
        } else if (seg == 1) {
            A[r * ASTR + 130] = (_Float16)(xb[j * 3 + 2] - xb[np_ * 3 + 2]);
        }
    }
    __syncthreads();

    // ---- MFMA main loop: wave w covers cols [w*64, w*64+64) ----
    int w = tid >> 6, lane = tid & 63, quad = lane >> 4, lr = lane & 15;
    v4f acc[4][4];
    #pragma unroll
    for (int rt = 0; rt < 4; ++rt)
        #pragma unroll
        for (int ct = 0; ct < 4; ++ct)
            acc[rt][ct] = (v4f){0.0f, 0.0f, 0.0f, 0.0f};

    #pragma unroll
    for (int kk = 0; kk < KPAD; kk += 32) {
        v8h af[4], bf[4];
        #pragma unroll
        for (int rt = 0; rt < 4; ++rt)
            af[rt] = *(const v8h*)&A[(rt * 16 + lr) * ASTR + kk + quad * 8];
        #pragma unroll
        for (int ct = 0; ct < 4; ++ct) {
            int ncol = w * 64 + ct * 16 + lr;
            bf[ct] = *(const v8h*)(W2t + (size_t)ncol * KPAD + kk + quad * 8);
        }
        #pragma unroll
        for (int rt = 0; rt < 4; ++rt)
            #pragma unroll
            for (int ct = 0; ct < 4; ++ct)
                acc[rt][ct] = __builtin_amdgcn_mfma_f32_16x16x32_f16(af[rt], bf[ct], acc[rt][ct], 0, 0, 0);
    }

    // ---- max over k rows inside C fragments ----
    // C layout: col = lane&15 (n), row = quad*4 + reg (m). rows 0..31 = point0, 32..63 = point1.
    #pragma unroll
    for (int ct = 0; ct < 4; ++ct) {
        float tm[4];
        #pragma unroll
        for (int rt = 0; rt < 4; ++rt) {
            v4f a = acc[rt][ct];
            float v = fmaxf(fmaxf(a[0], a[1]), fmaxf(a[2], a[3]));
            v = fmaxf(v, __shfl_xor(v, 16));
            v = fmaxf(v, __shfl_xor(v, 32));
            tm[rt] = v;   // max over all 16 rows of row-tile rt (valid in every lane)
        }
        float p0 = fmaxf(tm[0], tm[1]);
        float p1 = fmaxf(tm[2], tm[3]);
        if (quad == 0) {
            colmax[0 * CD + w * 64 + ct * 16 + lr] = p0;
            colmax[1 * CD + w * 64 + ct * 16 + lr] = p1;
        }
    }
    __syncthreads();

    // ---- bias + relu + LayerNorm per point ----
    int d = tid;
    #pragma unroll
    for (int p = 0; p < 2; ++p) {
        float v = fmaxf(colmax[p * CD + d] + b2[d], 0.0f);
        float s = block_sum256(v, red);
        float mean = s * (1.0f / 256.0f);
        float s2 = block_sum256(v * v, red);
        float var = s2 * (1.0f / 256.0f) - mean * mean;
        float iv = (v - mean) * rsqrtf(var + 1e-5f) * g_in[d] + b_in[d];
        inp[(size_t)(gp0 + p) * CD + d] = iv;
    }
}

// kk = inp @ Wk, vv = inp @ Wv ; 16 points per block to amortize weight reads
__global__ __launch_bounds__(256) void kv_kernel(const float* __restrict__ inp,
                                                 const float* __restrict__ Wk,
                                                 const float* __restrict__ Wv,
                                                 float* __restrict__ kk,
                                                 float* __restrict__ vv) {
    int base = blockIdx.x * 16;
    int d = threadIdx.x;
    __shared__ float t[CD * 16];    // t[c*16+p]
    for (int p = 0; p < 16; ++p) t[d * 16 + p] = inp[((size_t)base + p) * CD + d];
    __syncthreads();
    float ka[16], va[16];
    #pragma unroll
    for (int p = 0; p < 16; ++p) { ka[p] = 0.0f; va[p] = 0.0f; }
    for (int c = 0; c < CD; ++c) {
        float wk = Wk[c * CD + d], wv = Wv[c * CD + d];
        const float4* tp = (const float4*)&t[c * 16];
        #pragma unroll
        for (int q4 = 0; q4 < 4; ++q4) {
            float4 x = tp[q4];
            ka[q4 * 4 + 0] += x.x * wk; va[q4 * 4 + 0] += x.x * wv;
            ka[q4 * 4 + 1] += x.y * wk; va[q4 * 4 + 1] += x.y * wv;
            ka[q4 * 4 + 2] += x.z * wk; va[q4 * 4 + 2] += x.z * wv;
            ka[q4 * 4 + 3] += x.w * wk; va[q4 * 4 + 3] += x.w * wv;
        }
    }
    for (int p = 0; p < 16; ++p) {
        kk[((size_t)base + p) * CD + d] = ka[p];
        vv[((size_t)base + p) * CD + d] = va[p];
    }
}

// q = LN(slots) @ Wq, one block per row (b,k); block 0 zeroes attn_sum
__global__ __launch_bounds__(256) void slotq_kernel(const float* __restrict__ slots,
                                                    const float* __restrict__ g_sl,
                                                    const float* __restrict__ b_sl,
                                                    const float* __restrict__ Wq,
                                                    float* __restrict__ q,
                                                    float* __restrict__ asum) {
    int row = blockIdx.x;
    int d = threadIdx.x;
    __shared__ float sl[CD];
    __shared__ float red[4];
    float v = slots[row * CD + d];
    float s = block_sum256(v, red);
    float mean = s * (1.0f / 256.0f);
    float s2 = block_sum256(v * v, red);
    float var = s2 * (1.0f / 256.0f) - mean * mean;
    float ln = (v - mean) * rsqrtf(var + 1e-5f) * g_sl[d] + b_sl[d];
    sl[d] = ln;
    __syncthreads();
    float acc = 0.0f;
    const float4* sp = (const float4*)sl;
    for (int c4 = 0; c4 < 64; ++c4) {
        float4 x = sp[c4];
        int cb = c4 * 4;
        acc += x.x * Wq[cb * CD + d] + x.y * Wq[(cb + 1) * CD + d]
             + x.z * Wq[(cb + 2) * CD + d] + x.w * Wq[(cb + 3) * CD + d];
    }
    q[row * CD + d] = acc;
    if (row == 0 && d < 16) asum[d] = 0.0f;
}

// logits -> softmax over slots -> attn [B,4,N]; atomic per-slot sums over n
__global__ __launch_bounds__(256) void attn_kernel(const float* __restrict__ q,
                                                   const float* __restrict__ kk,
                                                   float* __restrict__ attn,
                                                   float* __restrict__ asum) {
    int b = blockIdx.x >> 4;
    int nb = blockIdx.x & 15;
    int n = nb * 256 + threadIdx.x;
    __shared__ float qs[4 * CD];
    __shared__ float redk[16];
    for (int i = threadIdx.x; i < 4 * CD; i += 256) qs[i] = q[b * 4 * CD + i];
    __syncthreads();
    const float4* kp = (const float4*)(kk + ((size_t)b * NPTS + n) * CD);
    const float4* q0 = (const float4*)(qs);
    const float4* q1 = (const float4*)(qs + CD);
    const float4* q2 = (const float4*)(qs + 2 * CD);
    const float4* q3 = (const float4*)(qs + 3 * CD);
    float a0 = 0, a1 = 0, a2 = 0, a3 = 0;
    for (int c4 = 0; c4 < 64; ++c4) {
        float4 kv = kp[c4];
        float4 x;
        x = q0[c4]; a0 += kv.x * x.x + kv.y * x.y + kv.z * x.z + kv.w * x.w;
        x = q1[c4]; a1 += kv.x * x.x + kv.y * x.y + kv.z * x.z + kv.w * x.w;
        x = q2[c4]; a2 += kv.x * x.x + kv.y * x.y + kv.z * x.z + kv.w * x.w;
        x = q3[c4]; a3 += kv.x * x.x + kv.y * x.y + kv.z * x.z + kv.w * x.w;
    }
    const float scale = 0.0625f;   // 256^-0.5
    float l0 = scale * a0, l1 = scale * a1, l2 = scale * a2, l3 = scale * a3;
    float mx = fmaxf(fmaxf(l0, l1), fmaxf(l2, l3));
    float e0 = expf(l0 - mx), e1 = expf(l1 - mx), e2 = expf(l2 - mx), e3 = expf(l3 - mx);
    float inv = 1.0f / (e0 + e1 + e2 + e3);
    e0 *= inv; e1 *= inv; e2 *= inv; e3 *= inv;
    attn[((size_t)b * 4 + 0) * NPTS + n] = e0;
    attn[((size_t)b * 4 + 1) * NPTS + n] = e1;
    attn[((size_t)b * 4 + 2) * NPTS + n] = e2;
    attn[((size_t)b * 4 + 3) * NPTS + n] = e3;
    float as[4] = {e0, e1, e2, e3};
    #pragma unroll
    for (int k = 0; k < 4; ++k) {
        float v = as[k];
        #pragma unroll
        for (int o = 32; o; o >>= 1) v += __shfl_down(v, o);
        if ((threadIdx.x & 63) == 0) redk[(threadIdx.x >> 6) * 4 + k] = v;
    }
    __syncthreads();
    if (threadIdx.x < 4) {
        float s = redk[threadIdx.x] + redk[4 + threadIdx.x] + redk[8 + threadIdx.x] + redk[12 + threadIdx.x];
        atomicAdd(&asum[b * 4 + threadIdx.x], s);
    }
}

// partial sums of attn*vv over 256-point chunks (deterministic, no atomics)
__global__ __launch_bounds__(256) void updp_kernel(const float* __restrict__ attn,
                                                   const float* __restrict__ vv,
                                                   float* __restrict__ updp) {
    int row = blockIdx.x >> 4, chunk = blockIdx.x & 15;
    int b = row >> 2;
    int d = threadIdx.x;
    const float* arow = attn + (size_t)row * NPTS + chunk * 256;
    const float* vb = vv + ((size_t)b * NPTS + chunk * 256) * CD;
    float acc = 0.0f;
    for (int n = 0; n < 256; ++n) acc += arow[n] * vb[(size_t)n * CD + d];
    updp[((size_t)row * 16 + chunk) * CD + d] = acc;
}

// GRU + LN_ff + MLP residual, one block per row (b,k), slots updated in place
__global__ __launch_bounds__(256) void gru_mlp_kernel(const float* __restrict__ updp,
                                                      const float* __restrict__ asum,
                                                      float* __restrict__ slots,
                                                      const float* __restrict__ W_ih,
                                                      const float* __restrict__ W_hh,
                                                      const float* __restrict__ b_ih,
                                                      const float* __restrict__ b_hh,
                                                      const float* __restrict__ g_ff,
                                                      const float* __restrict__ b_ff,
                                                      const float* __restrict__ Wm1,
                                                      const float* __restrict__ bm1,
                                                      const float* __restrict__ Wm2,
                                                      const float* __restrict__ bm2) {
    int row = blockIdx.x;
    int d = threadIdx.x;
    __shared__ float su[CD], sp[CD], sh[CD];
    __shared__ float red[4];
    float f = 1.0f / (asum[row] + 1e-8f);
    float u = 0.0f;
    for (int p = 0; p < 16; ++p) u += updp[((size_t)row * 16 + p) * CD + d];
    u *= f;
    float prev = slots[row * CD + d];
    su[d] = u; sp[d] = prev;
    __syncthreads();
    float gir = b_ih[d], giz = b_ih[CD + d], gin = b_ih[2 * CD + d];
    float ghr = b_hh[d], ghz = b_hh[CD + d], ghn = b_hh[2 * CD + d];
    for (int c = 0; c < CD; ++c) {
        float uc = su[c], pc = sp[c];
        const float* wi = W_ih + c * 3 * CD;
        const float* wh = W_hh + c * 3 * CD;
        gir += uc * wi[d]; giz += uc * wi[CD + d]; gin += uc * wi[2 * CD + d];
        ghr += pc * wh[d]; ghz += pc * wh[CD + d]; ghn += pc * wh[2 * CD + d];
    }
    float r = 1.0f / (1.0f + expf(-(gir + ghr)));
    float z = 1.0f / (1.0f + expf(-(giz + ghz)));
    float nn = tanhf(gin + r * ghn);
    float sNew = (1.0f - z) * nn + z * prev;
    float s = block_sum256(sNew, red);
    float mean = s * (1.0f / 256.0f);
    float s2 = block_sum256(sNew * sNew, red);
    float var = s2 * (1.0f / 256.0f) - mean * mean;
    float h = (sNew - mean) * rsqrtf(var + 1e-5f) * g_ff[d] + b_ff[d];
    __syncthreads();
    sh[d] = h;
    __syncthreads();
    float y = bm1[d];
    {
        const float4* hp = (const float4*)sh;
        for (int c4 = 0; c4 < 64; ++c4) {
            float4 x = hp[c4];
            int cb = c4 * 4;
            y += x.x * Wm1[cb * CD + d] + x.y * Wm1[(cb + 1) * CD + d]
               + x.z * Wm1[(cb + 2) * CD + d] + x.w * Wm1[(cb + 3) * CD + d];
        }
    }
    y = fmaxf(y, 0.0f);
    __syncthreads();
    sh[d] = y;
    __syncthreads();
    float o = bm2[d];
    {
        const float4* hp = (const float4*)sh;
        for (int c4 = 0; c4 < 64; ++c4) {
            float4 x = hp[c4];
            int cb = c4 * 4;
            o += x.x * Wm2[cb * CD + d] + x.y * Wm2[(cb + 1) * CD + d]
               + x.z * Wm2[(cb + 2) * CD + d] + x.w * Wm2[(cb + 3) * CD + d];
        }
    }
    slots[row * CD + d] = sNew + o;
}

// recon head: two (linear+BN+relu) + final linear -> slot_pts [B,384,3]
__global__ __launch_bounds__(320) void recon_kernel(const float* __restrict__ slots,
                                                    const float* __restrict__ Wr1, const float* __restrict__ br1,
                                                    const float* __restrict__ g1, const float* __restrict__ be1,
                                                    const float* __restrict__ Wr2, const float* __restrict__ br2,
                                                    const float* __restrict__ g2, const float* __restrict__ be2,
                                                    const float* __restrict__ Wr3, const float* __restrict__ br3,
                                                    float* __restrict__ spts) {
    __shared__ float sl[16 * CD];
    __shared__ float h1[16 * CD];
    __shared__ float h2[16 * CD];
    int d = threadIdx.x;
    if (d < CD) for (int r = 0; r < 16; ++r) sl[r * CD + d] = slots[r * CD + d];
    __syncthreads();
    if (d < CD) {
        float t[16];
        for (int r = 0; r < 16; ++r) {
            float acc = br1[d];
            const float4* sp = (const float4*)(sl + r * CD);
            for (int c4 = 0; c4 < 64; ++c4) {
                float4 x = sp[c4];
                int cb = c4 * 4;
                acc += x.x * Wr1[cb * CD + d] + x.y * Wr1[(cb + 1) * CD + d]
                     + x.z * Wr1[(cb + 2) * CD + d] + x.w * Wr1[(cb + 3) * CD + d];
            }
            t[r] = acc;
        }
        float mean = 0.0f;
        for (int r = 0; r < 16; ++r) mean += t[r];
        mean *= (1.0f / 16.0f);
        float var = 0.0f;
        for (int r = 0; r < 16; ++r) { float dd = t[r] - mean; var += dd * dd; }
        var *= (1.0f / 16.0f);
        float inv = rsqrtf(var + 1e-5f);
        for (int r = 0; r < 16; ++r)
            h1[r * CD + d] = fmaxf(0.0f, (t[r] - mean) * inv * g1[d] + be1[d]);
    }
    __syncthreads();
    if (d < CD) {
        float t[16];
        for (int r = 0; r < 16; ++r) {
            float acc = br2[d];
            const float4* sp = (const float4*)(h1 + r * CD);
            for (int c4 = 0; c4 < 64; ++c4) {
                float4 x = sp[c4];
                int cb = c4 * 4;
                acc += x.x * Wr2[cb * CD + d] + x.y * Wr2[(cb + 1) * CD + d]
                     + x.z * Wr2[(cb + 2) * CD + d] + x.w * Wr2[(cb + 3) * CD + d];
            }
            t[r] = acc;
        }
        float mean = 0.0f;
        for (int r = 0; r < 16; ++r) mean += t[r];
        mean *= (1.0f / 16.0f);
        float var = 0.0f;
        for (int r = 0; r < 16; ++r) { float dd = t[r] - mean; var += dd * dd; }
        var *= (1.0f / 16.0f);
        float inv = rsqrtf(var + 1e-5f);
        for (int r = 0; r < 16; ++r)
            h2[r * CD + d] = fmaxf(0.0f, (t[r] - mean) * inv * g2[d] + be2[d]);
    }
    __syncthreads();
    if (d < 288) {
        for (int r = 0; r < 16; ++r) {
            float acc = br3[d];
            const float4* sp = (const float4*)(h2 + r * CD);
            for (int c4 = 0; c4 < 64; ++c4) {
                float4 x = sp[c4];
                int cb = c4 * 4;
                acc += x.x * Wr3[cb * 288 + d] + x.y * Wr3[(cb + 1) * 288 + d]
                     + x.z * Wr3[(cb + 2) * 288 + d] + x.w * Wr3[(cb + 3) * 288 + d];
            }
            spts[r * 288 + d] = acc;
        }
    }
}

// farthest point sampling: one block per batch, 384 pts, 128 selections
__global__ __launch_bounds__(128) void fps_kernel(const float* __restrict__ spts,
                                                  int* __restrict__ fidx,
                                                  float* __restrict__ lacc) {
    int b = blockIdx.x;
    int t = threadIdx.x;
    const float* pts = spts + (size_t)b * 384 * 3;
    __shared__ float rv[2];
    __shared__ int ri[2];
    __shared__ int bidx;
    int* out = fidx + b * 128;
    if (t == 0) out[0] = 0;
    if (b == 0 && t == 0) lacc[0] = 0.0f;
    float x0 = pts[t * 3], y0 = pts[t * 3 + 1], z0 = pts[t * 3 + 2];
    float x1 = pts[(t + 128) * 3], y1 = pts[(t + 128) * 3 + 1], z1 = pts[(t + 128) * 3 + 2];
    float x2 = pts[(t + 256) * 3], y2 = pts[(t + 256) * 3 + 1], z2 = pts[(t + 256) * 3 + 2];
    float d0 = 1e10f, d1 = 1e10f, d2 = 1e10f;
    float lx = pts[0], ly = pts[1], lz = pts[2];
    for (int s = 1; s < 128; ++s) {
        float dx, dy, dz;
        dx = x0 - lx; dy = y0 - ly; dz = z0 - lz; d0 = fminf(d0, dx * dx + dy * dy + dz * dz);
        dx = x1 - lx; dy = y1 - ly; dz = z1 - lz; d1 = fminf(d1, dx * dx + dy * dy + dz * dz);
        dx = x2 - lx; dy = y2 - ly; dz = z2 - lz; d2 = fminf(d2, dx * dx + dy * dy + dz * dz);
        float bv = d0; int bi = t;
        if (d1 > bv) { bv = d1; bi = t + 128; }
        if (d2 > bv) { bv = d2; bi = t + 256; }
        #pragma unroll
        for (int o = 32; o; o >>= 1) {
            float ov = __shfl_down(bv, o); int oi = __shfl_down(bi, o);
            if (ov > bv || (ov == bv && oi < bi)) { bv = ov; bi = oi; }
        }
        int lane = t & 63, w = t >> 6;
        if (lane == 0) { rv[w] = bv; ri[w] = bi; }
        __syncthreads();
        if (t == 0) {
            float fv = rv[0]; int fi = ri[0];
            if (rv[1] > fv || (rv[1] == fv && ri[1] < fi)) { fv = rv[1]; fi = ri[1]; }
            out[s] = fi;
            bidx = fi;
        }
        __syncthreads();
        int ni = bidx;
        lx = pts[ni * 3]; ly = pts[ni * 3 + 1]; lz = pts[ni * 3 + 2];
    }
}

// chamfer(ds, xyz), accumulate (mean d1 + mean d2) per batch
__global__ __launch_bounds__(256) void chamfer_kernel(const float* __restrict__ spts,
                                                      const int* __restrict__ fidx,
                                                      const float* __restrict__ xyz,
                                                      float* __restrict__ lacc) {
    int b = blockIdx.x;
    int t = threadIdx.x;
    __shared__ float ds[128 * 3];
    __shared__ float red[4];
    const float* pts = spts + (size_t)b * 384 * 3;
    if (t < 128) {
        int j = fidx[b * 128 + t];
        ds[t * 3] = pts[j * 3]; ds[t * 3 + 1] = pts[j * 3 + 1]; ds[t * 3 + 2] = pts[j * 3 + 2];
    }
    __syncthreads();
    const float* xb = xyz + (size_t)b * NPTS * 3;
    float sum2 = 0.0f;
    for (int n = t; n < NPTS; n += 256) {
        float px = xb[n * 3], py = xb[n * 3 + 1], pz = xb[n * 3 + 2];
        float mn = 1e30f;
        for (int j = 0; j < 128; ++j) {
            float dx = ds[j * 3] - px, dy = ds[j * 3 + 1] - py, dz = ds[j * 3 + 2] - pz;
            mn = fminf(mn, dx * dx + dy * dy + dz * dz);
        }
        sum2 += mn;
    }
    float sum1 = 0.0f;
    if (t < 128) {
        float px = ds[t * 3], py = ds[t * 3 + 1], pz = ds[t * 3 + 2];
        float mn = 1e30f;
        for (int n = 0; n < NPTS; ++n) {
            float dx = xb[n * 3] - px, dy = xb[n * 3 + 1] - py, dz = xb[n * 3 + 2] - pz;
            mn = fminf(mn, dx * dx + dy * dy + dz * dz);
        }
        sum1 = mn;
    }
    float total = block_sum256(sum2 * (1.0f / 4096.0f) + sum1 * (1.0f / 128.0f), red);
    if (t == 0) atomicAdd(lacc, total);
}

// write loss + attn_out [B,N,K]
__global__ void finalize_kernel(const float* __restrict__ attn,
                                const float* __restrict__ lacc,
                                float* __restrict__ out) {
    int gid = blockIdx.x * 256 + threadIdx.x;
    if (gid >= NBATCH * NPTS) return;
    int b = gid >> 12, n = gid & (NPTS - 1);
    float r0 = attn[((size_t)b * 4 + 0) * NPTS + n];
    float r1 = attn[((size_t)b * 4 + 1) * NPTS + n];
    float r2 = attn[((size_t)b * 4 + 2) * NPTS + n];
    float r3 = attn[((size_t)b * 4 + 3) * NPTS + n];
    out[1 + gid * 4 + 0] = r0;
    out[1 + gid * 4 + 1] = r1;
    out[1 + gid * 4 + 2] = r2;
    out[1 + gid * 4 + 3] = r3;
    if (gid == 0) out[0] = lacc[0] * 0.25f;
}

// ---------------- launch ----------------

extern "C" void kernel_launch(void* const* d_in, const int* in_sizes, int n_in,
                              void* d_out, int out_size, void* d_ws, size_t ws_size,
                              hipStream_t stream) {
    (void)in_sizes; (void)n_in; (void)out_size; (void)ws_size;
    const float* x    = (const float*)d_in[0];
    const float* W1   = (const float*)d_in[2];
    const float* b1   = (const float*)d_in[3];
    const float* W2   = (const float*)d_in[4];
    const float* b2   = (const float*)d_in[5];
    const float* mu   = (const float*)d_in[6];
    const float* sg   = (const float*)d_in[7];
    const float* g_in = (const float*)d_in[8];
    const float* b_in = (const float*)d_in[9];
    const float* g_sl = (const float*)d_in[10];
    const float* b_sl = (const float*)d_in[11];
    const float* g_ff = (const float*)d_in[12];
    const float* b_ff = (const float*)d_in[13];
    const float* Wq   = (const float*)d_in[14];
    const float* Wk   = (const float*)d_in[15];
    const float* Wv   = (const float*)d_in[16];
    const float* W_ih = (const float*)d_in[17];
    const float* W_hh = (const float*)d_in[18];
    const float* b_ih = (const float*)d_in[19];
    const float* b_hh = (const float*)d_in[20];
    const float* Wm1  = (const float*)d_in[21];
    const float* bm1  = (const float*)d_in[22];
    const float* Wm2  = (const float*)d_in[23];
    const float* bm2  = (const float*)d_in[24];
    const float* Wr1  = (const float*)d_in[25];
    const float* br1  = (const float*)d_in[26];
    const float* g1   = (const float*)d_in[27];
    const float* be1  = (const float*)d_in[28];
    const float* Wr2  = (const float*)d_in[29];
    const float* br2  = (const float*)d_in[30];
    const float* g2   = (const float*)d_in[31];
    const float* be2  = (const float*)d_in[32];
    const float* Wr3  = (const float*)d_in[33];
    const float* br3  = (const float*)d_in[34];

    float* ws    = (float*)d_ws;
    float* xyz   = ws;                               // 49152 f
    float* sq    = xyz + 49152;                      // 16384 f
    int*   knn   = (int*)(sq + 16384);               // 524288 i
    _Float16* f1h = (_Float16*)(knn + 524288);       // 2097152 h = 1048576 f
    _Float16* W2t = (_Float16*)((float*)f1h + 1048576); // 40960 h = 20480 f
    float* inp   = (float*)W2t + 20480;              // 4194304 f
    float* kkb   = inp + 4194304;                    // 4194304 f
    float* vvb   = kkb + 4194304;                    // 4194304 f
    float* slots = vvb + 4194304;                    // 4096 f
    float* qb    = slots + 4096;                     // 4096 f
    float* attn  = qb + 4096;                        // 65536 f
    float* asum  = attn + 65536;                     // 16 f
    float* updp  = asum + 16;                        // 65536 f
    float* spts  = updp + 65536;                     // 4608 f
    int*   fidx  = (int*)(spts + 4608);              // 512 i
    float* lacc  = (float*)(fidx + 512);             // 1 f

    prep_kernel<<<64, 256, 0, stream>>>(x, xyz, sq);
    slots_init_kernel<<<8, 256, 0, stream>>>(mu, sg, slots);
    knn_kernel<<<NBATCH * NPTS, 256, 0, stream>>>(xyz, sq, knn);
    conv1_kernel<<<NBATCH * NPTS, 128, 0, stream>>>(xyz, knn, W1, b1, f1h);
    w2t_kernel<<<256, 160, 0, stream>>>(W2, W2t);
    conv2_mfma_kernel<<<NBATCH * NPTS / 2, 256, 0, stream>>>(xyz, f1h, knn, W2t, b2, g_in, b_in, inp);
    kv_kernel<<<NBATCH * NPTS / 16, 256, 0, stream>>>(inp, Wk, Wv, kkb, vvb);

    for (int it = 0; it < 3; ++it) {
        slotq_kernel<<<16, 256, 0, stream>>>(slots, g_sl, b_sl, Wq, qb, asum);
        attn_kernel<<<64, 256, 0, stream>>>(qb, kkb, attn, asum);
        updp_kernel<<<256, 256, 0, stream>>>(attn, vvb, updp);
        gru_mlp_kernel<<<16, 256, 0, stream>>>(updp, asum, slots, W_ih, W_hh, b_ih, b_hh,
                                               g_ff, b_ff, Wm1, bm1, Wm2, bm2);
    }

    recon_kernel<<<1, 320, 0, stream>>>(slots, Wr1, br1, g1, be1, Wr2, br2, g2, be2, Wr3, br3, spts);
    fps_kernel<<<4, 128, 0, stream>>>(spts, fidx, lacc);
    chamfer_kernel<<<4, 256, 0, stream>>>(spts, fidx, xyz, lacc);
    finalize_kernel<<<64, 256, 0, stream>>>(attn, lacc, (float*)d_out);
}

// Round 4
// 1439.362 us; speedup vs baseline: 1.6016x; 1.1331x over previous
//
#include <hip/hip_runtime.h>

#define NBATCH 4
#define NPTS   4096
#define KNNK   32
#define C1D    128
#define CD     256
#define KPAD   160   // conv2 K padded (131 -> 160, 5 mfma K-steps of 32)
#define ASTR   168   // LDS A row stride in halves

typedef _Float16 v8h __attribute__((ext_vector_type(8)));
typedef float    v4f __attribute__((ext_vector_type(4)));

// ---------------- helpers ----------------

__device__ __forceinline__ float block_sum256(float v, float* red) {
    #pragma unroll
    for (int o = 32; o; o >>= 1) v += __shfl_down(v, o);
    __syncthreads();
    if ((threadIdx.x & 63) == 0) red[threadIdx.x >> 6] = v;
    __syncthreads();
    return red[0] + red[1] + red[2] + red[3];
}

__device__ __forceinline__ unsigned rotl32(unsigned x, unsigned r) {
    return (x << r) | (x >> (32u - r));
}

// XLA f32 erf_inv (Giles polynomial)
__device__ float erfinv_f(float x) {
    float w = -log1pf(-x * x);
    float p;
    if (w < 5.0f) {
        w -= 2.5f;
        p = 2.81022636e-08f;
        p = fmaf(p, w, 3.43273939e-07f);
        p = fmaf(p, w, -3.5233877e-06f);
        p = fmaf(p, w, -4.39150654e-06f);
        p = fmaf(p, w, 0.00021858087f);
        p = fmaf(p, w, -0.00125372503f);
        p = fmaf(p, w, -0.00417768164f);
        p = fmaf(p, w, 0.246640727f);
        p = fmaf(p, w, 1.50140941f);
    } else {
        w = sqrtf(w) - 3.0f;
        p = -0.000200214257f;
        p = fmaf(p, w, 0.000100950558f);
        p = fmaf(p, w, 0.00134934322f);
        p = fmaf(p, w, -0.00367342844f);
        p = fmaf(p, w, 0.00573950773f);
        p = fmaf(p, w, -0.0076224613f);
        p = fmaf(p, w, 0.00943887047f);
        p = fmaf(p, w, 1.00167406f);
        p = fmaf(p, w, 2.83297682f);
    }
    return p * x;
}

__device__ __forceinline__ float bits_to_normal(unsigned bits) {
    unsigned fb = (bits >> 9) | 0x3f800000u;
    float f = __uint_as_float(fb) - 1.0f;
    const float lo = -0.99999994f;           // nextafterf(-1,0)
    float u = fmaf(f, 2.0f, lo);
    u = fmaxf(u, lo);
    return 1.41421356237f * erfinv_f(u);
}

// ---------------- kernels ----------------

// x [B,3,N] -> xyz [B,N,3], xyzw [B,N] (x,y,z,sq)
__global__ void prep_kernel(const float* __restrict__ x, float* __restrict__ xyz,
                            float4* __restrict__ xyzw) {
    int gid = blockIdx.x * 256 + threadIdx.x;
    if (gid >= NBATCH * NPTS) return;
    int b = gid >> 12, n = gid & (NPTS - 1);
    float a0 = x[(b * 3 + 0) * NPTS + n];
    float a1 = x[(b * 3 + 1) * NPTS + n];
    float a2 = x[(b * 3 + 2) * NPTS + n];
    xyz[gid * 3 + 0] = a0; xyz[gid * 3 + 1] = a1; xyz[gid * 3 + 2] = a2;
    float sq = a0 * a0 + a1 * a1 + a2 * a2;
    xyzw[gid] = make_float4(a0, a1, a2, sq);
}

// JAX threefry2x32, key(42) -> slots = mu + sigma * normal
__global__ void slots_init_kernel(const float* __restrict__ mu, const float* __restrict__ sg,
                                  float* __restrict__ slots) {
    int j = blockIdx.x * 256 + threadIdx.x;
    if (j >= 2048) return;
    unsigned ks0 = 0u, ks1 = 42u, ks2 = 0u ^ 42u ^ 0x1BD11BDAu;
    unsigned x0 = (unsigned)j + ks0;
    unsigned x1 = (unsigned)(j + 2048) + ks1;
    #define RND(r) { x0 += x1; x1 = rotl32(x1, r); x1 ^= x0; }
    RND(13u) RND(15u) RND(26u) RND(6u);  x0 += ks1; x1 += ks2 + 1u;
    RND(17u) RND(29u) RND(16u) RND(24u); x0 += ks2; x1 += ks0 + 2u;
    RND(13u) RND(15u) RND(26u) RND(6u);  x0 += ks0; x1 += ks1 + 3u;
    RND(17u) RND(29u) RND(16u) RND(24u); x0 += ks1; x1 += ks2 + 4u;
    RND(13u) RND(15u) RND(26u) RND(6u);  x0 += ks2; x1 += ks0 + 5u;
    #undef RND
    int c0 = j & 255, c1 = (j + 2048) & 255;
    slots[j]        = mu[c0] + sg[c0] * bits_to_normal(x0);
    slots[j + 2048] = mu[c1] + sg[c1] * bits_to_normal(x1);
}

// KNN: ONE WAVE PER POINT, no barriers. Each lane caches 64 candidate dists
// in registers (2 groups of 32 with cached group-mins). Per round: wave
// shuffle-argmin + owner-only group rescan. Tie-breaks identical to lax.top_k
// (strict <, ascending index scans, smallest index on value ties).
__global__ __launch_bounds__(256) void knn_kernel(const float4* __restrict__ xyzw,
                                                  int* __restrict__ knn_idx) {
    int wid = threadIdx.x >> 6, lane = threadIdx.x & 63;
    int pid = blockIdx.x * 4 + wid;
    int b = pid >> 12, n = pid & (NPTS - 1);
    const float4* xb = xyzw + (size_t)b * NPTS;
    float4 p = xb[n];
    float d0[32], d1[32];
    #pragma unroll
    for (int i = 0; i < 32; ++i) {
        float4 c = xb[i * 64 + lane];
        float dot = p.x * c.x + p.y * c.y + p.z * c.z;
        d0[i] = p.w + c.w - 2.0f * dot;
    }
    #pragma unroll
    for (int i = 0; i < 32; ++i) {
        float4 c = xb[(i + 32) * 64 + lane];
        float dot = p.x * c.x + p.y * c.y + p.z * c.z;
        d1[i] = p.w + c.w - 2.0f * dot;
    }
    float mv0 = 1e30f; int mi0 = 0;
    #pragma unroll
    for (int i = 0; i < 32; ++i)
        if (d0[i] < mv0) { mv0 = d0[i]; mi0 = i * 64 + lane; }
    float mv1 = 1e30f; int mi1 = 0;
    #pragma unroll
    for (int i = 0; i < 32; ++i)
        if (d1[i] < mv1) { mv1 = d1[i]; mi1 = (i + 32) * 64 + lane; }

    int* out = knn_idx + (size_t)pid * KNNK;
    #pragma unroll 1
    for (int s = 0; s < KNNK; ++s) {
        float bv = mv0; int bi = mi0;
        if (mv1 < bv) { bv = mv1; bi = mi1; }   // tie -> group0 (smaller index)
        #pragma unroll
        for (int o = 32; o; o >>= 1) {
            float ov = __shfl_down(bv, o); int oi = __shfl_down(bi, o);
            if (ov < bv || (ov == bv && oi < bi)) { bv = ov; bi = oi; }
        }
        int fi = __shfl(bi, 0);
        if (lane == 0) out[s] = fi;
        if ((fi & 63) == lane) {
            int slot = fi >> 6;
            if (slot < 32) {
                #pragma unroll
                for (int i = 0; i < 32; ++i)
                    if (i == slot) d0[i] = 1e30f;
                mv0 = 1e30f; mi0 = 0;
                #pragma unroll
                for (int i = 0; i < 32; ++i)
                    if (d0[i] < mv0) { mv0 = d0[i]; mi0 = i * 64 + lane; }
            } else {
                int s1 = slot - 32;
                #pragma unroll
                for (int i = 0; i < 32; ++i)
                    if (i == s1) d1[i] = 1e30f;
                mv1 = 1e30f; mi1 = 0;
                #pragma unroll
                for (int i = 0; i < 32; ++i)
                    if (d1[i] < mv1) { mv1 = d1[i]; mi1 = (i + 32) * 64 + lane; }
            }
        }
    }
}

// conv1 -> fp16 features for the MFMA conv2
__global__ __launch_bounds__(128) void conv1_kernel(const float* __restrict__ xyz,
                                                    const int* __restrict__ knn_idx,
                                                    const float* __restrict__ W1,
                                                    const float* __restrict__ b1,
                                                    _Float16* __restrict__ f1h) {
    int pid = blockIdx.x;
    int b = pid >> 12, n = pid & (NPTS - 1);
    int d = threadIdx.x;
    const float* xb = xyz + (size_t)b * NPTS * 3;
    float w0 = W1[d], wx = W1[C1D + d], wy = W1[2 * C1D + d], wz = W1[3 * C1D + d];
    float bb = b1[d];
    float px = xb[n * 3], py = xb[n * 3 + 1], pz = xb[n * 3 + 2];
    const int* idx = knn_idx + (size_t)pid * KNNK;
    float m = -1e30f;
    for (int k = 0; k < KNNK; ++k) {
        int j = idx[k];
        float rx = xb[j * 3] - px, ry = xb[j * 3 + 1] - py, rz = xb[j * 3 + 2] - pz;
        float v = w0 + bb + rx * wx + ry * wy + rz * wz;
        m = fmaxf(m, v);
    }
    f1h[(size_t)pid * C1D + d] = (_Float16)fmaxf(m, 0.0f);
}

// W2 [131x256 fp32] -> W2t [256][160] fp16 (transposed, zero-padded)
__global__ void w2t_kernel(const float* __restrict__ W2, _Float16* __restrict__ W2t) {
    int n = blockIdx.x;          // 0..255
    int k = threadIdx.x;         // 0..159
    W2t[n * KPAD + k] = (k < 131) ? (_Float16)W2[k * CD + n] : (_Float16)0.0f;
}

// conv2 via MFMA f16 (fp32 accumulate) + fused bias/relu/max-over-k/LayerNorm.
__global__ __launch_bounds__(256) void conv2_mfma_kernel(const float* __restrict__ xyz,
                                                         const _Float16* __restrict__ f1h,
                                                         const int* __restrict__ knn_idx,
                                                         const _Float16* __restrict__ W2t,
                                                         const float* __restrict__ b2,
                                                         const float* __restrict__ g_in,
                                                         const float* __restrict__ b_in,
                                                         float* __restrict__ inp) {
    __shared__ _Float16 A[64 * ASTR];
    __shared__ float colmax[2 * CD];
    __shared__ float red[4];
    int pid2 = blockIdx.x;
    int gp0 = pid2 * 2;
    int b = gp0 >> 12, n0 = gp0 & (NPTS - 1);
    int tid = threadIdx.x;
    const int* idx = knn_idx + (size_t)pid2 * 64;   // [2][32]
    const float* xb = xyz + (size_t)b * NPTS * 3;

    {
        int r = tid & 63, seg = tid >> 6;
        int j = idx[r];
        const uint4* s4 = (const uint4*)(f1h + ((size_t)b * NPTS + j) * C1D);
        uint4* d4 = (uint4*)&A[r * ASTR];
        #pragma unroll
        for (int i = 0; i < 4; ++i) d4[seg * 4 + i] = s4[seg * 4 + i];
        unsigned* z = (unsigned*)&A[r * ASTR + 128];
        for (int i = seg; i < 20; i += 4) z[i] = 0u;
        int np_ = (r < 32) ? n0 : (n0 + 1);
        if (seg == 0) {
            A[r * ASTR + 128] = (_Float16)(xb[j * 3 + 0] - xb[np_ * 3 + 0]);
            A[r * ASTR + 129] = (_Float16)(xb[j * 3 + 1] - xb[np_ * 3 + 1]);
        } else if (seg == 1) {
            A[r * ASTR + 130] = (_Float16)(xb[j * 3 + 2] - xb[np_ * 3 + 2]);
        }
    }
    __syncthreads();

    int w = tid >> 6, lane = tid & 63, quad = lane >> 4, lr = lane & 15;
    v4f acc[4][4];
    #pragma unroll
    for (int rt = 0; rt < 4; ++rt)
        #pragma unroll
        for (int ct = 0; ct < 4; ++ct)
            acc[rt][ct] = (v4f){0.0f, 0.0f, 0.0f, 0.0f};

    #pragma unroll
    for (int kk = 0; kk < KPAD; kk += 32) {
        v8h af[4], bf[4];
        #pragma unroll
        for (int rt = 0; rt < 4; ++rt)
            af[rt] = *(const v8h*)&A[(rt * 16 + lr) * ASTR + kk + quad * 8];
        #pragma unroll
        for (int ct = 0; ct < 4; ++ct) {
            int ncol = w * 64 + ct * 16 + lr;
            bf[ct] = *(const v8h*)(W2t + (size_t)ncol * KPAD + kk + quad * 8);
        }
        #pragma unroll
        for (int rt = 0; rt < 4; ++rt)
            #pragma unroll
            for (int ct = 0; ct < 4; ++ct)
                acc[rt][ct] = __builtin_amdgcn_mfma_f32_16x16x32_f16(af[rt], bf[ct], acc[rt][ct], 0, 0, 0);
    }

    #pragma unroll
    for (int ct = 0; ct < 4; ++ct) {
        float tm[4];
        #pragma unroll
        for (int rt = 0; rt < 4; ++rt) {
            v4f a = acc[rt][ct];
            float v = fmaxf(fmaxf(a[0], a[1]), fmaxf(a[2], a[3]));
            v = fmaxf(v, __shfl_xor(v, 16));
            v = fmaxf(v, __shfl_xor(v, 32));
            tm[rt] = v;
        }
        float p0 = fmaxf(tm[0], tm[1]);
        float p1 = fmaxf(tm[2], tm[3]);
        if (quad == 0) {
            colmax[0 * CD + w * 64 + ct * 16 + lr] = p0;
            colmax[1 * CD + w * 64 + ct * 16 + lr] = p1;
        }
    }
    __syncthreads();

    int d = tid;
    #pragma unroll
    for (int p = 0; p < 2; ++p) {
        float v = fmaxf(colmax[p * CD + d] + b2[d], 0.0f);
        float s = block_sum256(v, red);
        float mean = s * (1.0f / 256.0f);
        float s2 = block_sum256(v * v, red);
        float var = s2 * (1.0f / 256.0f) - mean * mean;
        float iv = (v - mean) * rsqrtf(var + 1e-5f) * g_in[d] + b_in[d];
        inp[(size_t)(gp0 + p) * CD + d] = iv;
    }
}

// kk = inp @ Wk, vv = inp @ Wv ; 16 points per block
__global__ __launch_bounds__(256) void kv_kernel(const float* __restrict__ inp,
                                                 const float* __restrict__ Wk,
                                                 const float* __restrict__ Wv,
                                                 float* __restrict__ kk,
                                                 float* __restrict__ vv) {
    int base = blockIdx.x * 16;
    int d = threadIdx.x;
    __shared__ float t[CD * 16];    // t[c*16+p]
    for (int p = 0; p < 16; ++p) t[d * 16 + p] = inp[((size_t)base + p) * CD + d];
    __syncthreads();
    float ka[16], va[16];
    #pragma unroll
    for (int p = 0; p < 16; ++p) { ka[p] = 0.0f; va[p] = 0.0f; }
    for (int c = 0; c < CD; ++c) {
        float wk = Wk[c * CD + d], wv = Wv[c * CD + d];
        const float4* tp = (const float4*)&t[c * 16];
        #pragma unroll
        for (int q4 = 0; q4 < 4; ++q4) {
            float4 x = tp[q4];
            ka[q4 * 4 + 0] += x.x * wk; va[q4 * 4 + 0] += x.x * wv;
            ka[q4 * 4 + 1] += x.y * wk; va[q4 * 4 + 1] += x.y * wv;
            ka[q4 * 4 + 2] += x.z * wk; va[q4 * 4 + 2] += x.z * wv;
            ka[q4 * 4 + 3] += x.w * wk; va[q4 * 4 + 3] += x.w * wv;
        }
    }
    for (int p = 0; p < 16; ++p) {
        kk[((size_t)base + p) * CD + d] = ka[p];
        vv[((size_t)base + p) * CD + d] = va[p];
    }
}

// q = LN(slots) @ Wq, one block per row (b,k); block 0 zeroes attn_sum
__global__ __launch_bounds__(256) void slotq_kernel(const float* __restrict__ slots,
                                                    const float* __restrict__ g_sl,
                                                    const float* __restrict__ b_sl,
                                                    const float* __restrict__ Wq,
                                                    float* __restrict__ q,
                                                    float* __restrict__ asum) {
    int row = blockIdx.x;
    int d = threadIdx.x;
    __shared__ float sl[CD];
    __shared__ float red[4];
    float v = slots[row * CD + d];
    float s = block_sum256(v, red);
    float mean = s * (1.0f / 256.0f);
    float s2 = block_sum256(v * v, red);
    float var = s2 * (1.0f / 256.0f) - mean * mean;
    float ln = (v - mean) * rsqrtf(var + 1e-5f) * g_sl[d] + b_sl[d];
    sl[d] = ln;
    __syncthreads();
    float acc = 0.0f;
    const float4* sp = (const float4*)sl;
    for (int c4 = 0; c4 < 64; ++c4) {
        float4 x = sp[c4];
        int cb = c4 * 4;
        acc += x.x * Wq[cb * CD + d] + x.y * Wq[(cb + 1) * CD + d]
             + x.z * Wq[(cb + 2) * CD + d] + x.w * Wq[(cb + 3) * CD + d];
    }
    q[row * CD + d] = acc;
    if (row == 0 && d < 16) asum[d] = 0.0f;
}

// logits -> softmax over slots -> attn [B,4,N]; on last iter also writes out
__global__ __launch_bounds__(256) void attn_kernel(const float* __restrict__ q,
                                                   const float* __restrict__ kk,
                                                   float* __restrict__ attn,
                                                   float* __restrict__ asum,
                                                   float* __restrict__ out_attn) {
    int b = blockIdx.x >> 4;
    int nb = blockIdx.x & 15;
    int n = nb * 256 + threadIdx.x;
    __shared__ float qs[4 * CD];
    __shared__ float redk[16];
    for (int i = threadIdx.x; i < 4 * CD; i += 256) qs[i] = q[b * 4 * CD + i];
    __syncthreads();
    const float4* kp = (const float4*)(kk + ((size_t)b * NPTS + n) * CD);
    const float4* q0 = (const float4*)(qs);
    const float4* q1 = (const float4*)(qs + CD);
    const float4* q2 = (const float4*)(qs + 2 * CD);
    const float4* q3 = (const float4*)(qs + 3 * CD);
    float a0 = 0, a1 = 0, a2 = 0, a3 = 0;
    for (int c4 = 0; c4 < 64; ++c4) {
        float4 kv = kp[c4];
        float4 x;
        x = q0[c4]; a0 += kv.x * x.x + kv.y * x.y + kv.z * x.z + kv.w * x.w;
        x = q1[c4]; a1 += kv.x * x.x + kv.y * x.y + kv.z * x.z + kv.w * x.w;
        x = q2[c4]; a2 += kv.x * x.x + kv.y * x.y + kv.z * x.z + kv.w * x.w;
        x = q3[c4]; a3 += kv.x * x.x + kv.y * x.y + kv.z * x.z + kv.w * x.w;
    }
    const float scale = 0.0625f;   // 256^-0.5
    float l0 = scale * a0, l1 = scale * a1, l2 = scale * a2, l3 = scale * a3;
    float mx = fmaxf(fmaxf(l0, l1), fmaxf(l2, l3));
    float e0 = expf(l0 - mx), e1 = expf(l1 - mx), e2 = expf(l2 - mx), e3 = expf(l3 - mx);
    float inv = 1.0f / (e0 + e1 + e2 + e3);
    e0 *= inv; e1 *= inv; e2 *= inv; e3 *= inv;
    attn[((size_t)b * 4 + 0) * NPTS + n] = e0;
    attn[((size_t)b * 4 + 1) * NPTS + n] = e1;
    attn[((size_t)b * 4 + 2) * NPTS + n] = e2;
    attn[((size_t)b * 4 + 3) * NPTS + n] = e3;
    if (out_attn) {
        float* o = out_attn + ((size_t)b * NPTS + n) * 4;
        o[0] = e0; o[1] = e1; o[2] = e2; o[3] = e3;
    }
    float as[4] = {e0, e1, e2, e3};
    #pragma unroll
    for (int k = 0; k < 4; ++k) {
        float v = as[k];
        #pragma unroll
        for (int o = 32; o; o >>= 1) v += __shfl_down(v, o);
        if ((threadIdx.x & 63) == 0) redk[(threadIdx.x >> 6) * 4 + k] = v;
    }
    __syncthreads();
    if (threadIdx.x < 4) {
        float s = redk[threadIdx.x] + redk[4 + threadIdx.x] + redk[8 + threadIdx.x] + redk[12 + threadIdx.x];
        atomicAdd(&asum[b * 4 + threadIdx.x], s);
    }
}

// partial sums of attn*vv over 256-point chunks
__global__ __launch_bounds__(256) void updp_kernel(const float* __restrict__ attn,
                                                   const float* __restrict__ vv,
                                                   float* __restrict__ updp) {
    int row = blockIdx.x >> 4, chunk = blockIdx.x & 15;
    int b = row >> 2;
    int d = threadIdx.x;
    const float* arow = attn + (size_t)row * NPTS + chunk * 256;
    const float* vb = vv + ((size_t)b * NPTS + chunk * 256) * CD;
    float acc = 0.0f;
    for (int n = 0; n < 256; ++n) acc += arow[n] * vb[(size_t)n * CD + d];
    updp[((size_t)row * 16 + chunk) * CD + d] = acc;
}

// GRU + LN_ff + MLP residual, one block per row (b,k)
__global__ __launch_bounds__(256) void gru_mlp_kernel(const float* __restrict__ updp,
                                                      const float* __restrict__ asum,
                                                      float* __restrict__ slots,
                                                      const float* __restrict__ W_ih,
                                                      const float* __restrict__ W_hh,
                                                      const float* __restrict__ b_ih,
                                                      const float* __restrict__ b_hh,
                                                      const float* __restrict__ g_ff,
                                                      const float* __restrict__ b_ff,
                                                      const float* __restrict__ Wm1,
                                                      const float* __restrict__ bm1,
                                                      const float* __restrict__ Wm2,
                                                      const float* __restrict__ bm2) {
    int row = blockIdx.x;
    int d = threadIdx.x;
    __shared__ float su[CD], sp[CD], sh[CD];
    __shared__ float red[4];
    float f = 1.0f / (asum[row] + 1e-8f);
    float u = 0.0f;
    for (int p = 0; p < 16; ++p) u += updp[((size_t)row * 16 + p) * CD + d];
    u *= f;
    float prev = slots[row * CD + d];
    su[d] = u; sp[d] = prev;
    __syncthreads();
    float gir = b_ih[d], giz = b_ih[CD + d], gin = b_ih[2 * CD + d];
    float ghr = b_hh[d], ghz = b_hh[CD + d], ghn = b_hh[2 * CD + d];
    for (int c = 0; c < CD; ++c) {
        float uc = su[c], pc = sp[c];
        const float* wi = W_ih + c * 3 * CD;
        const float* wh = W_hh + c * 3 * CD;
        gir += uc * wi[d]; giz += uc * wi[CD + d]; gin += uc * wi[2 * CD + d];
        ghr += pc * wh[d]; ghz += pc * wh[CD + d]; ghn += pc * wh[2 * CD + d];
    }
    float r = 1.0f / (1.0f + expf(-(gir + ghr)));
    float z = 1.0f / (1.0f + expf(-(giz + ghz)));
    float nn = tanhf(gin + r * ghn);
    float sNew = (1.0f - z) * nn + z * prev;
    float s = block_sum256(sNew, red);
    float mean = s * (1.0f / 256.0f);
    float s2 = block_sum256(sNew * sNew, red);
    float var = s2 * (1.0f / 256.0f) - mean * mean;
    float h = (sNew - mean) * rsqrtf(var + 1e-5f) * g_ff[d] + b_ff[d];
    __syncthreads();
    sh[d] = h;
    __syncthreads();
    float y = bm1[d];
    {
        const float4* hp = (const float4*)sh;
        for (int c4 = 0; c4 < 64; ++c4) {
            float4 x = hp[c4];
            int cb = c4 * 4;
            y += x.x * Wm1[cb * CD + d] + x.y * Wm1[(cb + 1) * CD + d]
               + x.z * Wm1[(cb + 2) * CD + d] + x.w * Wm1[(cb + 3) * CD + d];
        }
    }
    y = fmaxf(y, 0.0f);
    __syncthreads();
    sh[d] = y;
    __syncthreads();
    float o = bm2[d];
    {
        const float4* hp = (const float4*)sh;
        for (int c4 = 0; c4 < 64; ++c4) {
            float4 x = hp[c4];
            int cb = c4 * 4;
            o += x.x * Wm2[cb * CD + d] + x.y * Wm2[(cb + 1) * CD + d]
               + x.z * Wm2[(cb + 2) * CD + d] + x.w * Wm2[(cb + 3) * CD + d];
        }
    }
    slots[row * CD + d] = sNew + o;
}

// recon head, loop-interchanged: weights read once, 16 rows accumulated inner.
__global__ __launch_bounds__(320) void recon_kernel(const float* __restrict__ slots,
                                                    const float* __restrict__ Wr1, const float* __restrict__ br1,
                                                    const float* __restrict__ g1, const float* __restrict__ be1,
                                                    const float* __restrict__ Wr2, const float* __restrict__ br2,
                                                    const float* __restrict__ g2, const float* __restrict__ be2,
                                                    const float* __restrict__ Wr3, const float* __restrict__ br3,
                                                    float* __restrict__ spts) {
    __shared__ float sl[16 * CD];
    __shared__ float h1[16 * CD];
    __shared__ float h2[16 * CD];
    int d = threadIdx.x;
    if (d < CD) for (int r = 0; r < 16; ++r) sl[r * CD + d] = slots[r * CD + d];
    __syncthreads();
    if (d < CD) {
        float t[16];
        #pragma unroll
        for (int r = 0; r < 16; ++r) t[r] = br1[d];
        for (int c4 = 0; c4 < 64; ++c4) {
            int cb = c4 * 4;
            float w0 = Wr1[cb * CD + d], w1 = Wr1[(cb + 1) * CD + d];
            float w2 = Wr1[(cb + 2) * CD + d], w3 = Wr1[(cb + 3) * CD + d];
            #pragma unroll
            for (int r = 0; r < 16; ++r) {
                float4 x = *(const float4*)(sl + r * CD + cb);
                t[r] += x.x * w0 + x.y * w1 + x.z * w2 + x.w * w3;
            }
        }
        float mean = 0.0f;
        for (int r = 0; r < 16; ++r) mean += t[r];
        mean *= (1.0f / 16.0f);
        float var = 0.0f;
        for (int r = 0; r < 16; ++r) { float dd = t[r] - mean; var += dd * dd; }
        var *= (1.0f / 16.0f);
        float inv = rsqrtf(var + 1e-5f);
        for (int r = 0; r < 16; ++r)
            h1[r * CD + d] = fmaxf(0.0f, (t[r] - mean) * inv * g1[d] + be1[d]);
    }
    __syncthreads();
    if (d < CD) {
        float t[16];
        #pragma unroll
        for (int r = 0; r < 16; ++r) t[r] = br2[d];
        for (int c4 = 0; c4 < 64; ++c4) {
            int cb = c4 * 4;
            float w0 = Wr2[cb * CD + d], w1 = Wr2[(cb + 1) * CD + d];
            float w2 = Wr2[(cb + 2) * CD + d], w3 = Wr2[(cb + 3) * CD + d];
            #pragma unroll
            for (int r = 0; r < 16; ++r) {
                float4 x = *(const float4*)(h1 + r * CD + cb);
                t[r] += x.x * w0 + x.y * w1 + x.z * w2 + x.w * w3;
            }
        }
        float mean = 0.0f;
        for (int r = 0; r < 16; ++r) mean += t[r];
        mean *= (1.0f / 16.0f);
        float var = 0.0f;
        for (int r = 0; r < 16; ++r) { float dd = t[r] - mean; var += dd * dd; }
        var *= (1.0f / 16.0f);
        float inv = rsqrtf(var + 1e-5f);
        for (int r = 0; r < 16; ++r)
            h2[r * CD + d] = fmaxf(0.0f, (t[r] - mean) * inv * g2[d] + be2[d]);
    }
    __syncthreads();
    if (d < 288) {
        float t[16];
        #pragma unroll
        for (int r = 0; r < 16; ++r) t[r] = br3[d];
        for (int c4 = 0; c4 < 64; ++c4) {
            int cb = c4 * 4;
            float w0 = Wr3[cb * 288 + d], w1 = Wr3[(cb + 1) * 288 + d];
            float w2 = Wr3[(cb + 2) * 288 + d], w3 = Wr3[(cb + 3) * 288 + d];
            #pragma unroll
            for (int r = 0; r < 16; ++r) {
                float4 x = *(const float4*)(h2 + r * CD + cb);
                t[r] += x.x * w0 + x.y * w1 + x.z * w2 + x.w * w3;
            }
        }
        for (int r = 0; r < 16; ++r) spts[r * 288 + d] = t[r];
    }
}

// farthest point sampling: one block per batch, 384 pts, 128 selections
__global__ __launch_bounds__(128) void fps_kernel(const float* __restrict__ spts,
                                                  int* __restrict__ fidx,
                                                  float* __restrict__ lacc) {
    int b = blockIdx.x;
    int t = threadIdx.x;
    const float* pts = spts + (size_t)b * 384 * 3;
    __shared__ float rv[2];
    __shared__ int ri[2];
    __shared__ int bidx;
    int* out = fidx + b * 128;
    if (t == 0) out[0] = 0;
    if (b == 0 && t == 0) lacc[0] = 0.0f;
    float x0 = pts[t * 3], y0 = pts[t * 3 + 1], z0 = pts[t * 3 + 2];
    float x1 = pts[(t + 128) * 3], y1 = pts[(t + 128) * 3 + 1], z1 = pts[(t + 128) * 3 + 2];
    float x2 = pts[(t + 256) * 3], y2 = pts[(t + 256) * 3 + 1], z2 = pts[(t + 256) * 3 + 2];
    float d0 = 1e10f, d1 = 1e10f, d2 = 1e10f;
    float lx = pts[0], ly = pts[1], lz = pts[2];
    for (int s = 1; s < 128; ++s) {
        float dx, dy, dz;
        dx = x0 - lx; dy = y0 - ly; dz = z0 - lz; d0 = fminf(d0, dx * dx + dy * dy + dz * dz);
        dx = x1 - lx; dy = y1 - ly; dz = z1 - lz; d1 = fminf(d1, dx * dx + dy * dy + dz * dz);
        dx = x2 - lx; dy = y2 - ly; dz = z2 - lz; d2 = fminf(d2, dx * dx + dy * dy + dz * dz);
        float bv = d0; int bi = t;
        if (d1 > bv) { bv = d1; bi = t + 128; }
        if (d2 > bv) { bv = d2; bi = t + 256; }
        #pragma unroll
        for (int o = 32; o; o >>= 1) {
            float ov = __shfl_down(bv, o); int oi = __shfl_down(bi, o);
            if (ov > bv || (ov == bv && oi < bi)) { bv = ov; bi = oi; }
        }
        int lane = t & 63, w = t >> 6;
        if (lane == 0) { rv[w] = bv; ri[w] = bi; }
        __syncthreads();
        if (t == 0) {
            float fv = rv[0]; int fi = ri[0];
            if (rv[1] > fv || (rv[1] == fv && ri[1] < fi)) { fv = rv[1]; fi = ri[1]; }
            out[s] = fi;
            bidx = fi;
        }
        __syncthreads();
        int ni = bidx;
        lx = pts[ni * 3]; ly = pts[ni * 3 + 1]; lz = pts[ni * 3 + 2];
    }
}

// chamfer(ds, xyz), accumulate (mean d1 + mean d2) per batch
__global__ __launch_bounds__(256) void chamfer_kernel(const float* __restrict__ spts,
                                                      const int* __restrict__ fidx,
                                                      const float* __restrict__ xyz,
                                                      float* __restrict__ lacc) {
    int b = blockIdx.x;
    int t = threadIdx.x;
    __shared__ float ds[128 * 3];
    __shared__ float red[4];
    const float* pts = spts + (size_t)b * 384 * 3;
    if (t < 128) {
        int j = fidx[b * 128 + t];
        ds[t * 3] = pts[j * 3]; ds[t * 3 + 1] = pts[j * 3 + 1]; ds[t * 3 + 2] = pts[j * 3 + 2];
    }
    __syncthreads();
    const float* xb = xyz + (size_t)b * NPTS * 3;
    float sum2 = 0.0f;
    for (int n = t; n < NPTS; n += 256) {
        float px = xb[n * 3], py = xb[n * 3 + 1], pz = xb[n * 3 + 2];
        float mn = 1e30f;
        for (int j = 0; j < 128; ++j) {
            float dx = ds[j * 3] - px, dy = ds[j * 3 + 1] - py, dz = ds[j * 3 + 2] - pz;
            mn = fminf(mn, dx * dx + dy * dy + dz * dz);
        }
        sum2 += mn;
    }
    float sum1 = 0.0f;
    if (t < 128) {
        float px = ds[t * 3], py = ds[t * 3 + 1], pz = ds[t * 3 + 2];
        float mn = 1e30f;
        for (int n = 0; n < NPTS; ++n) {
            float dx = xb[n * 3] - px, dy = xb[n * 3 + 1] - py, dz = xb[n * 3 + 2] - pz;
            mn = fminf(mn, dx * dx + dy * dy + dz * dz);
        }
        sum1 = mn;
    }
    float total = block_sum256(sum2 * (1.0f / 4096.0f) + sum1 * (1.0f / 128.0f), red);
    if (t == 0) atomicAdd(lacc, total);
}

// loss scalar only (attn written by last attn_kernel)
__global__ void finalize_kernel(const float* __restrict__ lacc, float* __restrict__ out) {
    if (threadIdx.x == 0) out[0] = lacc[0] * 0.25f;
}

// ---------------- launch ----------------

extern "C" void kernel_launch(void* const* d_in, const int* in_sizes, int n_in,
                              void* d_out, int out_size, void* d_ws, size_t ws_size,
                              hipStream_t stream) {
    (void)in_sizes; (void)n_in; (void)out_size; (void)ws_size;
    const float* x    = (const float*)d_in[0];
    const float* W1   = (const float*)d_in[2];
    const float* b1   = (const float*)d_in[3];
    const float* W2   = (const float*)d_in[4];
    const float* b2   = (const float*)d_in[5];
    const float* mu   = (const float*)d_in[6];
    const float* sg   = (const float*)d_in[7];
    const float* g_in = (const float*)d_in[8];
    const float* b_in = (const float*)d_in[9];
    const float* g_sl = (const float*)d_in[10];
    const float* b_sl = (const float*)d_in[11];
    const float* g_ff = (const float*)d_in[12];
    const float* b_ff = (const float*)d_in[13];
    const float* Wq   = (const float*)d_in[14];
    const float* Wk   = (const float*)d_in[15];
    const float* Wv   = (const float*)d_in[16];
    const float* W_ih = (const float*)d_in[17];
    const float* W_hh = (const float*)d_in[18];
    const float* b_ih = (const float*)d_in[19];
    const float* b_hh = (const float*)d_in[20];
    const float* Wm1  = (const float*)d_in[21];
    const float* bm1  = (const float*)d_in[22];
    const float* Wm2  = (const float*)d_in[23];
    const float* bm2  = (const float*)d_in[24];
    const float* Wr1  = (const float*)d_in[25];
    const float* br1  = (const float*)d_in[26];
    const float* g1   = (const float*)d_in[27];
    const float* be1  = (const float*)d_in[28];
    const float* Wr2  = (const float*)d_in[29];
    const float* br2  = (const float*)d_in[30];
    const float* g2   = (const float*)d_in[31];
    const float* be2  = (const float*)d_in[32];
    const float* Wr3  = (const float*)d_in[33];
    const float* br3  = (const float*)d_in[34];

    float* ws    = (float*)d_ws;
    float* xyz   = ws;                               // 49152 f
    float* xyzw  = xyz + 49152;                      // 65536 f (float4 [B*N])
    int*   knn   = (int*)(xyzw + 65536);             // 524288 i
    _Float16* f1h = (_Float16*)(knn + 524288);       // 2097152 h
    _Float16* W2t = (_Float16*)((float*)f1h + 1048576); // 40960 h
    float* inp   = (float*)W2t + 20480;              // 4194304 f
    float* kkb   = inp + 4194304;                    // 4194304 f
    float* vvb   = kkb + 4194304;                    // 4194304 f
    float* slots = vvb + 4194304;                    // 4096 f
    float* qb    = slots + 4096;                     // 4096 f
    float* attn  = qb + 4096;                        // 65536 f
    float* asum  = attn + 65536;                     // 16 f
    float* updp  = asum + 16;                        // 65536 f
    float* spts  = updp + 65536;                     // 4608 f
    int*   fidx  = (int*)(spts + 4608);              // 512 i
    float* lacc  = (float*)(fidx + 512);             // 1 f

    float* out = (float*)d_out;

    prep_kernel<<<64, 256, 0, stream>>>(x, xyz, (float4*)xyzw);
    slots_init_kernel<<<8, 256, 0, stream>>>(mu, sg, slots);
    knn_kernel<<<NBATCH * NPTS / 4, 256, 0, stream>>>((const float4*)xyzw, knn);
    conv1_kernel<<<NBATCH * NPTS, 128, 0, stream>>>(xyz, knn, W1, b1, f1h);
    w2t_kernel<<<256, 160, 0, stream>>>(W2, W2t);
    conv2_mfma_kernel<<<NBATCH * NPTS / 2, 256, 0, stream>>>(xyz, f1h, knn, W2t, b2, g_in, b_in, inp);
    kv_kernel<<<NBATCH * NPTS / 16, 256, 0, stream>>>(inp, Wk, Wv, kkb, vvb);

    for (int it = 0; it < 3; ++it) {
        slotq_kernel<<<16, 256, 0, stream>>>(slots, g_sl, b_sl, Wq, qb, asum);
        attn_kernel<<<64, 256, 0, stream>>>(qb, kkb, attn, asum,
                                            (it == 2) ? (out + 1) : (float*)nullptr);
        updp_kernel<<<256, 256, 0, stream>>>(attn, vvb, updp);
        gru_mlp_kernel<<<16, 256, 0, stream>>>(updp, asum, slots, W_ih, W_hh, b_ih, b_hh,
                                               g_ff, b_ff, Wm1, bm1, Wm2, bm2);
    }

    recon_kernel<<<1, 320, 0, stream>>>(slots, Wr1, br1, g1, be1, Wr2, br2, g2, be2, Wr3, br3, spts);
    fps_kernel<<<4, 128, 0, stream>>>(spts, fidx, lacc);
    chamfer_kernel<<<4, 256, 0, stream>>>(spts, fidx, xyz, lacc);
    finalize_kernel<<<1, 64, 0, stream>>>(lacc, out);
}

// Round 5
// 1410.697 us; speedup vs baseline: 1.6341x; 1.0203x over previous
//
#include <hip/hip_runtime.h>

#define NBATCH 4
#define NPTS   4096
#define KNNK   32
#define C1D    128
#define CD     256
#define KPAD   160   // conv2 K padded (131 -> 160, 5 mfma K-steps of 32)
#define ASTR   168   // LDS A row stride in halves

typedef _Float16 v8h __attribute__((ext_vector_type(8)));
typedef float    v4f __attribute__((ext_vector_type(4)));

// ---------------- helpers ----------------

__device__ __forceinline__ float block_sum256(float v, float* red) {
    #pragma unroll
    for (int o = 32; o; o >>= 1) v += __shfl_down(v, o);
    __syncthreads();
    if ((threadIdx.x & 63) == 0) red[threadIdx.x >> 6] = v;
    __syncthreads();
    return red[0] + red[1] + red[2] + red[3];
}

__device__ __forceinline__ unsigned rotl32(unsigned x, unsigned r) {
    return (x << r) | (x >> (32u - r));
}

// XLA f32 erf_inv (Giles polynomial)
__device__ float erfinv_f(float x) {
    float w = -log1pf(-x * x);
    float p;
    if (w < 5.0f) {
        w -= 2.5f;
        p = 2.81022636e-08f;
        p = fmaf(p, w, 3.43273939e-07f);
        p = fmaf(p, w, -3.5233877e-06f);
        p = fmaf(p, w, -4.39150654e-06f);
        p = fmaf(p, w, 0.00021858087f);
        p = fmaf(p, w, -0.00125372503f);
        p = fmaf(p, w, -0.00417768164f);
        p = fmaf(p, w, 0.246640727f);
        p = fmaf(p, w, 1.50140941f);
    } else {
        w = sqrtf(w) - 3.0f;
        p = -0.000200214257f;
        p = fmaf(p, w, 0.000100950558f);
        p = fmaf(p, w, 0.00134934322f);
        p = fmaf(p, w, -0.00367342844f);
        p = fmaf(p, w, 0.00573950773f);
        p = fmaf(p, w, -0.0076224613f);
        p = fmaf(p, w, 0.00943887047f);
        p = fmaf(p, w, 1.00167406f);
        p = fmaf(p, w, 2.83297682f);
    }
    return p * x;
}

__device__ __forceinline__ float bits_to_normal(unsigned bits) {
    unsigned fb = (bits >> 9) | 0x3f800000u;
    float f = __uint_as_float(fb) - 1.0f;
    const float lo = -0.99999994f;           // nextafterf(-1,0)
    float u = fmaf(f, 2.0f, lo);
    u = fmaxf(u, lo);
    return 1.41421356237f * erfinv_f(u);
}

// ---------------- kernels ----------------

// x [B,3,N] -> xyz [B,N,3], xyzw [B,N] (x,y,z,sq)
__global__ void prep_kernel(const float* __restrict__ x, float* __restrict__ xyz,
                            float4* __restrict__ xyzw) {
    int gid = blockIdx.x * 256 + threadIdx.x;
    if (gid >= NBATCH * NPTS) return;
    int b = gid >> 12, n = gid & (NPTS - 1);
    float a0 = x[(b * 3 + 0) * NPTS + n];
    float a1 = x[(b * 3 + 1) * NPTS + n];
    float a2 = x[(b * 3 + 2) * NPTS + n];
    xyz[gid * 3 + 0] = a0; xyz[gid * 3 + 1] = a1; xyz[gid * 3 + 2] = a2;
    float sq = a0 * a0 + a1 * a1 + a2 * a2;
    xyzw[gid] = make_float4(a0, a1, a2, sq);
}

// JAX threefry2x32, key(42) -> slots = mu + sigma * normal
__global__ void slots_init_kernel(const float* __restrict__ mu, const float* __restrict__ sg,
                                  float* __restrict__ slots) {
    int j = blockIdx.x * 256 + threadIdx.x;
    if (j >= 2048) return;
    unsigned ks0 = 0u, ks1 = 42u, ks2 = 0u ^ 42u ^ 0x1BD11BDAu;
    unsigned x0 = (unsigned)j + ks0;
    unsigned x1 = (unsigned)(j + 2048) + ks1;
    #define RND(r) { x0 += x1; x1 = rotl32(x1, r); x1 ^= x0; }
    RND(13u) RND(15u) RND(26u) RND(6u);  x0 += ks1; x1 += ks2 + 1u;
    RND(17u) RND(29u) RND(16u) RND(24u); x0 += ks2; x1 += ks0 + 2u;
    RND(13u) RND(15u) RND(26u) RND(6u);  x0 += ks0; x1 += ks1 + 3u;
    RND(17u) RND(29u) RND(16u) RND(24u); x0 += ks1; x1 += ks2 + 4u;
    RND(13u) RND(15u) RND(26u) RND(6u);  x0 += ks2; x1 += ks0 + 5u;
    #undef RND
    int c0 = j & 255, c1 = (j + 2048) & 255;
    slots[j]        = mu[c0] + sg[c0] * bits_to_normal(x0);
    slots[j + 2048] = mu[c1] + sg[c1] * bits_to_normal(x1);
}

// KNN: one wave per point, no barriers; 64 register-cached dists per lane.
__global__ __launch_bounds__(256) void knn_kernel(const float4* __restrict__ xyzw,
                                                  int* __restrict__ knn_idx) {
    int wid = threadIdx.x >> 6, lane = threadIdx.x & 63;
    int pid = blockIdx.x * 4 + wid;
    int b = pid >> 12, n = pid & (NPTS - 1);
    const float4* xb = xyzw + (size_t)b * NPTS;
    float4 p = xb[n];
    float d0[32], d1[32];
    #pragma unroll
    for (int i = 0; i < 32; ++i) {
        float4 c = xb[i * 64 + lane];
        float dot = p.x * c.x + p.y * c.y + p.z * c.z;
        d0[i] = p.w + c.w - 2.0f * dot;
    }
    #pragma unroll
    for (int i = 0; i < 32; ++i) {
        float4 c = xb[(i + 32) * 64 + lane];
        float dot = p.x * c.x + p.y * c.y + p.z * c.z;
        d1[i] = p.w + c.w - 2.0f * dot;
    }
    float mv0 = 1e30f; int mi0 = 0;
    #pragma unroll
    for (int i = 0; i < 32; ++i)
        if (d0[i] < mv0) { mv0 = d0[i]; mi0 = i * 64 + lane; }
    float mv1 = 1e30f; int mi1 = 0;
    #pragma unroll
    for (int i = 0; i < 32; ++i)
        if (d1[i] < mv1) { mv1 = d1[i]; mi1 = (i + 32) * 64 + lane; }

    int* out = knn_idx + (size_t)pid * KNNK;
    #pragma unroll 1
    for (int s = 0; s < KNNK; ++s) {
        float bv = mv0; int bi = mi0;
        if (mv1 < bv) { bv = mv1; bi = mi1; }
        #pragma unroll
        for (int o = 32; o; o >>= 1) {
            float ov = __shfl_down(bv, o); int oi = __shfl_down(bi, o);
            if (ov < bv || (ov == bv && oi < bi)) { bv = ov; bi = oi; }
        }
        int fi = __shfl(bi, 0);
        if (lane == 0) out[s] = fi;
        if ((fi & 63) == lane) {
            int slot = fi >> 6;
            if (slot < 32) {
                #pragma unroll
                for (int i = 0; i < 32; ++i)
                    if (i == slot) d0[i] = 1e30f;
                mv0 = 1e30f; mi0 = 0;
                #pragma unroll
                for (int i = 0; i < 32; ++i)
                    if (d0[i] < mv0) { mv0 = d0[i]; mi0 = i * 64 + lane; }
            } else {
                int s1 = slot - 32;
                #pragma unroll
                for (int i = 0; i < 32; ++i)
                    if (i == s1) d1[i] = 1e30f;
                mv1 = 1e30f; mi1 = 0;
                #pragma unroll
                for (int i = 0; i < 32; ++i)
                    if (d1[i] < mv1) { mv1 = d1[i]; mi1 = (i + 32) * 64 + lane; }
            }
        }
    }
}

// conv1 -> fp16 features for the MFMA conv2
__global__ __launch_bounds__(128) void conv1_kernel(const float* __restrict__ xyz,
                                                    const int* __restrict__ knn_idx,
                                                    const float* __restrict__ W1,
                                                    const float* __restrict__ b1,
                                                    _Float16* __restrict__ f1h) {
    int pid = blockIdx.x;
    int b = pid >> 12, n = pid & (NPTS - 1);
    int d = threadIdx.x;
    const float* xb = xyz + (size_t)b * NPTS * 3;
    float w0 = W1[d], wx = W1[C1D + d], wy = W1[2 * C1D + d], wz = W1[3 * C1D + d];
    float bb = b1[d];
    float px = xb[n * 3], py = xb[n * 3 + 1], pz = xb[n * 3 + 2];
    const int* idx = knn_idx + (size_t)pid * KNNK;
    float m = -1e30f;
    for (int k = 0; k < KNNK; ++k) {
        int j = idx[k];
        float rx = xb[j * 3] - px, ry = xb[j * 3 + 1] - py, rz = xb[j * 3 + 2] - pz;
        float v = w0 + bb + rx * wx + ry * wy + rz * wz;
        m = fmaxf(m, v);
    }
    f1h[(size_t)pid * C1D + d] = (_Float16)fmaxf(m, 0.0f);
}

// W2 [131x256 fp32] -> W2t [256][160] fp16 (transposed, zero-padded)
__global__ void w2t_kernel(const float* __restrict__ W2, _Float16* __restrict__ W2t) {
    int n = blockIdx.x;          // 0..255
    int k = threadIdx.x;         // 0..159
    W2t[n * KPAD + k] = (k < 131) ? (_Float16)W2[k * CD + n] : (_Float16)0.0f;
}

// conv2 via MFMA f16 (fp32 accumulate) + fused bias/relu/max-over-k/LayerNorm.
__global__ __launch_bounds__(256) void conv2_mfma_kernel(const float* __restrict__ xyz,
                                                         const _Float16* __restrict__ f1h,
                                                         const int* __restrict__ knn_idx,
                                                         const _Float16* __restrict__ W2t,
                                                         const float* __restrict__ b2,
                                                         const float* __restrict__ g_in,
                                                         const float* __restrict__ b_in,
                                                         float* __restrict__ inp) {
    __shared__ _Float16 A[64 * ASTR];
    __shared__ float colmax[2 * CD];
    __shared__ float red[4];
    int pid2 = blockIdx.x;
    int gp0 = pid2 * 2;
    int b = gp0 >> 12, n0 = gp0 & (NPTS - 1);
    int tid = threadIdx.x;
    const int* idx = knn_idx + (size_t)pid2 * 64;   // [2][32]
    const float* xb = xyz + (size_t)b * NPTS * 3;

    {
        int r = tid & 63, seg = tid >> 6;
        int j = idx[r];
        const uint4* s4 = (const uint4*)(f1h + ((size_t)b * NPTS + j) * C1D);
        uint4* d4 = (uint4*)&A[r * ASTR];
        #pragma unroll
        for (int i = 0; i < 4; ++i) d4[seg * 4 + i] = s4[seg * 4 + i];
        unsigned* z = (unsigned*)&A[r * ASTR + 128];
        for (int i = seg; i < 20; i += 4) z[i] = 0u;
        int np_ = (r < 32) ? n0 : (n0 + 1);
        if (seg == 0) {
            A[r * ASTR + 128] = (_Float16)(xb[j * 3 + 0] - xb[np_ * 3 + 0]);
            A[r * ASTR + 129] = (_Float16)(xb[j * 3 + 1] - xb[np_ * 3 + 1]);
        } else if (seg == 1) {
            A[r * ASTR + 130] = (_Float16)(xb[j * 3 + 2] - xb[np_ * 3 + 2]);
        }
    }
    __syncthreads();

    int w = tid >> 6, lane = tid & 63, quad = lane >> 4, lr = lane & 15;
    v4f acc[4][4];
    #pragma unroll
    for (int rt = 0; rt < 4; ++rt)
        #pragma unroll
        for (int ct = 0; ct < 4; ++ct)
            acc[rt][ct] = (v4f){0.0f, 0.0f, 0.0f, 0.0f};

    #pragma unroll
    for (int kk = 0; kk < KPAD; kk += 32) {
        v8h af[4], bf[4];
        #pragma unroll
        for (int rt = 0; rt < 4; ++rt)
            af[rt] = *(const v8h*)&A[(rt * 16 + lr) * ASTR + kk + quad * 8];
        #pragma unroll
        for (int ct = 0; ct < 4; ++ct) {
            int ncol = w * 64 + ct * 16 + lr;
            bf[ct] = *(const v8h*)(W2t + (size_t)ncol * KPAD + kk + quad * 8);
        }
        #pragma unroll
        for (int rt = 0; rt < 4; ++rt)
            #pragma unroll
            for (int ct = 0; ct < 4; ++ct)
                acc[rt][ct] = __builtin_amdgcn_mfma_f32_16x16x32_f16(af[rt], bf[ct], acc[rt][ct], 0, 0, 0);
    }

    #pragma unroll
    for (int ct = 0; ct < 4; ++ct) {
        float tm[4];
        #pragma unroll
        for (int rt = 0; rt < 4; ++rt) {
            v4f a = acc[rt][ct];
            float v = fmaxf(fmaxf(a[0], a[1]), fmaxf(a[2], a[3]));
            v = fmaxf(v, __shfl_xor(v, 16));
            v = fmaxf(v, __shfl_xor(v, 32));
            tm[rt] = v;
        }
        float p0 = fmaxf(tm[0], tm[1]);
        float p1 = fmaxf(tm[2], tm[3]);
        if (quad == 0) {
            colmax[0 * CD + w * 64 + ct * 16 + lr] = p0;
            colmax[1 * CD + w * 64 + ct * 16 + lr] = p1;
        }
    }
    __syncthreads();

    int d = tid;
    #pragma unroll
    for (int p = 0; p < 2; ++p) {
        float v = fmaxf(colmax[p * CD + d] + b2[d], 0.0f);
        float s = block_sum256(v, red);
        float mean = s * (1.0f / 256.0f);
        float s2 = block_sum256(v * v, red);
        float var = s2 * (1.0f / 256.0f) - mean * mean;
        float iv = (v - mean) * rsqrtf(var + 1e-5f) * g_in[d] + b_in[d];
        inp[(size_t)(gp0 + p) * CD + d] = iv;
    }
}

// kk = inp @ Wk, vv = inp @ Wv ; 16 points per block
__global__ __launch_bounds__(256) void kv_kernel(const float* __restrict__ inp,
                                                 const float* __restrict__ Wk,
                                                 const float* __restrict__ Wv,
                                                 float* __restrict__ kk,
                                                 float* __restrict__ vv) {
    int base = blockIdx.x * 16;
    int d = threadIdx.x;
    __shared__ float t[CD * 16];    // t[c*16+p]
    for (int p = 0; p < 16; ++p) t[d * 16 + p] = inp[((size_t)base + p) * CD + d];
    __syncthreads();
    float ka[16], va[16];
    #pragma unroll
    for (int p = 0; p < 16; ++p) { ka[p] = 0.0f; va[p] = 0.0f; }
    for (int c = 0; c < CD; ++c) {
        float wk = Wk[c * CD + d], wv = Wv[c * CD + d];
        const float4* tp = (const float4*)&t[c * 16];
        #pragma unroll
        for (int q4 = 0; q4 < 4; ++q4) {
            float4 x = tp[q4];
            ka[q4 * 4 + 0] += x.x * wk; va[q4 * 4 + 0] += x.x * wv;
            ka[q4 * 4 + 1] += x.y * wk; va[q4 * 4 + 1] += x.y * wv;
            ka[q4 * 4 + 2] += x.z * wk; va[q4 * 4 + 2] += x.z * wv;
            ka[q4 * 4 + 3] += x.w * wk; va[q4 * 4 + 3] += x.w * wv;
        }
    }
    for (int p = 0; p < 16; ++p) {
        kk[((size_t)base + p) * CD + d] = ka[p];
        vv[((size_t)base + p) * CD + d] = va[p];
    }
}

// q = LN(slots) @ Wq, one block per row (b,k); block 0 zeroes attn_sum
__global__ __launch_bounds__(256) void slotq_kernel(const float* __restrict__ slots,
                                                    const float* __restrict__ g_sl,
                                                    const float* __restrict__ b_sl,
                                                    const float* __restrict__ Wq,
                                                    float* __restrict__ q,
                                                    float* __restrict__ asum) {
    int row = blockIdx.x;
    int d = threadIdx.x;
    __shared__ float sl[CD];
    __shared__ float red[4];
    float v = slots[row * CD + d];
    float s = block_sum256(v, red);
    float mean = s * (1.0f / 256.0f);
    float s2 = block_sum256(v * v, red);
    float var = s2 * (1.0f / 256.0f) - mean * mean;
    float ln = (v - mean) * rsqrtf(var + 1e-5f) * g_sl[d] + b_sl[d];
    sl[d] = ln;
    __syncthreads();
    float acc = 0.0f;
    const float4* sp = (const float4*)sl;
    for (int c4 = 0; c4 < 64; ++c4) {
        float4 x = sp[c4];
        int cb = c4 * 4;
        acc += x.x * Wq[cb * CD + d] + x.y * Wq[(cb + 1) * CD + d]
             + x.z * Wq[(cb + 2) * CD + d] + x.w * Wq[(cb + 3) * CD + d];
    }
    q[row * CD + d] = acc;
    if (row == 0 && d < 16) asum[d] = 0.0f;
}

// logits -> softmax over slots -> attn [B,4,N]; on last iter also writes out
__global__ __launch_bounds__(256) void attn_kernel(const float* __restrict__ q,
                                                   const float* __restrict__ kk,
                                                   float* __restrict__ attn,
                                                   float* __restrict__ asum,
                                                   float* __restrict__ out_attn) {
    int b = blockIdx.x >> 4;
    int nb = blockIdx.x & 15;
    int n = nb * 256 + threadIdx.x;
    __shared__ float qs[4 * CD];
    __shared__ float redk[16];
    for (int i = threadIdx.x; i < 4 * CD; i += 256) qs[i] = q[b * 4 * CD + i];
    __syncthreads();
    const float4* kp = (const float4*)(kk + ((size_t)b * NPTS + n) * CD);
    const float4* q0 = (const float4*)(qs);
    const float4* q1 = (const float4*)(qs + CD);
    const float4* q2 = (const float4*)(qs + 2 * CD);
    const float4* q3 = (const float4*)(qs + 3 * CD);
    float a0 = 0, a1 = 0, a2 = 0, a3 = 0;
    for (int c4 = 0; c4 < 64; ++c4) {
        float4 kv = kp[c4];
        float4 x;
        x = q0[c4]; a0 += kv.x * x.x + kv.y * x.y + kv.z * x.z + kv.w * x.w;
        x = q1[c4]; a1 += kv.x * x.x + kv.y * x.y + kv.z * x.z + kv.w * x.w;
        x = q2[c4]; a2 += kv.x * x.x + kv.y * x.y + kv.z * x.z + kv.w * x.w;
        x = q3[c4]; a3 += kv.x * x.x + kv.y * x.y + kv.z * x.z + kv.w * x.w;
    }
    const float scale = 0.0625f;   // 256^-0.5
    float l0 = scale * a0, l1 = scale * a1, l2 = scale * a2, l3 = scale * a3;
    float mx = fmaxf(fmaxf(l0, l1), fmaxf(l2, l3));
    float e0 = expf(l0 - mx), e1 = expf(l1 - mx), e2 = expf(l2 - mx), e3 = expf(l3 - mx);
    float inv = 1.0f / (e0 + e1 + e2 + e3);
    e0 *= inv; e1 *= inv; e2 *= inv; e3 *= inv;
    attn[((size_t)b * 4 + 0) * NPTS + n] = e0;
    attn[((size_t)b * 4 + 1) * NPTS + n] = e1;
    attn[((size_t)b * 4 + 2) * NPTS + n] = e2;
    attn[((size_t)b * 4 + 3) * NPTS + n] = e3;
    if (out_attn) {
        float* o = out_attn + ((size_t)b * NPTS + n) * 4;
        o[0] = e0; o[1] = e1; o[2] = e2; o[3] = e3;
    }
    float as[4] = {e0, e1, e2, e3};
    #pragma unroll
    for (int k = 0; k < 4; ++k) {
        float v = as[k];
        #pragma unroll
        for (int o = 32; o; o >>= 1) v += __shfl_down(v, o);
        if ((threadIdx.x & 63) == 0) redk[(threadIdx.x >> 6) * 4 + k] = v;
    }
    __syncthreads();
    if (threadIdx.x < 4) {
        float s = redk[threadIdx.x] + redk[4 + threadIdx.x] + redk[8 + threadIdx.x] + redk[12 + threadIdx.x];
        atomicAdd(&asum[b * 4 + threadIdx.x], s);
    }
}

// partial sums of attn*vv over 256-point chunks
__global__ __launch_bounds__(256) void updp_kernel(const float* __restrict__ attn,
                                                   const float* __restrict__ vv,
                                                   float* __restrict__ updp) {
    int row = blockIdx.x >> 4, chunk = blockIdx.x & 15;
    int b = row >> 2;
    int d = threadIdx.x;
    const float* arow = attn + (size_t)row * NPTS + chunk * 256;
    const float* vb = vv + ((size_t)b * NPTS + chunk * 256) * CD;
    float acc = 0.0f;
    for (int n = 0; n < 256; ++n) acc += arow[n] * vb[(size_t)n * CD + d];
    updp[((size_t)row * 16 + chunk) * CD + d] = acc;
}

// GRU + LN_ff + MLP residual, one block per row (b,k)
__global__ __launch_bounds__(256) void gru_mlp_kernel(const float* __restrict__ updp,
                                                      const float* __restrict__ asum,
                                                      float* __restrict__ slots,
                                                      const float* __restrict__ W_ih,
                                                      const float* __restrict__ W_hh,
                                                      const float* __restrict__ b_ih,
                                                      const float* __restrict__ b_hh,
                                                      const float* __restrict__ g_ff,
                                                      const float* __restrict__ b_ff,
                                                      const float* __restrict__ Wm1,
                                                      const float* __restrict__ bm1,
                                                      const float* __restrict__ Wm2,
                                                      const float* __restrict__ bm2) {
    int row = blockIdx.x;
    int d = threadIdx.x;
    __shared__ float su[CD], sp[CD], sh[CD];
    __shared__ float red[4];
    float f = 1.0f / (asum[row] + 1e-8f);
    float u = 0.0f;
    for (int p = 0; p < 16; ++p) u += updp[((size_t)row * 16 + p) * CD + d];
    u *= f;
    float prev = slots[row * CD + d];
    su[d] = u; sp[d] = prev;
    __syncthreads();
    float gir = b_ih[d], giz = b_ih[CD + d], gin = b_ih[2 * CD + d];
    float ghr = b_hh[d], ghz = b_hh[CD + d], ghn = b_hh[2 * CD + d];
    for (int c = 0; c < CD; ++c) {
        float uc = su[c], pc = sp[c];
        const float* wi = W_ih + c * 3 * CD;
        const float* wh = W_hh + c * 3 * CD;
        gir += uc * wi[d]; giz += uc * wi[CD + d]; gin += uc * wi[2 * CD + d];
        ghr += pc * wh[d]; ghz += pc * wh[CD + d]; ghn += pc * wh[2 * CD + d];
    }
    float r = 1.0f / (1.0f + expf(-(gir + ghr)));
    float z = 1.0f / (1.0f + expf(-(giz + ghz)));
    float nn = tanhf(gin + r * ghn);
    float sNew = (1.0f - z) * nn + z * prev;
    float s = block_sum256(sNew, red);
    float mean = s * (1.0f / 256.0f);
    float s2 = block_sum256(sNew * sNew, red);
    float var = s2 * (1.0f / 256.0f) - mean * mean;
    float h = (sNew - mean) * rsqrtf(var + 1e-5f) * g_ff[d] + b_ff[d];
    __syncthreads();
    sh[d] = h;
    __syncthreads();
    float y = bm1[d];
    {
        const float4* hp = (const float4*)sh;
        for (int c4 = 0; c4 < 64; ++c4) {
            float4 x = hp[c4];
            int cb = c4 * 4;
            y += x.x * Wm1[cb * CD + d] + x.y * Wm1[(cb + 1) * CD + d]
               + x.z * Wm1[(cb + 2) * CD + d] + x.w * Wm1[(cb + 3) * CD + d];
        }
    }
    y = fmaxf(y, 0.0f);
    __syncthreads();
    sh[d] = y;
    __syncthreads();
    float o = bm2[d];
    {
        const float4* hp = (const float4*)sh;
        for (int c4 = 0; c4 < 64; ++c4) {
            float4 x = hp[c4];
            int cb = c4 * 4;
            o += x.x * Wm2[cb * CD + d] + x.y * Wm2[(cb + 1) * CD + d]
               + x.z * Wm2[(cb + 2) * CD + d] + x.w * Wm2[(cb + 3) * CD + d];
        }
    }
    slots[row * CD + d] = sNew + o;
}

// recon head, loop-interchanged: weights read once, 16 rows accumulated inner.
__global__ __launch_bounds__(320) void recon_kernel(const float* __restrict__ slots,
                                                    const float* __restrict__ Wr1, const float* __restrict__ br1,
                                                    const float* __restrict__ g1, const float* __restrict__ be1,
                                                    const float* __restrict__ Wr2, const float* __restrict__ br2,
                                                    const float* __restrict__ g2, const float* __restrict__ be2,
                                                    const float* __restrict__ Wr3, const float* __restrict__ br3,
                                                    float* __restrict__ spts) {
    __shared__ float sl[16 * CD];
    __shared__ float h1[16 * CD];
    __shared__ float h2[16 * CD];
    int d = threadIdx.x;
    if (d < CD) for (int r = 0; r < 16; ++r) sl[r * CD + d] = slots[r * CD + d];
    __syncthreads();
    if (d < CD) {
        float t[16];
        #pragma unroll
        for (int r = 0; r < 16; ++r) t[r] = br1[d];
        for (int c4 = 0; c4 < 64; ++c4) {
            int cb = c4 * 4;
            float w0 = Wr1[cb * CD + d], w1 = Wr1[(cb + 1) * CD + d];
            float w2 = Wr1[(cb + 2) * CD + d], w3 = Wr1[(cb + 3) * CD + d];
            #pragma unroll
            for (int r = 0; r < 16; ++r) {
                float4 x = *(const float4*)(sl + r * CD + cb);
                t[r] += x.x * w0 + x.y * w1 + x.z * w2 + x.w * w3;
            }
        }
        float mean = 0.0f;
        for (int r = 0; r < 16; ++r) mean += t[r];
        mean *= (1.0f / 16.0f);
        float var = 0.0f;
        for (int r = 0; r < 16; ++r) { float dd = t[r] - mean; var += dd * dd; }
        var *= (1.0f / 16.0f);
        float inv = rsqrtf(var + 1e-5f);
        for (int r = 0; r < 16; ++r)
            h1[r * CD + d] = fmaxf(0.0f, (t[r] - mean) * inv * g1[d] + be1[d]);
    }
    __syncthreads();
    if (d < CD) {
        float t[16];
        #pragma unroll
        for (int r = 0; r < 16; ++r) t[r] = br2[d];
        for (int c4 = 0; c4 < 64; ++c4) {
            int cb = c4 * 4;
            float w0 = Wr2[cb * CD + d], w1 = Wr2[(cb + 1) * CD + d];
            float w2 = Wr2[(cb + 2) * CD + d], w3 = Wr2[(cb + 3) * CD + d];
            #pragma unroll
            for (int r = 0; r < 16; ++r) {
                float4 x = *(const float4*)(h1 + r * CD + cb);
                t[r] += x.x * w0 + x.y * w1 + x.z * w2 + x.w * w3;
            }
        }
        float mean = 0.0f;
        for (int r = 0; r < 16; ++r) mean += t[r];
        mean *= (1.0f / 16.0f);
        float var = 0.0f;
        for (int r = 0; r < 16; ++r) { float dd = t[r] - mean; var += dd * dd; }
        var *= (1.0f / 16.0f);
        float inv = rsqrtf(var + 1e-5f);
        for (int r = 0; r < 16; ++r)
            h2[r * CD + d] = fmaxf(0.0f, (t[r] - mean) * inv * g2[d] + be2[d]);
    }
    __syncthreads();
    if (d < 288) {
        float t[16];
        #pragma unroll
        for (int r = 0; r < 16; ++r) t[r] = br3[d];
        for (int c4 = 0; c4 < 64; ++c4) {
            int cb = c4 * 4;
            float w0 = Wr3[cb * 288 + d], w1 = Wr3[(cb + 1) * 288 + d];
            float w2 = Wr3[(cb + 2) * 288 + d], w3 = Wr3[(cb + 3) * 288 + d];
            #pragma unroll
            for (int r = 0; r < 16; ++r) {
                float4 x = *(const float4*)(h2 + r * CD + cb);
                t[r] += x.x * w0 + x.y * w1 + x.z * w2 + x.w * w3;
            }
        }
        for (int r = 0; r < 16; ++r) spts[r * 288 + d] = t[r];
    }
}

// farthest point sampling: one block per batch, 384 pts, 128 selections
__global__ __launch_bounds__(128) void fps_kernel(const float* __restrict__ spts,
                                                  int* __restrict__ fidx,
                                                  float* __restrict__ lacc) {
    int b = blockIdx.x;
    int t = threadIdx.x;
    const float* pts = spts + (size_t)b * 384 * 3;
    __shared__ float rv[2];
    __shared__ int ri[2];
    __shared__ int bidx;
    int* out = fidx + b * 128;
    if (t == 0) out[0] = 0;
    if (b == 0 && t == 0) lacc[0] = 0.0f;
    float x0 = pts[t * 3], y0 = pts[t * 3 + 1], z0 = pts[t * 3 + 2];
    float x1 = pts[(t + 128) * 3], y1 = pts[(t + 128) * 3 + 1], z1 = pts[(t + 128) * 3 + 2];
    float x2 = pts[(t + 256) * 3], y2 = pts[(t + 256) * 3 + 1], z2 = pts[(t + 256) * 3 + 2];
    float d0 = 1e10f, d1 = 1e10f, d2 = 1e10f;
    float lx = pts[0], ly = pts[1], lz = pts[2];
    for (int s = 1; s < 128; ++s) {
        float dx, dy, dz;
        dx = x0 - lx; dy = y0 - ly; dz = z0 - lz; d0 = fminf(d0, dx * dx + dy * dy + dz * dz);
        dx = x1 - lx; dy = y1 - ly; dz = z1 - lz; d1 = fminf(d1, dx * dx + dy * dy + dz * dz);
        dx = x2 - lx; dy = y2 - ly; dz = z2 - lz; d2 = fminf(d2, dx * dx + dy * dy + dz * dz);
        float bv = d0; int bi = t;
        if (d1 > bv) { bv = d1; bi = t + 128; }
        if (d2 > bv) { bv = d2; bi = t + 256; }
        #pragma unroll
        for (int o = 32; o; o >>= 1) {
            float ov = __shfl_down(bv, o); int oi = __shfl_down(bi, o);
            if (ov > bv || (ov == bv && oi < bi)) { bv = ov; bi = oi; }
        }
        int lane = t & 63, w = t >> 6;
        if (lane == 0) { rv[w] = bv; ri[w] = bi; }
        __syncthreads();
        if (t == 0) {
            float fv = rv[0]; int fi = ri[0];
            if (rv[1] > fv || (rv[1] == fv && ri[1] < fi)) { fv = rv[1]; fi = ri[1]; }
            out[s] = fi;
            bidx = fi;
        }
        __syncthreads();
        int ni = bidx;
        lx = pts[ni * 3]; ly = pts[ni * 3 + 1]; lz = pts[ni * 3 + 2];
    }
}

// chamfer(ds, xyz): LDS-tiled both directions (avoids wave-uniform scalar-load
// stalls). sum2 per-thread n-set and accumulation order identical to previous
// version (bitwise-same); sum1 is an exact min (order-free).
__global__ __launch_bounds__(256) void chamfer_kernel(const float* __restrict__ spts,
                                                      const int* __restrict__ fidx,
                                                      const float* __restrict__ xyz,
                                                      float* __restrict__ lacc) {
    int b = blockIdx.x;
    int t = threadIdx.x;
    __shared__ float ds[128 * 3];
    __shared__ float tile[512 * 3];
    __shared__ float mn1s[128];
    __shared__ float red[4];
    const float* pts = spts + (size_t)b * 384 * 3;
    if (t < 128) {
        int j = fidx[b * 128 + t];
        ds[t * 3] = pts[j * 3]; ds[t * 3 + 1] = pts[j * 3 + 1]; ds[t * 3 + 2] = pts[j * 3 + 2];
    }
    __syncthreads();
    const float* xb = xyz + (size_t)b * NPTS * 3;
    int j = t & 127, half = t >> 7;
    float pjx = ds[j * 3], pjy = ds[j * 3 + 1], pjz = ds[j * 3 + 2];
    float mn1 = 1e30f;
    float sum2 = 0.0f;
    for (int ti = 0; ti < 8; ++ti) {
        __syncthreads();
        for (int i = t; i < 1536; i += 256) tile[i] = xb[ti * 1536 + i];
        __syncthreads();
        // sum2: n = ti*512 + t, then ti*512 + 256 + t (ascending, same as before)
        #pragma unroll
        for (int hh = 0; hh < 2; ++hh) {
            int nl = hh * 256 + t;
            float px = tile[nl * 3], py = tile[nl * 3 + 1], pz = tile[nl * 3 + 2];
            float mn = 1e30f;
            for (int jj = 0; jj < 128; ++jj) {
                float dx = ds[jj * 3] - px, dy = ds[jj * 3 + 1] - py, dz = ds[jj * 3 + 2] - pz;
                mn = fminf(mn, dx * dx + dy * dy + dz * dz);
            }
            sum2 += mn;
        }
        // sum1: halves alternate tiles (exact min, order-free)
        if ((ti & 1) == half) {
            for (int i = 0; i < 512; ++i) {
                float dx = tile[i * 3] - pjx, dy = tile[i * 3 + 1] - pjy, dz = tile[i * 3 + 2] - pjz;
                mn1 = fminf(mn1, dx * dx + dy * dy + dz * dz);
            }
        }
    }
    __syncthreads();
    if (half == 1) mn1s[j] = mn1;
    __syncthreads();
    float contrib = 0.0f;
    if (half == 0) contrib = fminf(mn1, mn1s[j]) * (1.0f / 128.0f);
    float total = block_sum256(sum2 * (1.0f / 4096.0f) + contrib, red);
    if (t == 0) atomicAdd(lacc, total);
}

// loss scalar only (attn written by last attn_kernel)
__global__ void finalize_kernel(const float* __restrict__ lacc, float* __restrict__ out) {
    if (threadIdx.x == 0) out[0] = lacc[0] * 0.25f;
}

// ---------------- launch ----------------

extern "C" void kernel_launch(void* const* d_in, const int* in_sizes, int n_in,
                              void* d_out, int out_size, void* d_ws, size_t ws_size,
                              hipStream_t stream) {
    (void)in_sizes; (void)n_in; (void)out_size; (void)ws_size;
    const float* x    = (const float*)d_in[0];
    const float* W1   = (const float*)d_in[2];
    const float* b1   = (const float*)d_in[3];
    const float* W2   = (const float*)d_in[4];
    const float* b2   = (const float*)d_in[5];
    const float* mu   = (const float*)d_in[6];
    const float* sg   = (const float*)d_in[7];
    const float* g_in = (const float*)d_in[8];
    const float* b_in = (const float*)d_in[9];
    const float* g_sl = (const float*)d_in[10];
    const float* b_sl = (const float*)d_in[11];
    const float* g_ff = (const float*)d_in[12];
    const float* b_ff = (const float*)d_in[13];
    const float* Wq   = (const float*)d_in[14];
    const float* Wk   = (const float*)d_in[15];
    const float* Wv   = (const float*)d_in[16];
    const float* W_ih = (const float*)d_in[17];
    const float* W_hh = (const float*)d_in[18];
    const float* b_ih = (const float*)d_in[19];
    const float* b_hh = (const float*)d_in[20];
    const float* Wm1  = (const float*)d_in[21];
    const float* bm1  = (const float*)d_in[22];
    const float* Wm2  = (const float*)d_in[23];
    const float* bm2  = (const float*)d_in[24];
    const float* Wr1  = (const float*)d_in[25];
    const float* br1  = (const float*)d_in[26];
    const float* g1   = (const float*)d_in[27];
    const float* be1  = (const float*)d_in[28];
    const float* Wr2  = (const float*)d_in[29];
    const float* br2  = (const float*)d_in[30];
    const float* g2   = (const float*)d_in[31];
    const float* be2  = (const float*)d_in[32];
    const float* Wr3  = (const float*)d_in[33];
    const float* br3  = (const float*)d_in[34];

    float* ws    = (float*)d_ws;
    float* xyz   = ws;                               // 49152 f
    float* xyzw  = xyz + 49152;                      // 65536 f (float4 [B*N])
    int*   knn   = (int*)(xyzw + 65536);             // 524288 i
    _Float16* f1h = (_Float16*)(knn + 524288);       // 2097152 h
    _Float16* W2t = (_Float16*)((float*)f1h + 1048576); // 40960 h
    float* inp   = (float*)W2t + 20480;              // 4194304 f
    float* kkb   = inp + 4194304;                    // 4194304 f
    float* vvb   = kkb + 4194304;                    // 4194304 f
    float* slots = vvb + 4194304;                    // 4096 f
    float* qb    = slots + 4096;                     // 4096 f
    float* attn  = qb + 4096;                        // 65536 f
    float* asum  = attn + 65536;                     // 16 f
    float* updp  = asum + 16;                        // 65536 f
    float* spts  = updp + 65536;                     // 4608 f
    int*   fidx  = (int*)(spts + 4608);              // 512 i
    float* lacc  = (float*)(fidx + 512);             // 1 f

    float* out = (float*)d_out;

    prep_kernel<<<64, 256, 0, stream>>>(x, xyz, (float4*)xyzw);
    slots_init_kernel<<<8, 256, 0, stream>>>(mu, sg, slots);
    knn_kernel<<<NBATCH * NPTS / 4, 256, 0, stream>>>((const float4*)xyzw, knn);
    conv1_kernel<<<NBATCH * NPTS, 128, 0, stream>>>(xyz, knn, W1, b1, f1h);
    w2t_kernel<<<256, 160, 0, stream>>>(W2, W2t);
    conv2_mfma_kernel<<<NBATCH * NPTS / 2, 256, 0, stream>>>(xyz, f1h, knn, W2t, b2, g_in, b_in, inp);
    kv_kernel<<<NBATCH * NPTS / 16, 256, 0, stream>>>(inp, Wk, Wv, kkb, vvb);

    for (int it = 0; it < 3; ++it) {
        slotq_kernel<<<16, 256, 0, stream>>>(slots, g_sl, b_sl, Wq, qb, asum);
        attn_kernel<<<64, 256, 0, stream>>>(qb, kkb, attn, asum,
                                            (it == 2) ? (out + 1) : (float*)nullptr);
        updp_kernel<<<256, 256, 0, stream>>>(attn, vvb, updp);
        gru_mlp_kernel<<<16, 256, 0, stream>>>(updp, asum, slots, W_ih, W_hh, b_ih, b_hh,
                                               g_ff, b_ff, Wm1, bm1, Wm2, bm2);
    }

    recon_kernel<<<1, 320, 0, stream>>>(slots, Wr1, br1, g1, be1, Wr2, br2, g2, be2, Wr3, br3, spts);
    fps_kernel<<<4, 128, 0, stream>>>(spts, fidx, lacc);
    chamfer_kernel<<<4, 256, 0, stream>>>(spts, fidx, xyz, lacc);
    finalize_kernel<<<1, 64, 0, stream>>>(lacc, out);
}

// Round 6
// 1030.595 us; speedup vs baseline: 2.2368x; 1.3688x over previous
//
#include <hip/hip_runtime.h>

#define NBATCH 4
#define NPTS   4096
#define KNNK   32
#define C1D    128
#define CD     256
#define KPAD   160   // conv2 K padded (131 -> 160, 5 mfma K-steps of 32)
#define ASTR   168   // LDS A row stride in halves

typedef _Float16 v8h __attribute__((ext_vector_type(8)));
typedef float    v4f __attribute__((ext_vector_type(4)));

// ---------------- helpers ----------------

__device__ __forceinline__ float block_sum256(float v, float* red) {
    #pragma unroll
    for (int o = 32; o; o >>= 1) v += __shfl_down(v, o);
    __syncthreads();
    if ((threadIdx.x & 63) == 0) red[threadIdx.x >> 6] = v;
    __syncthreads();
    return red[0] + red[1] + red[2] + red[3];
}

__device__ __forceinline__ unsigned rotl32(unsigned x, unsigned r) {
    return (x << r) | (x >> (32u - r));
}

// XLA f32 erf_inv (Giles polynomial)
__device__ float erfinv_f(float x) {
    float w = -log1pf(-x * x);
    float p;
    if (w < 5.0f) {
        w -= 2.5f;
        p = 2.81022636e-08f;
        p = fmaf(p, w, 3.43273939e-07f);
        p = fmaf(p, w, -3.5233877e-06f);
        p = fmaf(p, w, -4.39150654e-06f);
        p = fmaf(p, w, 0.00021858087f);
        p = fmaf(p, w, -0.00125372503f);
        p = fmaf(p, w, -0.00417768164f);
        p = fmaf(p, w, 0.246640727f);
        p = fmaf(p, w, 1.50140941f);
    } else {
        w = sqrtf(w) - 3.0f;
        p = -0.000200214257f;
        p = fmaf(p, w, 0.000100950558f);
        p = fmaf(p, w, 0.00134934322f);
        p = fmaf(p, w, -0.00367342844f);
        p = fmaf(p, w, 0.00573950773f);
        p = fmaf(p, w, -0.0076224613f);
        p = fmaf(p, w, 0.00943887047f);
        p = fmaf(p, w, 1.00167406f);
        p = fmaf(p, w, 2.83297682f);
    }
    return p * x;
}

__device__ __forceinline__ float bits_to_normal(unsigned bits) {
    unsigned fb = (bits >> 9) | 0x3f800000u;
    float f = __uint_as_float(fb) - 1.0f;
    const float lo = -0.99999994f;           // nextafterf(-1,0)
    float u = fmaf(f, 2.0f, lo);
    u = fmaxf(u, lo);
    return 1.41421356237f * erfinv_f(u);
}

// ---------------- kernels ----------------

// x [B,3,N] -> xyz [B,N,3], xyzw [B,N] (x,y,z,sq)
__global__ void prep_kernel(const float* __restrict__ x, float* __restrict__ xyz,
                            float4* __restrict__ xyzw) {
    int gid = blockIdx.x * 256 + threadIdx.x;
    if (gid >= NBATCH * NPTS) return;
    int b = gid >> 12, n = gid & (NPTS - 1);
    float a0 = x[(b * 3 + 0) * NPTS + n];
    float a1 = x[(b * 3 + 1) * NPTS + n];
    float a2 = x[(b * 3 + 2) * NPTS + n];
    xyz[gid * 3 + 0] = a0; xyz[gid * 3 + 1] = a1; xyz[gid * 3 + 2] = a2;
    float sq = a0 * a0 + a1 * a1 + a2 * a2;
    xyzw[gid] = make_float4(a0, a1, a2, sq);
}

// JAX threefry2x32, key(42) -> slots = mu + sigma * normal
__global__ void slots_init_kernel(const float* __restrict__ mu, const float* __restrict__ sg,
                                  float* __restrict__ slots) {
    int j = blockIdx.x * 256 + threadIdx.x;
    if (j >= 2048) return;
    unsigned ks0 = 0u, ks1 = 42u, ks2 = 0u ^ 42u ^ 0x1BD11BDAu;
    unsigned x0 = (unsigned)j + ks0;
    unsigned x1 = (unsigned)(j + 2048) + ks1;
    #define RND(r) { x0 += x1; x1 = rotl32(x1, r); x1 ^= x0; }
    RND(13u) RND(15u) RND(26u) RND(6u);  x0 += ks1; x1 += ks2 + 1u;
    RND(17u) RND(29u) RND(16u) RND(24u); x0 += ks2; x1 += ks0 + 2u;
    RND(13u) RND(15u) RND(26u) RND(6u);  x0 += ks0; x1 += ks1 + 3u;
    RND(17u) RND(29u) RND(16u) RND(24u); x0 += ks1; x1 += ks2 + 4u;
    RND(13u) RND(15u) RND(26u) RND(6u);  x0 += ks2; x1 += ks0 + 5u;
    #undef RND
    int c0 = j & 255, c1 = (j + 2048) & 255;
    slots[j]        = mu[c0] + sg[c0] * bits_to_normal(x0);
    slots[j + 2048] = mu[c1] + sg[c1] * bits_to_normal(x1);
}

// KNN: one wave per point, no barriers; 64 register-cached dists per lane.
__global__ __launch_bounds__(256) void knn_kernel(const float4* __restrict__ xyzw,
                                                  int* __restrict__ knn_idx) {
    int wid = threadIdx.x >> 6, lane = threadIdx.x & 63;
    int pid = blockIdx.x * 4 + wid;
    int b = pid >> 12, n = pid & (NPTS - 1);
    const float4* xb = xyzw + (size_t)b * NPTS;
    float4 p = xb[n];
    float d0[32], d1[32];
    #pragma unroll
    for (int i = 0; i < 32; ++i) {
        float4 c = xb[i * 64 + lane];
        float dot = p.x * c.x + p.y * c.y + p.z * c.z;
        d0[i] = p.w + c.w - 2.0f * dot;
    }
    #pragma unroll
    for (int i = 0; i < 32; ++i) {
        float4 c = xb[(i + 32) * 64 + lane];
        float dot = p.x * c.x + p.y * c.y + p.z * c.z;
        d1[i] = p.w + c.w - 2.0f * dot;
    }
    float mv0 = 1e30f; int mi0 = 0;
    #pragma unroll
    for (int i = 0; i < 32; ++i)
        if (d0[i] < mv0) { mv0 = d0[i]; mi0 = i * 64 + lane; }
    float mv1 = 1e30f; int mi1 = 0;
    #pragma unroll
    for (int i = 0; i < 32; ++i)
        if (d1[i] < mv1) { mv1 = d1[i]; mi1 = (i + 32) * 64 + lane; }

    int* out = knn_idx + (size_t)pid * KNNK;
    #pragma unroll 1
    for (int s = 0; s < KNNK; ++s) {
        float bv = mv0; int bi = mi0;
        if (mv1 < bv) { bv = mv1; bi = mi1; }
        #pragma unroll
        for (int o = 32; o; o >>= 1) {
            float ov = __shfl_down(bv, o); int oi = __shfl_down(bi, o);
            if (ov < bv || (ov == bv && oi < bi)) { bv = ov; bi = oi; }
        }
        int fi = __shfl(bi, 0);
        if (lane == 0) out[s] = fi;
        if ((fi & 63) == lane) {
            int slot = fi >> 6;
            if (slot < 32) {
                #pragma unroll
                for (int i = 0; i < 32; ++i)
                    if (i == slot) d0[i] = 1e30f;
                mv0 = 1e30f; mi0 = 0;
                #pragma unroll
                for (int i = 0; i < 32; ++i)
                    if (d0[i] < mv0) { mv0 = d0[i]; mi0 = i * 64 + lane; }
            } else {
                int s1 = slot - 32;
                #pragma unroll
                for (int i = 0; i < 32; ++i)
                    if (i == s1) d1[i] = 1e30f;
                mv1 = 1e30f; mi1 = 0;
                #pragma unroll
                for (int i = 0; i < 32; ++i)
                    if (d1[i] < mv1) { mv1 = d1[i]; mi1 = (i + 32) * 64 + lane; }
            }
        }
    }
}

// conv1 -> fp16 features for the MFMA conv2
__global__ __launch_bounds__(128) void conv1_kernel(const float* __restrict__ xyz,
                                                    const int* __restrict__ knn_idx,
                                                    const float* __restrict__ W1,
                                                    const float* __restrict__ b1,
                                                    _Float16* __restrict__ f1h) {
    int pid = blockIdx.x;
    int b = pid >> 12, n = pid & (NPTS - 1);
    int d = threadIdx.x;
    const float* xb = xyz + (size_t)b * NPTS * 3;
    float w0 = W1[d], wx = W1[C1D + d], wy = W1[2 * C1D + d], wz = W1[3 * C1D + d];
    float bb = b1[d];
    float px = xb[n * 3], py = xb[n * 3 + 1], pz = xb[n * 3 + 2];
    const int* idx = knn_idx + (size_t)pid * KNNK;
    float m = -1e30f;
    for (int k = 0; k < KNNK; ++k) {
        int j = idx[k];
        float rx = xb[j * 3] - px, ry = xb[j * 3 + 1] - py, rz = xb[j * 3 + 2] - pz;
        float v = w0 + bb + rx * wx + ry * wy + rz * wz;
        m = fmaxf(m, v);
    }
    f1h[(size_t)pid * C1D + d] = (_Float16)fmaxf(m, 0.0f);
}

// W2 [131x256 fp32] -> W2t [256][160] fp16 (transposed, zero-padded)
__global__ void w2t_kernel(const float* __restrict__ W2, _Float16* __restrict__ W2t) {
    int n = blockIdx.x;          // 0..255
    int k = threadIdx.x;         // 0..159
    W2t[n * KPAD + k] = (k < 131) ? (_Float16)W2[k * CD + n] : (_Float16)0.0f;
}

// conv2 via MFMA f16 (fp32 accumulate) + fused bias/relu/max-over-k/LayerNorm.
__global__ __launch_bounds__(256) void conv2_mfma_kernel(const float* __restrict__ xyz,
                                                         const _Float16* __restrict__ f1h,
                                                         const int* __restrict__ knn_idx,
                                                         const _Float16* __restrict__ W2t,
                                                         const float* __restrict__ b2,
                                                         const float* __restrict__ g_in,
                                                         const float* __restrict__ b_in,
                                                         float* __restrict__ inp) {
    __shared__ _Float16 A[64 * ASTR];
    __shared__ float colmax[2 * CD];
    __shared__ float red[4];
    int pid2 = blockIdx.x;
    int gp0 = pid2 * 2;
    int b = gp0 >> 12, n0 = gp0 & (NPTS - 1);
    int tid = threadIdx.x;
    const int* idx = knn_idx + (size_t)pid2 * 64;   // [2][32]
    const float* xb = xyz + (size_t)b * NPTS * 3;

    {
        int r = tid & 63, seg = tid >> 6;
        int j = idx[r];
        const uint4* s4 = (const uint4*)(f1h + ((size_t)b * NPTS + j) * C1D);
        uint4* d4 = (uint4*)&A[r * ASTR];
        #pragma unroll
        for (int i = 0; i < 4; ++i) d4[seg * 4 + i] = s4[seg * 4 + i];
        unsigned* z = (unsigned*)&A[r * ASTR + 128];
        for (int i = seg; i < 20; i += 4) z[i] = 0u;
        int np_ = (r < 32) ? n0 : (n0 + 1);
        if (seg == 0) {
            A[r * ASTR + 128] = (_Float16)(xb[j * 3 + 0] - xb[np_ * 3 + 0]);
            A[r * ASTR + 129] = (_Float16)(xb[j * 3 + 1] - xb[np_ * 3 + 1]);
        } else if (seg == 1) {
            A[r * ASTR + 130] = (_Float16)(xb[j * 3 + 2] - xb[np_ * 3 + 2]);
        }
    }
    __syncthreads();

    int w = tid >> 6, lane = tid & 63, quad = lane >> 4, lr = lane & 15;
    v4f acc[4][4];
    #pragma unroll
    for (int rt = 0; rt < 4; ++rt)
        #pragma unroll
        for (int ct = 0; ct < 4; ++ct)
            acc[rt][ct] = (v4f){0.0f, 0.0f, 0.0f, 0.0f};

    #pragma unroll
    for (int kk = 0; kk < KPAD; kk += 32) {
        v8h af[4], bf[4];
        #pragma unroll
        for (int rt = 0; rt < 4; ++rt)
            af[rt] = *(const v8h*)&A[(rt * 16 + lr) * ASTR + kk + quad * 8];
        #pragma unroll
        for (int ct = 0; ct < 4; ++ct) {
            int ncol = w * 64 + ct * 16 + lr;
            bf[ct] = *(const v8h*)(W2t + (size_t)ncol * KPAD + kk + quad * 8);
        }
        #pragma unroll
        for (int rt = 0; rt < 4; ++rt)
            #pragma unroll
            for (int ct = 0; ct < 4; ++ct)
                acc[rt][ct] = __builtin_amdgcn_mfma_f32_16x16x32_f16(af[rt], bf[ct], acc[rt][ct], 0, 0, 0);
    }

    #pragma unroll
    for (int ct = 0; ct < 4; ++ct) {
        float tm[4];
        #pragma unroll
        for (int rt = 0; rt < 4; ++rt) {
            v4f a = acc[rt][ct];
            float v = fmaxf(fmaxf(a[0], a[1]), fmaxf(a[2], a[3]));
            v = fmaxf(v, __shfl_xor(v, 16));
            v = fmaxf(v, __shfl_xor(v, 32));
            tm[rt] = v;
        }
        float p0 = fmaxf(tm[0], tm[1]);
        float p1 = fmaxf(tm[2], tm[3]);
        if (quad == 0) {
            colmax[0 * CD + w * 64 + ct * 16 + lr] = p0;
            colmax[1 * CD + w * 64 + ct * 16 + lr] = p1;
        }
    }
    __syncthreads();

    int d = tid;
    #pragma unroll
    for (int p = 0; p < 2; ++p) {
        float v = fmaxf(colmax[p * CD + d] + b2[d], 0.0f);
        float s = block_sum256(v, red);
        float mean = s * (1.0f / 256.0f);
        float s2 = block_sum256(v * v, red);
        float var = s2 * (1.0f / 256.0f) - mean * mean;
        float iv = (v - mean) * rsqrtf(var + 1e-5f) * g_in[d] + b_in[d];
        inp[(size_t)(gp0 + p) * CD + d] = iv;
    }
}

// kk = inp @ Wk, vv = inp @ Wv ; 16 points per block
__global__ __launch_bounds__(256) void kv_kernel(const float* __restrict__ inp,
                                                 const float* __restrict__ Wk,
                                                 const float* __restrict__ Wv,
                                                 float* __restrict__ kk,
                                                 float* __restrict__ vv) {
    int base = blockIdx.x * 16;
    int d = threadIdx.x;
    __shared__ float t[CD * 16];    // t[c*16+p]
    for (int p = 0; p < 16; ++p) t[d * 16 + p] = inp[((size_t)base + p) * CD + d];
    __syncthreads();
    float ka[16], va[16];
    #pragma unroll
    for (int p = 0; p < 16; ++p) { ka[p] = 0.0f; va[p] = 0.0f; }
    for (int c = 0; c < CD; ++c) {
        float wk = Wk[c * CD + d], wv = Wv[c * CD + d];
        const float4* tp = (const float4*)&t[c * 16];
        #pragma unroll
        for (int q4 = 0; q4 < 4; ++q4) {
            float4 x = tp[q4];
            ka[q4 * 4 + 0] += x.x * wk; va[q4 * 4 + 0] += x.x * wv;
            ka[q4 * 4 + 1] += x.y * wk; va[q4 * 4 + 1] += x.y * wv;
            ka[q4 * 4 + 2] += x.z * wk; va[q4 * 4 + 2] += x.z * wv;
            ka[q4 * 4 + 3] += x.w * wk; va[q4 * 4 + 3] += x.w * wv;
        }
    }
    for (int p = 0; p < 16; ++p) {
        kk[((size_t)base + p) * CD + d] = ka[p];
        vv[((size_t)base + p) * CD + d] = va[p];
    }
}

// q = LN(slots) @ Wq, one block per row (b,k); block 0 zeroes attn_sum
__global__ __launch_bounds__(256) void slotq_kernel(const float* __restrict__ slots,
                                                    const float* __restrict__ g_sl,
                                                    const float* __restrict__ b_sl,
                                                    const float* __restrict__ Wq,
                                                    float* __restrict__ q,
                                                    float* __restrict__ asum) {
    int row = blockIdx.x;
    int d = threadIdx.x;
    __shared__ float sl[CD];
    __shared__ float red[4];
    float v = slots[row * CD + d];
    float s = block_sum256(v, red);
    float mean = s * (1.0f / 256.0f);
    float s2 = block_sum256(v * v, red);
    float var = s2 * (1.0f / 256.0f) - mean * mean;
    float ln = (v - mean) * rsqrtf(var + 1e-5f) * g_sl[d] + b_sl[d];
    sl[d] = ln;
    __syncthreads();
    float acc = 0.0f;
    const float4* sp = (const float4*)sl;
    for (int c4 = 0; c4 < 64; ++c4) {
        float4 x = sp[c4];
        int cb = c4 * 4;
        acc += x.x * Wq[cb * CD + d] + x.y * Wq[(cb + 1) * CD + d]
             + x.z * Wq[(cb + 2) * CD + d] + x.w * Wq[(cb + 3) * CD + d];
    }
    q[row * CD + d] = acc;
    if (row == 0 && d < 16) asum[d] = 0.0f;
}

// logits -> softmax over slots -> attn [B,4,N]; on last iter also writes out
__global__ __launch_bounds__(256) void attn_kernel(const float* __restrict__ q,
                                                   const float* __restrict__ kk,
                                                   float* __restrict__ attn,
                                                   float* __restrict__ asum,
                                                   float* __restrict__ out_attn) {
    int b = blockIdx.x >> 4;
    int nb = blockIdx.x & 15;
    int n = nb * 256 + threadIdx.x;
    __shared__ float qs[4 * CD];
    __shared__ float redk[16];
    for (int i = threadIdx.x; i < 4 * CD; i += 256) qs[i] = q[b * 4 * CD + i];
    __syncthreads();
    const float4* kp = (const float4*)(kk + ((size_t)b * NPTS + n) * CD);
    const float4* q0 = (const float4*)(qs);
    const float4* q1 = (const float4*)(qs + CD);
    const float4* q2 = (const float4*)(qs + 2 * CD);
    const float4* q3 = (const float4*)(qs + 3 * CD);
    float a0 = 0, a1 = 0, a2 = 0, a3 = 0;
    for (int c4 = 0; c4 < 64; ++c4) {
        float4 kv = kp[c4];
        float4 x;
        x = q0[c4]; a0 += kv.x * x.x + kv.y * x.y + kv.z * x.z + kv.w * x.w;
        x = q1[c4]; a1 += kv.x * x.x + kv.y * x.y + kv.z * x.z + kv.w * x.w;
        x = q2[c4]; a2 += kv.x * x.x + kv.y * x.y + kv.z * x.z + kv.w * x.w;
        x = q3[c4]; a3 += kv.x * x.x + kv.y * x.y + kv.z * x.z + kv.w * x.w;
    }
    const float scale = 0.0625f;   // 256^-0.5
    float l0 = scale * a0, l1 = scale * a1, l2 = scale * a2, l3 = scale * a3;
    float mx = fmaxf(fmaxf(l0, l1), fmaxf(l2, l3));
    float e0 = expf(l0 - mx), e1 = expf(l1 - mx), e2 = expf(l2 - mx), e3 = expf(l3 - mx);
    float inv = 1.0f / (e0 + e1 + e2 + e3);
    e0 *= inv; e1 *= inv; e2 *= inv; e3 *= inv;
    attn[((size_t)b * 4 + 0) * NPTS + n] = e0;
    attn[((size_t)b * 4 + 1) * NPTS + n] = e1;
    attn[((size_t)b * 4 + 2) * NPTS + n] = e2;
    attn[((size_t)b * 4 + 3) * NPTS + n] = e3;
    if (out_attn) {
        float* o = out_attn + ((size_t)b * NPTS + n) * 4;
        o[0] = e0; o[1] = e1; o[2] = e2; o[3] = e3;
    }
    float as[4] = {e0, e1, e2, e3};
    #pragma unroll
    for (int k = 0; k < 4; ++k) {
        float v = as[k];
        #pragma unroll
        for (int o = 32; o; o >>= 1) v += __shfl_down(v, o);
        if ((threadIdx.x & 63) == 0) redk[(threadIdx.x >> 6) * 4 + k] = v;
    }
    __syncthreads();
    if (threadIdx.x < 4) {
        float s = redk[threadIdx.x] + redk[4 + threadIdx.x] + redk[8 + threadIdx.x] + redk[12 + threadIdx.x];
        atomicAdd(&asum[b * 4 + threadIdx.x], s);
    }
}

// partial sums of attn*vv over 256-point chunks
__global__ __launch_bounds__(256) void updp_kernel(const float* __restrict__ attn,
                                                   const float* __restrict__ vv,
                                                   float* __restrict__ updp) {
    int row = blockIdx.x >> 4, chunk = blockIdx.x & 15;
    int b = row >> 2;
    int d = threadIdx.x;
    const float* arow = attn + (size_t)row * NPTS + chunk * 256;
    const float* vb = vv + ((size_t)b * NPTS + chunk * 256) * CD;
    float acc = 0.0f;
    for (int n = 0; n < 256; ++n) acc += arow[n] * vb[(size_t)n * CD + d];
    updp[((size_t)row * 16 + chunk) * CD + d] = acc;
}

// GRU + LN_ff + MLP residual, one block per row (b,k)
__global__ __launch_bounds__(256) void gru_mlp_kernel(const float* __restrict__ updp,
                                                      const float* __restrict__ asum,
                                                      float* __restrict__ slots,
                                                      const float* __restrict__ W_ih,
                                                      const float* __restrict__ W_hh,
                                                      const float* __restrict__ b_ih,
                                                      const float* __restrict__ b_hh,
                                                      const float* __restrict__ g_ff,
                                                      const float* __restrict__ b_ff,
                                                      const float* __restrict__ Wm1,
                                                      const float* __restrict__ bm1,
                                                      const float* __restrict__ Wm2,
                                                      const float* __restrict__ bm2) {
    int row = blockIdx.x;
    int d = threadIdx.x;
    __shared__ float su[CD], sp[CD], sh[CD];
    __shared__ float red[4];
    float f = 1.0f / (asum[row] + 1e-8f);
    float u = 0.0f;
    for (int p = 0; p < 16; ++p) u += updp[((size_t)row * 16 + p) * CD + d];
    u *= f;
    float prev = slots[row * CD + d];
    su[d] = u; sp[d] = prev;
    __syncthreads();
    float gir = b_ih[d], giz = b_ih[CD + d], gin = b_ih[2 * CD + d];
    float ghr = b_hh[d], ghz = b_hh[CD + d], ghn = b_hh[2 * CD + d];
    for (int c = 0; c < CD; ++c) {
        float uc = su[c], pc = sp[c];
        const float* wi = W_ih + c * 3 * CD;
        const float* wh = W_hh + c * 3 * CD;
        gir += uc * wi[d]; giz += uc * wi[CD + d]; gin += uc * wi[2 * CD + d];
        ghr += pc * wh[d]; ghz += pc * wh[CD + d]; ghn += pc * wh[2 * CD + d];
    }
    float r = 1.0f / (1.0f + expf(-(gir + ghr)));
    float z = 1.0f / (1.0f + expf(-(giz + ghz)));
    float nn = tanhf(gin + r * ghn);
    float sNew = (1.0f - z) * nn + z * prev;
    float s = block_sum256(sNew, red);
    float mean = s * (1.0f / 256.0f);
    float s2 = block_sum256(sNew * sNew, red);
    float var = s2 * (1.0f / 256.0f) - mean * mean;
    float h = (sNew - mean) * rsqrtf(var + 1e-5f) * g_ff[d] + b_ff[d];
    __syncthreads();
    sh[d] = h;
    __syncthreads();
    float y = bm1[d];
    {
        const float4* hp = (const float4*)sh;
        for (int c4 = 0; c4 < 64; ++c4) {
            float4 x = hp[c4];
            int cb = c4 * 4;
            y += x.x * Wm1[cb * CD + d] + x.y * Wm1[(cb + 1) * CD + d]
               + x.z * Wm1[(cb + 2) * CD + d] + x.w * Wm1[(cb + 3) * CD + d];
        }
    }
    y = fmaxf(y, 0.0f);
    __syncthreads();
    sh[d] = y;
    __syncthreads();
    float o = bm2[d];
    {
        const float4* hp = (const float4*)sh;
        for (int c4 = 0; c4 < 64; ++c4) {
            float4 x = hp[c4];
            int cb = c4 * 4;
            o += x.x * Wm2[cb * CD + d] + x.y * Wm2[(cb + 1) * CD + d]
               + x.z * Wm2[(cb + 2) * CD + d] + x.w * Wm2[(cb + 3) * CD + d];
        }
    }
    slots[row * CD + d] = sNew + o;
}

// recon head, loop-interchanged: weights read once, 16 rows accumulated inner.
__global__ __launch_bounds__(320) void recon_kernel(const float* __restrict__ slots,
                                                    const float* __restrict__ Wr1, const float* __restrict__ br1,
                                                    const float* __restrict__ g1, const float* __restrict__ be1,
                                                    const float* __restrict__ Wr2, const float* __restrict__ br2,
                                                    const float* __restrict__ g2, const float* __restrict__ be2,
                                                    const float* __restrict__ Wr3, const float* __restrict__ br3,
                                                    float* __restrict__ spts) {
    __shared__ float sl[16 * CD];
    __shared__ float h1[16 * CD];
    __shared__ float h2[16 * CD];
    int d = threadIdx.x;
    if (d < CD) for (int r = 0; r < 16; ++r) sl[r * CD + d] = slots[r * CD + d];
    __syncthreads();
    if (d < CD) {
        float t[16];
        #pragma unroll
        for (int r = 0; r < 16; ++r) t[r] = br1[d];
        for (int c4 = 0; c4 < 64; ++c4) {
            int cb = c4 * 4;
            float w0 = Wr1[cb * CD + d], w1 = Wr1[(cb + 1) * CD + d];
            float w2 = Wr1[(cb + 2) * CD + d], w3 = Wr1[(cb + 3) * CD + d];
            #pragma unroll
            for (int r = 0; r < 16; ++r) {
                float4 x = *(const float4*)(sl + r * CD + cb);
                t[r] += x.x * w0 + x.y * w1 + x.z * w2 + x.w * w3;
            }
        }
        float mean = 0.0f;
        for (int r = 0; r < 16; ++r) mean += t[r];
        mean *= (1.0f / 16.0f);
        float var = 0.0f;
        for (int r = 0; r < 16; ++r) { float dd = t[r] - mean; var += dd * dd; }
        var *= (1.0f / 16.0f);
        float inv = rsqrtf(var + 1e-5f);
        for (int r = 0; r < 16; ++r)
            h1[r * CD + d] = fmaxf(0.0f, (t[r] - mean) * inv * g1[d] + be1[d]);
    }
    __syncthreads();
    if (d < CD) {
        float t[16];
        #pragma unroll
        for (int r = 0; r < 16; ++r) t[r] = br2[d];
        for (int c4 = 0; c4 < 64; ++c4) {
            int cb = c4 * 4;
            float w0 = Wr2[cb * CD + d], w1 = Wr2[(cb + 1) * CD + d];
            float w2 = Wr2[(cb + 2) * CD + d], w3 = Wr2[(cb + 3) * CD + d];
            #pragma unroll
            for (int r = 0; r < 16; ++r) {
                float4 x = *(const float4*)(h1 + r * CD + cb);
                t[r] += x.x * w0 + x.y * w1 + x.z * w2 + x.w * w3;
            }
        }
        float mean = 0.0f;
        for (int r = 0; r < 16; ++r) mean += t[r];
        mean *= (1.0f / 16.0f);
        float var = 0.0f;
        for (int r = 0; r < 16; ++r) { float dd = t[r] - mean; var += dd * dd; }
        var *= (1.0f / 16.0f);
        float inv = rsqrtf(var + 1e-5f);
        for (int r = 0; r < 16; ++r)
            h2[r * CD + d] = fmaxf(0.0f, (t[r] - mean) * inv * g2[d] + be2[d]);
    }
    __syncthreads();
    if (d < 288) {
        float t[16];
        #pragma unroll
        for (int r = 0; r < 16; ++r) t[r] = br3[d];
        for (int c4 = 0; c4 < 64; ++c4) {
            int cb = c4 * 4;
            float w0 = Wr3[cb * 288 + d], w1 = Wr3[(cb + 1) * 288 + d];
            float w2 = Wr3[(cb + 2) * 288 + d], w3 = Wr3[(cb + 3) * 288 + d];
            #pragma unroll
            for (int r = 0; r < 16; ++r) {
                float4 x = *(const float4*)(h2 + r * CD + cb);
                t[r] += x.x * w0 + x.y * w1 + x.z * w2 + x.w * w3;
            }
        }
        for (int r = 0; r < 16; ++r) spts[r * 288 + d] = t[r];
    }
}

// farthest point sampling: one block per batch; also inits lacc and mnbuf
__global__ __launch_bounds__(128) void fps_kernel(const float* __restrict__ spts,
                                                  int* __restrict__ fidx,
                                                  float* __restrict__ lacc,
                                                  unsigned* __restrict__ mnbuf) {
    int b = blockIdx.x;
    int t = threadIdx.x;
    const float* pts = spts + (size_t)b * 384 * 3;
    __shared__ float rv[2];
    __shared__ int ri[2];
    __shared__ int bidx;
    int* out = fidx + b * 128;
    if (t == 0) out[0] = 0;
    if (b == 0 && t == 0) lacc[0] = 0.0f;
    mnbuf[b * 128 + t] = 0x7F800000u;   // +inf
    float x0 = pts[t * 3], y0 = pts[t * 3 + 1], z0 = pts[t * 3 + 2];
    float x1 = pts[(t + 128) * 3], y1 = pts[(t + 128) * 3 + 1], z1 = pts[(t + 128) * 3 + 2];
    float x2 = pts[(t + 256) * 3], y2 = pts[(t + 256) * 3 + 1], z2 = pts[(t + 256) * 3 + 2];
    float d0 = 1e10f, d1 = 1e10f, d2 = 1e10f;
    float lx = pts[0], ly = pts[1], lz = pts[2];
    for (int s = 1; s < 128; ++s) {
        float dx, dy, dz;
        dx = x0 - lx; dy = y0 - ly; dz = z0 - lz; d0 = fminf(d0, dx * dx + dy * dy + dz * dz);
        dx = x1 - lx; dy = y1 - ly; dz = z1 - lz; d1 = fminf(d1, dx * dx + dy * dy + dz * dz);
        dx = x2 - lx; dy = y2 - ly; dz = z2 - lz; d2 = fminf(d2, dx * dx + dy * dy + dz * dz);
        float bv = d0; int bi = t;
        if (d1 > bv) { bv = d1; bi = t + 128; }
        if (d2 > bv) { bv = d2; bi = t + 256; }
        #pragma unroll
        for (int o = 32; o; o >>= 1) {
            float ov = __shfl_down(bv, o); int oi = __shfl_down(bi, o);
            if (ov > bv || (ov == bv && oi < bi)) { bv = ov; bi = oi; }
        }
        int lane = t & 63, w = t >> 6;
        if (lane == 0) { rv[w] = bv; ri[w] = bi; }
        __syncthreads();
        if (t == 0) {
            float fv = rv[0]; int fi = ri[0];
            if (rv[1] > fv || (rv[1] == fv && ri[1] < fi)) { fv = rv[1]; fi = ri[1]; }
            out[s] = fi;
            bidx = fi;
        }
        __syncthreads();
        int ni = bidx;
        lx = pts[ni * 3]; ly = pts[ni * 3 + 1]; lz = pts[ni * 3 + 2];
    }
}

// chamfer direction 2: per input point n, min over the 128 sampled ds points.
// 64 blocks (b x 16 chunks) for occupancy; atomicAdd partial means to lacc.
__global__ __launch_bounds__(256) void chamfer_sum2_kernel(const float* __restrict__ spts,
                                                           const int* __restrict__ fidx,
                                                           const float* __restrict__ xyz,
                                                           float* __restrict__ lacc) {
    int b = blockIdx.x >> 4, chunk = blockIdx.x & 15;
    int t = threadIdx.x;
    __shared__ float ds[128 * 3];
    __shared__ float red[4];
    const float* pts = spts + (size_t)b * 384 * 3;
    if (t < 128) {
        int j = fidx[b * 128 + t];
        ds[t * 3] = pts[j * 3]; ds[t * 3 + 1] = pts[j * 3 + 1]; ds[t * 3 + 2] = pts[j * 3 + 2];
    }
    __syncthreads();
    int n = chunk * 256 + t;
    const float* xb = xyz + (size_t)b * NPTS * 3;
    float px = xb[n * 3], py = xb[n * 3 + 1], pz = xb[n * 3 + 2];
    float mn = 1e30f;
    #pragma unroll 4
    for (int jj = 0; jj < 128; ++jj) {
        float dx = ds[jj * 3] - px, dy = ds[jj * 3 + 1] - py, dz = ds[jj * 3 + 2] - pz;
        mn = fminf(mn, dx * dx + dy * dy + dz * dz);
    }
    float total = block_sum256(mn * (1.0f / 4096.0f), red);
    if (t == 0) atomicAdd(lacc, total);
}

// chamfer direction 1: per sampled ds point j, min over input points via
// 64 blocks (b x 16 chunks of 256 n); exact min via uint atomicMin (dists >= 0).
__global__ __launch_bounds__(128) void chamfer_min1_kernel(const float* __restrict__ spts,
                                                           const int* __restrict__ fidx,
                                                           const float* __restrict__ xyz,
                                                           unsigned* __restrict__ mnbuf) {
    int b = blockIdx.x >> 4, chunk = blockIdx.x & 15;
    int t = threadIdx.x;   // 128
    __shared__ float tile[256 * 3];
    const float* xb = xyz + ((size_t)b * NPTS + chunk * 256) * 3;
    for (int i = t; i < 768; i += 128) tile[i] = xb[i];
    __syncthreads();
    int j = fidx[b * 128 + t];
    const float* pts = spts + (size_t)b * 384 * 3;
    float px = pts[j * 3], py = pts[j * 3 + 1], pz = pts[j * 3 + 2];
    float mn = 1e30f;
    #pragma unroll 4
    for (int i = 0; i < 256; ++i) {
        float dx = tile[i * 3] - px, dy = tile[i * 3 + 1] - py, dz = tile[i * 3 + 2] - pz;
        mn = fminf(mn, dx * dx + dy * dy + dz * dz);
    }
    atomicMin(&mnbuf[b * 128 + t], __float_as_uint(mn));
}

// final: sum the 512 per-ds-point mins (/128 per batch), add lacc, write loss
__global__ __launch_bounds__(512) void chamfer_final_kernel(const unsigned* __restrict__ mnbuf,
                                                            const float* __restrict__ lacc,
                                                            float* __restrict__ out) {
    int t = threadIdx.x;   // 512
    __shared__ float r[8];
    float v = __uint_as_float(mnbuf[t]) * (1.0f / 128.0f);
    #pragma unroll
    for (int o = 32; o; o >>= 1) v += __shfl_down(v, o);
    if ((t & 63) == 0) r[t >> 6] = v;
    __syncthreads();
    if (t == 0) {
        float tot = 0.0f;
        #pragma unroll
        for (int i = 0; i < 8; ++i) tot += r[i];
        out[0] = (lacc[0] + tot) * 0.25f;
    }
}

// ---------------- launch ----------------

extern "C" void kernel_launch(void* const* d_in, const int* in_sizes, int n_in,
                              void* d_out, int out_size, void* d_ws, size_t ws_size,
                              hipStream_t stream) {
    (void)in_sizes; (void)n_in; (void)out_size; (void)ws_size;
    const float* x    = (const float*)d_in[0];
    const float* W1   = (const float*)d_in[2];
    const float* b1   = (const float*)d_in[3];
    const float* W2   = (const float*)d_in[4];
    const float* b2   = (const float*)d_in[5];
    const float* mu   = (const float*)d_in[6];
    const float* sg   = (const float*)d_in[7];
    const float* g_in = (const float*)d_in[8];
    const float* b_in = (const float*)d_in[9];
    const float* g_sl = (const float*)d_in[10];
    const float* b_sl = (const float*)d_in[11];
    const float* g_ff = (const float*)d_in[12];
    const float* b_ff = (const float*)d_in[13];
    const float* Wq   = (const float*)d_in[14];
    const float* Wk   = (const float*)d_in[15];
    const float* Wv   = (const float*)d_in[16];
    const float* W_ih = (const float*)d_in[17];
    const float* W_hh = (const float*)d_in[18];
    const float* b_ih = (const float*)d_in[19];
    const float* b_hh = (const float*)d_in[20];
    const float* Wm1  = (const float*)d_in[21];
    const float* bm1  = (const float*)d_in[22];
    const float* Wm2  = (const float*)d_in[23];
    const float* bm2  = (const float*)d_in[24];
    const float* Wr1  = (const float*)d_in[25];
    const float* br1  = (const float*)d_in[26];
    const float* g1   = (const float*)d_in[27];
    const float* be1  = (const float*)d_in[28];
    const float* Wr2  = (const float*)d_in[29];
    const float* br2  = (const float*)d_in[30];
    const float* g2   = (const float*)d_in[31];
    const float* be2  = (const float*)d_in[32];
    const float* Wr3  = (const float*)d_in[33];
    const float* br3  = (const float*)d_in[34];

    float* ws    = (float*)d_ws;
    float* xyz   = ws;                               // 49152 f
    float* xyzw  = xyz + 49152;                      // 65536 f (float4 [B*N])
    int*   knn   = (int*)(xyzw + 65536);             // 524288 i
    _Float16* f1h = (_Float16*)(knn + 524288);       // 2097152 h
    _Float16* W2t = (_Float16*)((float*)f1h + 1048576); // 40960 h
    float* inp   = (float*)W2t + 20480;              // 4194304 f
    float* kkb   = inp + 4194304;                    // 4194304 f
    float* vvb   = kkb + 4194304;                    // 4194304 f
    float* slots = vvb + 4194304;                    // 4096 f
    float* qb    = slots + 4096;                     // 4096 f
    float* attn  = qb + 4096;                        // 65536 f
    float* asum  = attn + 65536;                     // 16 f
    float* updp  = asum + 16;                        // 65536 f
    float* spts  = updp + 65536;                     // 4608 f
    int*   fidx  = (int*)(spts + 4608);              // 512 i
    float* lacc  = (float*)(fidx + 512);             // 1 f
    unsigned* mnbuf = (unsigned*)(lacc + 1);         // 512 u

    float* out = (float*)d_out;

    prep_kernel<<<64, 256, 0, stream>>>(x, xyz, (float4*)xyzw);
    slots_init_kernel<<<8, 256, 0, stream>>>(mu, sg, slots);
    knn_kernel<<<NBATCH * NPTS / 4, 256, 0, stream>>>((const float4*)xyzw, knn);
    conv1_kernel<<<NBATCH * NPTS, 128, 0, stream>>>(xyz, knn, W1, b1, f1h);
    w2t_kernel<<<256, 160, 0, stream>>>(W2, W2t);
    conv2_mfma_kernel<<<NBATCH * NPTS / 2, 256, 0, stream>>>(xyz, f1h, knn, W2t, b2, g_in, b_in, inp);
    kv_kernel<<<NBATCH * NPTS / 16, 256, 0, stream>>>(inp, Wk, Wv, kkb, vvb);

    for (int it = 0; it < 3; ++it) {
        slotq_kernel<<<16, 256, 0, stream>>>(slots, g_sl, b_sl, Wq, qb, asum);
        attn_kernel<<<64, 256, 0, stream>>>(qb, kkb, attn, asum,
                                            (it == 2) ? (out + 1) : (float*)nullptr);
        updp_kernel<<<256, 256, 0, stream>>>(attn, vvb, updp);
        gru_mlp_kernel<<<16, 256, 0, stream>>>(updp, asum, slots, W_ih, W_hh, b_ih, b_hh,
                                               g_ff, b_ff, Wm1, bm1, Wm2, bm2);
    }

    recon_kernel<<<1, 320, 0, stream>>>(slots, Wr1, br1, g1, be1, Wr2, br2, g2, be2, Wr3, br3, spts);
    fps_kernel<<<4, 128, 0, stream>>>(spts, fidx, lacc, mnbuf);
    chamfer_sum2_kernel<<<64, 256, 0, stream>>>(spts, fidx, xyz, lacc);
    chamfer_min1_kernel<<<64, 128, 0, stream>>>(spts, fidx, xyz, mnbuf);
    chamfer_final_kernel<<<1, 512, 0, stream>>>(mnbuf, lacc, out);
}

// Round 8
// 865.907 us; speedup vs baseline: 2.6622x; 1.1902x over previous
//
#include <hip/hip_runtime.h>

#define NBATCH 4
#define NPTS   4096
#define KNNK   32
#define C1D    128
#define CD     256
#define KPAD   160   // conv2 K padded (131 -> 160, 5 mfma K-steps of 32)
#define ASTR   168   // LDS A row stride in halves

typedef _Float16 v8h __attribute__((ext_vector_type(8)));
typedef float    v4f __attribute__((ext_vector_type(4)));

// ---------------- helpers ----------------

__device__ __forceinline__ float block_sum256(float v, float* red) {
    #pragma unroll
    for (int o = 32; o; o >>= 1) v += __shfl_down(v, o);
    __syncthreads();
    if ((threadIdx.x & 63) == 0) red[threadIdx.x >> 6] = v;
    __syncthreads();
    return red[0] + red[1] + red[2] + red[3];
}

__device__ __forceinline__ unsigned rotl32(unsigned x, unsigned r) {
    return (x << r) | (x >> (32u - r));
}

// XLA f32 erf_inv (Giles polynomial)
__device__ float erfinv_f(float x) {
    float w = -log1pf(-x * x);
    float p;
    if (w < 5.0f) {
        w -= 2.5f;
        p = 2.81022636e-08f;
        p = fmaf(p, w, 3.43273939e-07f);
        p = fmaf(p, w, -3.5233877e-06f);
        p = fmaf(p, w, -4.39150654e-06f);
        p = fmaf(p, w, 0.00021858087f);
        p = fmaf(p, w, -0.00125372503f);
        p = fmaf(p, w, -0.00417768164f);
        p = fmaf(p, w, 0.246640727f);
        p = fmaf(p, w, 1.50140941f);
    } else {
        w = sqrtf(w) - 3.0f;
        p = -0.000200214257f;
        p = fmaf(p, w, 0.000100950558f);
        p = fmaf(p, w, 0.00134934322f);
        p = fmaf(p, w, -0.00367342844f);
        p = fmaf(p, w, 0.00573950773f);
        p = fmaf(p, w, -0.0076224613f);
        p = fmaf(p, w, 0.00943887047f);
        p = fmaf(p, w, 1.00167406f);
        p = fmaf(p, w, 2.83297682f);
    }
    return p * x;
}

__device__ __forceinline__ float bits_to_normal(unsigned bits) {
    unsigned fb = (bits >> 9) | 0x3f800000u;
    float f = __uint_as_float(fb) - 1.0f;
    const float lo = -0.99999994f;           // nextafterf(-1,0)
    float u = fmaf(f, 2.0f, lo);
    u = fmaxf(u, lo);
    return 1.41421356237f * erfinv_f(u);
}

// one level of wave64 lexicographic-min reduce via DPP (VALU-only, no LDS pipe)
template <int CTRL, int RM>
__device__ __forceinline__ void dpp_lexmin(float& v, int& ix) {
    int tv = __builtin_amdgcn_update_dpp(__float_as_int(v), __float_as_int(v), CTRL, RM, 0xf, false);
    int ti = __builtin_amdgcn_update_dpp(ix, ix, CTRL, RM, 0xf, false);
    float fv = __int_as_float(tv);
    bool take = (fv < v) || (fv == v && ti < ix);
    v  = take ? fv : v;
    ix = take ? ti : ix;
}

// ---------------- kernels ----------------

// x [B,3,N] -> xyz [B,N,3], xyzw [B,N] (x,y,z,sq)
__global__ void prep_kernel(const float* __restrict__ x, float* __restrict__ xyz,
                            float4* __restrict__ xyzw) {
    int gid = blockIdx.x * 256 + threadIdx.x;
    if (gid >= NBATCH * NPTS) return;
    int b = gid >> 12, n = gid & (NPTS - 1);
    float a0 = x[(b * 3 + 0) * NPTS + n];
    float a1 = x[(b * 3 + 1) * NPTS + n];
    float a2 = x[(b * 3 + 2) * NPTS + n];
    xyz[gid * 3 + 0] = a0; xyz[gid * 3 + 1] = a1; xyz[gid * 3 + 2] = a2;
    float sq = a0 * a0 + a1 * a1 + a2 * a2;
    xyzw[gid] = make_float4(a0, a1, a2, sq);
}

// JAX threefry2x32, key(42) -> slots = mu + sigma * normal
__global__ void slots_init_kernel(const float* __restrict__ mu, const float* __restrict__ sg,
                                  float* __restrict__ slots) {
    int j = blockIdx.x * 256 + threadIdx.x;
    if (j >= 2048) return;
    unsigned ks0 = 0u, ks1 = 42u, ks2 = 0u ^ 42u ^ 0x1BD11BDAu;
    unsigned x0 = (unsigned)j + ks0;
    unsigned x1 = (unsigned)(j + 2048) + ks1;
    #define RND(r) { x0 += x1; x1 = rotl32(x1, r); x1 ^= x0; }
    RND(13u) RND(15u) RND(26u) RND(6u);  x0 += ks1; x1 += ks2 + 1u;
    RND(17u) RND(29u) RND(16u) RND(24u); x0 += ks2; x1 += ks0 + 2u;
    RND(13u) RND(15u) RND(26u) RND(6u);  x0 += ks0; x1 += ks1 + 3u;
    RND(17u) RND(29u) RND(16u) RND(24u); x0 += ks1; x1 += ks2 + 4u;
    RND(13u) RND(15u) RND(26u) RND(6u);  x0 += ks2; x1 += ks0 + 5u;
    #undef RND
    int c0 = j & 255, c1 = (j + 2048) & 255;
    slots[j]        = mu[c0] + sg[c0] * bits_to_normal(x0);
    slots[j + 2048] = mu[c1] + sg[c1] * bits_to_normal(x1);
}

// KNN: one wave per point, no barriers. 64 register-cached dists per lane in
// 8 groups of 8 (cached group argmins). Per round: DPP wave argmin + scalar
// (readlane-uniform) owner rescan. Tie-breaks identical to lax.top_k.
__global__ __launch_bounds__(256) void knn_kernel(const float4* __restrict__ xyzw,
                                                  int* __restrict__ knn_idx) {
    int wid = threadIdx.x >> 6, lane = threadIdx.x & 63;
    int pid = blockIdx.x * 4 + wid;
    int b = pid >> 12, n = pid & (NPTS - 1);
    const float4* xb = xyzw + (size_t)b * NPTS;
    float4 p = xb[n];
    float d[64];
    #pragma unroll
    for (int i = 0; i < 64; ++i) {
        float4 c = xb[i * 64 + lane];
        float dot = p.x * c.x + p.y * c.y + p.z * c.z;
        d[i] = p.w + c.w - 2.0f * dot;
    }
    // per-group argmin, ascending scan + strict < (smallest m on ties; m = i*64+lane)
    float gv[8]; int gi[8];
    #pragma unroll
    for (int g = 0; g < 8; ++g) {
        float mv = d[g * 8]; int mi = g * 8;
        #pragma unroll
        for (int j = 1; j < 8; ++j)
            if (d[g * 8 + j] < mv) { mv = d[g * 8 + j]; mi = g * 8 + j; }
        gv[g] = mv; gi[g] = mi * 64 + lane;
    }
    int* out = knn_idx + (size_t)pid * KNNK;
    #pragma unroll 1
    for (int s = 0; s < KNNK; ++s) {
        // lane-level min over 8 groups (strict < suffices: larger g => larger m)
        float bv = gv[0]; int bi = gi[0];
        #pragma unroll
        for (int g = 1; g < 8; ++g)
            if (gv[g] < bv) { bv = gv[g]; bi = gi[g]; }
        // wave64 lexicographic argmin: row_shr 1/2/4/8 + row_bcast15/31
        dpp_lexmin<0x111, 0xf>(bv, bi);
        dpp_lexmin<0x112, 0xf>(bv, bi);
        dpp_lexmin<0x114, 0xf>(bv, bi);
        dpp_lexmin<0x118, 0xf>(bv, bi);
        dpp_lexmin<0x142, 0xa>(bv, bi);
        dpp_lexmin<0x143, 0xc>(bv, bi);
        int fm = __builtin_amdgcn_readlane(bi, 63);   // uniform winner index m
        if (lane == 0) out[s] = fm;
        int flane = fm & 63;     // uniform
        int slot  = fm >> 6;     // uniform, 0..63
        if (lane == flane) {
            int g = slot >> 3;   // uniform
            #pragma unroll
            for (int g2 = 0; g2 < 8; ++g2) {
                if (g2 == g) {   // scalar compare (slot uniform)
                    #pragma unroll
                    for (int j = 0; j < 8; ++j)
                        if (g2 * 8 + j == slot) d[g2 * 8 + j] = 1e30f;  // scalar guard
                    float mv = d[g2 * 8]; int mi = g2 * 8;
                    #pragma unroll
                    for (int j = 1; j < 8; ++j)
                        if (d[g2 * 8 + j] < mv) { mv = d[g2 * 8 + j]; mi = g2 * 8 + j; }
                    gv[g2] = mv; gi[g2] = mi * 64 + lane;
                }
            }
        }
    }
}

// conv1 -> fp16 features for the MFMA conv2
__global__ __launch_bounds__(128) void conv1_kernel(const float* __restrict__ xyz,
                                                    const int* __restrict__ knn_idx,
                                                    const float* __restrict__ W1,
                                                    const float* __restrict__ b1,
                                                    _Float16* __restrict__ f1h) {
    int pid = blockIdx.x;
    int b = pid >> 12, n = pid & (NPTS - 1);
    int d = threadIdx.x;
    const float* xb = xyz + (size_t)b * NPTS * 3;
    float w0 = W1[d], wx = W1[C1D + d], wy = W1[2 * C1D + d], wz = W1[3 * C1D + d];
    float bb = b1[d];
    float px = xb[n * 3], py = xb[n * 3 + 1], pz = xb[n * 3 + 2];
    const int* idx = knn_idx + (size_t)pid * KNNK;
    float m = -1e30f;
    for (int k = 0; k < KNNK; ++k) {
        int j = idx[k];
        float rx = xb[j * 3] - px, ry = xb[j * 3 + 1] - py, rz = xb[j * 3 + 2] - pz;
        float v = w0 + bb + rx * wx + ry * wy + rz * wz;
        m = fmaxf(m, v);
    }
    f1h[(size_t)pid * C1D + d] = (_Float16)fmaxf(m, 0.0f);
}

// W2 [131x256 fp32] -> W2t [256][160] fp16 (transposed, zero-padded)
__global__ void w2t_kernel(const float* __restrict__ W2, _Float16* __restrict__ W2t) {
    int n = blockIdx.x;          // 0..255
    int k = threadIdx.x;         // 0..159
    W2t[n * KPAD + k] = (k < 131) ? (_Float16)W2[k * CD + n] : (_Float16)0.0f;
}

// conv2 via MFMA f16 (fp32 accumulate) + fused bias/relu/max-over-k/LayerNorm.
__global__ __launch_bounds__(256) void conv2_mfma_kernel(const float* __restrict__ xyz,
                                                         const _Float16* __restrict__ f1h,
                                                         const int* __restrict__ knn_idx,
                                                         const _Float16* __restrict__ W2t,
                                                         const float* __restrict__ b2,
                                                         const float* __restrict__ g_in,
                                                         const float* __restrict__ b_in,
                                                         float* __restrict__ inp) {
    __shared__ _Float16 A[64 * ASTR];
    __shared__ float colmax[2 * CD];
    __shared__ float red[4];
    int pid2 = blockIdx.x;
    int gp0 = pid2 * 2;
    int b = gp0 >> 12, n0 = gp0 & (NPTS - 1);
    int tid = threadIdx.x;
    const int* idx = knn_idx + (size_t)pid2 * 64;   // [2][32]
    const float* xb = xyz + (size_t)b * NPTS * 3;

    {
        int r = tid & 63, seg = tid >> 6;
        int j = idx[r];
        const uint4* s4 = (const uint4*)(f1h + ((size_t)b * NPTS + j) * C1D);
        uint4* d4 = (uint4*)&A[r * ASTR];
        #pragma unroll
        for (int i = 0; i < 4; ++i) d4[seg * 4 + i] = s4[seg * 4 + i];
        unsigned* z = (unsigned*)&A[r * ASTR + 128];
        for (int i = seg; i < 20; i += 4) z[i] = 0u;
        int np_ = (r < 32) ? n0 : (n0 + 1);
        if (seg == 0) {
            A[r * ASTR + 128] = (_Float16)(xb[j * 3 + 0] - xb[np_ * 3 + 0]);
            A[r * ASTR + 129] = (_Float16)(xb[j * 3 + 1] - xb[np_ * 3 + 1]);
        } else if (seg == 1) {
            A[r * ASTR + 130] = (_Float16)(xb[j * 3 + 2] - xb[np_ * 3 + 2]);
        }
    }
    __syncthreads();

    int w = tid >> 6, lane = tid & 63, quad = lane >> 4, lr = lane & 15;
    v4f acc[4][4];
    #pragma unroll
    for (int rt = 0; rt < 4; ++rt)
        #pragma unroll
        for (int ct = 0; ct < 4; ++ct)
            acc[rt][ct] = (v4f){0.0f, 0.0f, 0.0f, 0.0f};

    #pragma unroll
    for (int kk = 0; kk < KPAD; kk += 32) {
        v8h af[4], bf[4];
        #pragma unroll
        for (int rt = 0; rt < 4; ++rt)
            af[rt] = *(const v8h*)&A[(rt * 16 + lr) * ASTR + kk + quad * 8];
        #pragma unroll
        for (int ct = 0; ct < 4; ++ct) {
            int ncol = w * 64 + ct * 16 + lr;
            bf[ct] = *(const v8h*)(W2t + (size_t)ncol * KPAD + kk + quad * 8);
        }
        #pragma unroll
        for (int rt = 0; rt < 4; ++rt)
            #pragma unroll
            for (int ct = 0; ct < 4; ++ct)
                acc[rt][ct] = __builtin_amdgcn_mfma_f32_16x16x32_f16(af[rt], bf[ct], acc[rt][ct], 0, 0, 0);
    }

    #pragma unroll
    for (int ct = 0; ct < 4; ++ct) {
        float tm[4];
        #pragma unroll
        for (int rt = 0; rt < 4; ++rt) {
            v4f a = acc[rt][ct];
            float v = fmaxf(fmaxf(a[0], a[1]), fmaxf(a[2], a[3]));
            v = fmaxf(v, __shfl_xor(v, 16));
            v = fmaxf(v, __shfl_xor(v, 32));
            tm[rt] = v;
        }
        float p0 = fmaxf(tm[0], tm[1]);
        float p1 = fmaxf(tm[2], tm[3]);
        if (quad == 0) {
            colmax[0 * CD + w * 64 + ct * 16 + lr] = p0;
            colmax[1 * CD + w * 64 + ct * 16 + lr] = p1;
        }
    }
    __syncthreads();

    int d = tid;
    #pragma unroll
    for (int p = 0; p < 2; ++p) {
        float v = fmaxf(colmax[p * CD + d] + b2[d], 0.0f);
        float s = block_sum256(v, red);
        float mean = s * (1.0f / 256.0f);
        float s2 = block_sum256(v * v, red);
        float var = s2 * (1.0f / 256.0f) - mean * mean;
        float iv = (v - mean) * rsqrtf(var + 1e-5f) * g_in[d] + b_in[d];
        inp[(size_t)(gp0 + p) * CD + d] = iv;
    }
}

// kk = inp @ Wk, vv = inp @ Wv ; 16 points per block
__global__ __launch_bounds__(256) void kv_kernel(const float* __restrict__ inp,
                                                 const float* __restrict__ Wk,
                                                 const float* __restrict__ Wv,
                                                 float* __restrict__ kk,
                                                 float* __restrict__ vv) {
    int base = blockIdx.x * 16;
    int d = threadIdx.x;
    __shared__ float t[CD * 16];    // t[c*16+p]
    for (int p = 0; p < 16; ++p) t[d * 16 + p] = inp[((size_t)base + p) * CD + d];
    __syncthreads();
    float ka[16], va[16];
    #pragma unroll
    for (int p = 0; p < 16; ++p) { ka[p] = 0.0f; va[p] = 0.0f; }
    for (int c = 0; c < CD; ++c) {
        float wk = Wk[c * CD + d], wv = Wv[c * CD + d];
        const float4* tp = (const float4*)&t[c * 16];
        #pragma unroll
        for (int q4 = 0; q4 < 4; ++q4) {
            float4 x = tp[q4];
            ka[q4 * 4 + 0] += x.x * wk; va[q4 * 4 + 0] += x.x * wv;
            ka[q4 * 4 + 1] += x.y * wk; va[q4 * 4 + 1] += x.y * wv;
            ka[q4 * 4 + 2] += x.z * wk; va[q4 * 4 + 2] += x.z * wv;
            ka[q4 * 4 + 3] += x.w * wk; va[q4 * 4 + 3] += x.w * wv;
        }
    }
    for (int p = 0; p < 16; ++p) {
        kk[((size_t)base + p) * CD + d] = ka[p];
        vv[((size_t)base + p) * CD + d] = va[p];
    }
}

// q = LN(slots) @ Wq, one block per row (b,k); block 0 zeroes attn_sum
__global__ __launch_bounds__(256) void slotq_kernel(const float* __restrict__ slots,
                                                    const float* __restrict__ g_sl,
                                                    const float* __restrict__ b_sl,
                                                    const float* __restrict__ Wq,
                                                    float* __restrict__ q,
                                                    float* __restrict__ asum) {
    int row = blockIdx.x;
    int d = threadIdx.x;
    __shared__ float sl[CD];
    __shared__ float red[4];
    float v = slots[row * CD + d];
    float s = block_sum256(v, red);
    float mean = s * (1.0f / 256.0f);
    float s2 = block_sum256(v * v, red);
    float var = s2 * (1.0f / 256.0f) - mean * mean;
    float ln = (v - mean) * rsqrtf(var + 1e-5f) * g_sl[d] + b_sl[d];
    sl[d] = ln;
    __syncthreads();
    float acc = 0.0f;
    const float4* sp = (const float4*)sl;
    for (int c4 = 0; c4 < 64; ++c4) {
        float4 x = sp[c4];
        int cb = c4 * 4;
        acc += x.x * Wq[cb * CD + d] + x.y * Wq[(cb + 1) * CD + d]
             + x.z * Wq[(cb + 2) * CD + d] + x.w * Wq[(cb + 3) * CD + d];
    }
    q[row * CD + d] = acc;
    if (row == 0 && d < 16) asum[d] = 0.0f;
}

// logits -> softmax over slots -> attn [B,4,N]; on last iter also writes out
__global__ __launch_bounds__(256) void attn_kernel(const float* __restrict__ q,
                                                   const float* __restrict__ kk,
                                                   float* __restrict__ attn,
                                                   float* __restrict__ asum,
                                                   float* __restrict__ out_attn) {
    int b = blockIdx.x >> 4;
    int nb = blockIdx.x & 15;
    int n = nb * 256 + threadIdx.x;
    __shared__ float qs[4 * CD];
    __shared__ float redk[16];
    for (int i = threadIdx.x; i < 4 * CD; i += 256) qs[i] = q[b * 4 * CD + i];
    __syncthreads();
    const float4* kp = (const float4*)(kk + ((size_t)b * NPTS + n) * CD);
    const float4* q0 = (const float4*)(qs);
    const float4* q1 = (const float4*)(qs + CD);
    const float4* q2 = (const float4*)(qs + 2 * CD);
    const float4* q3 = (const float4*)(qs + 3 * CD);
    float a0 = 0, a1 = 0, a2 = 0, a3 = 0;
    for (int c4 = 0; c4 < 64; ++c4) {
        float4 kv = kp[c4];
        float4 x;
        x = q0[c4]; a0 += kv.x * x.x + kv.y * x.y + kv.z * x.z + kv.w * x.w;
        x = q1[c4]; a1 += kv.x * x.x + kv.y * x.y + kv.z * x.z + kv.w * x.w;
        x = q2[c4]; a2 += kv.x * x.x + kv.y * x.y + kv.z * x.z + kv.w * x.w;
        x = q3[c4]; a3 += kv.x * x.x + kv.y * x.y + kv.z * x.z + kv.w * x.w;
    }
    const float scale = 0.0625f;   // 256^-0.5
    float l0 = scale * a0, l1 = scale * a1, l2 = scale * a2, l3 = scale * a3;
    float mx = fmaxf(fmaxf(l0, l1), fmaxf(l2, l3));
    float e0 = expf(l0 - mx), e1 = expf(l1 - mx), e2 = expf(l2 - mx), e3 = expf(l3 - mx);
    float inv = 1.0f / (e0 + e1 + e2 + e3);
    e0 *= inv; e1 *= inv; e2 *= inv; e3 *= inv;
    attn[((size_t)b * 4 + 0) * NPTS + n] = e0;
    attn[((size_t)b * 4 + 1) * NPTS + n] = e1;
    attn[((size_t)b * 4 + 2) * NPTS + n] = e2;
    attn[((size_t)b * 4 + 3) * NPTS + n] = e3;
    if (out_attn) {
        float* o = out_attn + ((size_t)b * NPTS + n) * 4;
        o[0] = e0; o[1] = e1; o[2] = e2; o[3] = e3;
    }
    float as[4] = {e0, e1, e2, e3};
    #pragma unroll
    for (int k = 0; k < 4; ++k) {
        float v = as[k];
        #pragma unroll
        for (int o = 32; o; o >>= 1) v += __shfl_down(v, o);
        if ((threadIdx.x & 63) == 0) redk[(threadIdx.x >> 6) * 4 + k] = v;
    }
    __syncthreads();
    if (threadIdx.x < 4) {
        float s = redk[threadIdx.x] + redk[4 + threadIdx.x] + redk[8 + threadIdx.x] + redk[12 + threadIdx.x];
        atomicAdd(&asum[b * 4 + threadIdx.x], s);
    }
}

// partial sums of attn*vv over 256-point chunks
__global__ __launch_bounds__(256) void updp_kernel(const float* __restrict__ attn,
                                                   const float* __restrict__ vv,
                                                   float* __restrict__ updp) {
    int row = blockIdx.x >> 4, chunk = blockIdx.x & 15;
    int b = row >> 2;
    int d = threadIdx.x;
    const float* arow = attn + (size_t)row * NPTS + chunk * 256;
    const float* vb = vv + ((size_t)b * NPTS + chunk * 256) * CD;
    float acc = 0.0f;
    for (int n = 0; n < 256; ++n) acc += arow[n] * vb[(size_t)n * CD + d];
    updp[((size_t)row * 16 + chunk) * CD + d] = acc;
}

// GRU + LN_ff + MLP residual, one block per row (b,k)
__global__ __launch_bounds__(256) void gru_mlp_kernel(const float* __restrict__ updp,
                                                      const float* __restrict__ asum,
                                                      float* __restrict__ slots,
                                                      const float* __restrict__ W_ih,
                                                      const float* __restrict__ W_hh,
                                                      const float* __restrict__ b_ih,
                                                      const float* __restrict__ b_hh,
                                                      const float* __restrict__ g_ff,
                                                      const float* __restrict__ b_ff,
                                                      const float* __restrict__ Wm1,
                                                      const float* __restrict__ bm1,
                                                      const float* __restrict__ Wm2,
                                                      const float* __restrict__ bm2) {
    int row = blockIdx.x;
    int d = threadIdx.x;
    __shared__ float su[CD], sp[CD], sh[CD];
    __shared__ float red[4];
    float f = 1.0f / (asum[row] + 1e-8f);
    float u = 0.0f;
    for (int p = 0; p < 16; ++p) u += updp[((size_t)row * 16 + p) * CD + d];
    u *= f;
    float prev = slots[row * CD + d];
    su[d] = u; sp[d] = prev;
    __syncthreads();
    float gir = b_ih[d], giz = b_ih[CD + d], gin = b_ih[2 * CD + d];
    float ghr = b_hh[d], ghz = b_hh[CD + d], ghn = b_hh[2 * CD + d];
    for (int c = 0; c < CD; ++c) {
        float uc = su[c], pc = sp[c];
        const float* wi = W_ih + c * 3 * CD;
        const float* wh = W_hh + c * 3 * CD;
        gir += uc * wi[d]; giz += uc * wi[CD + d]; gin += uc * wi[2 * CD + d];
        ghr += pc * wh[d]; ghz += pc * wh[CD + d]; ghn += pc * wh[2 * CD + d];
    }
    float r = 1.0f / (1.0f + expf(-(gir + ghr)));
    float z = 1.0f / (1.0f + expf(-(giz + ghz)));
    float nn = tanhf(gin + r * ghn);
    float sNew = (1.0f - z) * nn + z * prev;
    float s = block_sum256(sNew, red);
    float mean = s * (1.0f / 256.0f);
    float s2 = block_sum256(sNew * sNew, red);
    float var = s2 * (1.0f / 256.0f) - mean * mean;
    float h = (sNew - mean) * rsqrtf(var + 1e-5f) * g_ff[d] + b_ff[d];
    __syncthreads();
    sh[d] = h;
    __syncthreads();
    float y = bm1[d];
    {
        const float4* hp = (const float4*)sh;
        for (int c4 = 0; c4 < 64; ++c4) {
            float4 x = hp[c4];
            int cb = c4 * 4;
            y += x.x * Wm1[cb * CD + d] + x.y * Wm1[(cb + 1) * CD + d]
               + x.z * Wm1[(cb + 2) * CD + d] + x.w * Wm1[(cb + 3) * CD + d];
        }
    }
    y = fmaxf(y, 0.0f);
    __syncthreads();
    sh[d] = y;
    __syncthreads();
    float o = bm2[d];
    {
        const float4* hp = (const float4*)sh;
        for (int c4 = 0; c4 < 64; ++c4) {
            float4 x = hp[c4];
            int cb = c4 * 4;
            o += x.x * Wm2[cb * CD + d] + x.y * Wm2[(cb + 1) * CD + d]
               + x.z * Wm2[(cb + 2) * CD + d] + x.w * Wm2[(cb + 3) * CD + d];
        }
    }
    slots[row * CD + d] = sNew + o;
}

// recon head, loop-interchanged: weights read once, 16 rows accumulated inner.
__global__ __launch_bounds__(320) void recon_kernel(const float* __restrict__ slots,
                                                    const float* __restrict__ Wr1, const float* __restrict__ br1,
                                                    const float* __restrict__ g1, const float* __restrict__ be1,
                                                    const float* __restrict__ Wr2, const float* __restrict__ br2,
                                                    const float* __restrict__ g2, const float* __restrict__ be2,
                                                    const float* __restrict__ Wr3, const float* __restrict__ br3,
                                                    float* __restrict__ spts) {
    __shared__ float sl[16 * CD];
    __shared__ float h1[16 * CD];
    __shared__ float h2[16 * CD];
    int d = threadIdx.x;
    if (d < CD) for (int r = 0; r < 16; ++r) sl[r * CD + d] = slots[r * CD + d];
    __syncthreads();
    if (d < CD) {
        float t[16];
        #pragma unroll
        for (int r = 0; r < 16; ++r) t[r] = br1[d];
        for (int c4 = 0; c4 < 64; ++c4) {
            int cb = c4 * 4;
            float w0 = Wr1[cb * CD + d], w1 = Wr1[(cb + 1) * CD + d];
            float w2 = Wr1[(cb + 2) * CD + d], w3 = Wr1[(cb + 3) * CD + d];
            #pragma unroll
            for (int r = 0; r < 16; ++r) {
                float4 x = *(const float4*)(sl + r * CD + cb);
                t[r] += x.x * w0 + x.y * w1 + x.z * w2 + x.w * w3;
            }
        }
        float mean = 0.0f;
        for (int r = 0; r < 16; ++r) mean += t[r];
        mean *= (1.0f / 16.0f);
        float var = 0.0f;
        for (int r = 0; r < 16; ++r) { float dd = t[r] - mean; var += dd * dd; }
        var *= (1.0f / 16.0f);
        float inv = rsqrtf(var + 1e-5f);
        for (int r = 0; r < 16; ++r)
            h1[r * CD + d] = fmaxf(0.0f, (t[r] - mean) * inv * g1[d] + be1[d]);
    }
    __syncthreads();
    if (d < CD) {
        float t[16];
        #pragma unroll
        for (int r = 0; r < 16; ++r) t[r] = br2[d];
        for (int c4 = 0; c4 < 64; ++c4) {
            int cb = c4 * 4;
            float w0 = Wr2[cb * CD + d], w1 = Wr2[(cb + 1) * CD + d];
            float w2 = Wr2[(cb + 2) * CD + d], w3 = Wr2[(cb + 3) * CD + d];
            #pragma unroll
            for (int r = 0; r < 16; ++r) {
                float4 x = *(const float4*)(h1 + r * CD + cb);
                t[r] += x.x * w0 + x.y * w1 + x.z * w2 + x.w * w3;
            }
        }
        float mean = 0.0f;
        for (int r = 0; r < 16; ++r) mean += t[r];
        mean *= (1.0f / 16.0f);
        float var = 0.0f;
        for (int r = 0; r < 16; ++r) { float dd = t[r] - mean; var += dd * dd; }
        var *= (1.0f / 16.0f);
        float inv = rsqrtf(var + 1e-5f);
        for (int r = 0; r < 16; ++r)
            h2[r * CD + d] = fmaxf(0.0f, (t[r] - mean) * inv * g2[d] + be2[d]);
    }
    __syncthreads();
    if (d < 288) {
        float t[16];
        #pragma unroll
        for (int r = 0; r < 16; ++r) t[r] = br3[d];
        for (int c4 = 0; c4 < 64; ++c4) {
            int cb = c4 * 4;
            float w0 = Wr3[cb * 288 + d], w1 = Wr3[(cb + 1) * 288 + d];
            float w2 = Wr3[(cb + 2) * 288 + d], w3 = Wr3[(cb + 3) * 288 + d];
            #pragma unroll
            for (int r = 0; r < 16; ++r) {
                float4 x = *(const float4*)(h2 + r * CD + cb);
                t[r] += x.x * w0 + x.y * w1 + x.z * w2 + x.w * w3;
            }
        }
        for (int r = 0; r < 16; ++r) spts[r * 288 + d] = t[r];
    }
}

// farthest point sampling: one block per batch; also inits lacc and mnbuf
__global__ __launch_bounds__(128) void fps_kernel(const float* __restrict__ spts,
                                                  int* __restrict__ fidx,
                                                  float* __restrict__ lacc,
                                                  unsigned* __restrict__ mnbuf) {
    int b = blockIdx.x;
    int t = threadIdx.x;
    const float* pts = spts + (size_t)b * 384 * 3;
    __shared__ float rv[2];
    __shared__ int ri[2];
    __shared__ int bidx;
    int* out = fidx + b * 128;
    if (t == 0) out[0] = 0;
    if (b == 0 && t == 0) lacc[0] = 0.0f;
    mnbuf[b * 128 + t] = 0x7F800000u;   // +inf
    float x0 = pts[t * 3], y0 = pts[t * 3 + 1], z0 = pts[t * 3 + 2];
    float x1 = pts[(t + 128) * 3], y1 = pts[(t + 128) * 3 + 1], z1 = pts[(t + 128) * 3 + 2];
    float x2 = pts[(t + 256) * 3], y2 = pts[(t + 256) * 3 + 1], z2 = pts[(t + 256) * 3 + 2];
    float d0 = 1e10f, d1 = 1e10f, d2 = 1e10f;
    float lx = pts[0], ly = pts[1], lz = pts[2];
    for (int s = 1; s < 128; ++s) {
        float dx, dy, dz;
        dx = x0 - lx; dy = y0 - ly; dz = z0 - lz; d0 = fminf(d0, dx * dx + dy * dy + dz * dz);
        dx = x1 - lx; dy = y1 - ly; dz = z1 - lz; d1 = fminf(d1, dx * dx + dy * dy + dz * dz);
        dx = x2 - lx; dy = y2 - ly; dz = z2 - lz; d2 = fminf(d2, dx * dx + dy * dy + dz * dz);
        float bv = d0; int bi = t;
        if (d1 > bv) { bv = d1; bi = t + 128; }
        if (d2 > bv) { bv = d2; bi = t + 256; }
        #pragma unroll
        for (int o = 32; o; o >>= 1) {
            float ov = __shfl_down(bv, o); int oi = __shfl_down(bi, o);
            if (ov > bv || (ov == bv && oi < bi)) { bv = ov; bi = oi; }
        }
        int lane = t & 63, w = t >> 6;
        if (lane == 0) { rv[w] = bv; ri[w] = bi; }
        __syncthreads();
        if (t == 0) {
            float fv = rv[0]; int fi = ri[0];
            if (rv[1] > fv || (rv[1] == fv && ri[1] < fi)) { fv = rv[1]; fi = ri[1]; }
            out[s] = fi;
            bidx = fi;
        }
        __syncthreads();
        int ni = bidx;
        lx = pts[ni * 3]; ly = pts[ni * 3 + 1]; lz = pts[ni * 3 + 2];
    }
}

// chamfer direction 2: per input point n, min over the 128 sampled ds points.
__global__ __launch_bounds__(256) void chamfer_sum2_kernel(const float* __restrict__ spts,
                                                           const int* __restrict__ fidx,
                                                           const float* __restrict__ xyz,
                                                           float* __restrict__ lacc) {
    int b = blockIdx.x >> 4, chunk = blockIdx.x & 15;
    int t = threadIdx.x;
    __shared__ float ds[128 * 3];
    __shared__ float red[4];
    const float* pts = spts + (size_t)b * 384 * 3;
    if (t < 128) {
        int j = fidx[b * 128 + t];
        ds[t * 3] = pts[j * 3]; ds[t * 3 + 1] = pts[j * 3 + 1]; ds[t * 3 + 2] = pts[j * 3 + 2];
    }
    __syncthreads();
    int n = chunk * 256 + t;
    const float* xb = xyz + (size_t)b * NPTS * 3;
    float px = xb[n * 3], py = xb[n * 3 + 1], pz = xb[n * 3 + 2];
    float mn = 1e30f;
    #pragma unroll 4
    for (int jj = 0; jj < 128; ++jj) {
        float dx = ds[jj * 3] - px, dy = ds[jj * 3 + 1] - py, dz = ds[jj * 3 + 2] - pz;
        mn = fminf(mn, dx * dx + dy * dy + dz * dz);
    }
    float total = block_sum256(mn * (1.0f / 4096.0f), red);
    if (t == 0) atomicAdd(lacc, total);
}

// chamfer direction 1: per sampled ds point j, exact min via uint atomicMin.
__global__ __launch_bounds__(128) void chamfer_min1_kernel(const float* __restrict__ spts,
                                                           const int* __restrict__ fidx,
                                                           const float* __restrict__ xyz,
                                                           unsigned* __restrict__ mnbuf) {
    int b = blockIdx.x >> 4, chunk = blockIdx.x & 15;
    int t = threadIdx.x;   // 128
    __shared__ float tile[256 * 3];
    const float* xb = xyz + ((size_t)b * NPTS + chunk * 256) * 3;
    for (int i = t; i < 768; i += 128) tile[i] = xb[i];
    __syncthreads();
    int j = fidx[b * 128 + t];
    const float* pts = spts + (size_t)b * 384 * 3;
    float px = pts[j * 3], py = pts[j * 3 + 1], pz = pts[j * 3 + 2];
    float mn = 1e30f;
    #pragma unroll 4
    for (int i = 0; i < 256; ++i) {
        float dx = tile[i * 3] - px, dy = tile[i * 3 + 1] - py, dz = tile[i * 3 + 2] - pz;
        mn = fminf(mn, dx * dx + dy * dy + dz * dz);
    }
    atomicMin(&mnbuf[b * 128 + t], __float_as_uint(mn));
}

// final: sum the 512 per-ds-point mins (/128 per batch), add lacc, write loss
__global__ __launch_bounds__(512) void chamfer_final_kernel(const unsigned* __restrict__ mnbuf,
                                                            const float* __restrict__ lacc,
                                                            float* __restrict__ out) {
    int t = threadIdx.x;   // 512
    __shared__ float r[8];
    float v = __uint_as_float(mnbuf[t]) * (1.0f / 128.0f);
    #pragma unroll
    for (int o = 32; o; o >>= 1) v += __shfl_down(v, o);
    if ((t & 63) == 0) r[t >> 6] = v;
    __syncthreads();
    if (t == 0) {
        float tot = 0.0f;
        #pragma unroll
        for (int i = 0; i < 8; ++i) tot += r[i];
        out[0] = (lacc[0] + tot) * 0.25f;
    }
}

// ---------------- launch ----------------

extern "C" void kernel_launch(void* const* d_in, const int* in_sizes, int n_in,
                              void* d_out, int out_size, void* d_ws, size_t ws_size,
                              hipStream_t stream) {
    (void)in_sizes; (void)n_in; (void)out_size; (void)ws_size;
    const float* x    = (const float*)d_in[0];
    const float* W1   = (const float*)d_in[2];
    const float* b1   = (const float*)d_in[3];
    const float* W2   = (const float*)d_in[4];
    const float* b2   = (const float*)d_in[5];
    const float* mu   = (const float*)d_in[6];
    const float* sg   = (const float*)d_in[7];
    const float* g_in = (const float*)d_in[8];
    const float* b_in = (const float*)d_in[9];
    const float* g_sl = (const float*)d_in[10];
    const float* b_sl = (const float*)d_in[11];
    const float* g_ff = (const float*)d_in[12];
    const float* b_ff = (const float*)d_in[13];
    const float* Wq   = (const float*)d_in[14];
    const float* Wk   = (const float*)d_in[15];
    const float* Wv   = (const float*)d_in[16];
    const float* W_ih = (const float*)d_in[17];
    const float* W_hh = (const float*)d_in[18];
    const float* b_ih = (const float*)d_in[19];
    const float* b_hh = (const float*)d_in[20];
    const float* Wm1  = (const float*)d_in[21];
    const float* bm1  = (const float*)d_in[22];
    const float* Wm2  = (const float*)d_in[23];
    const float* bm2  = (const float*)d_in[24];
    const float* Wr1  = (const float*)d_in[25];
    const float* br1  = (const float*)d_in[26];
    const float* g1   = (const float*)d_in[27];
    const float* be1  = (const float*)d_in[28];
    const float* Wr2  = (const float*)d_in[29];
    const float* br2  = (const float*)d_in[30];
    const float* g2   = (const float*)d_in[31];
    const float* be2  = (const float*)d_in[32];
    const float* Wr3  = (const float*)d_in[33];
    const float* br3  = (const float*)d_in[34];

    float* ws    = (float*)d_ws;
    float* xyz   = ws;                               // 49152 f
    float* xyzw  = xyz + 49152;                      // 65536 f (float4 [B*N])
    int*   knn   = (int*)(xyzw + 65536);             // 524288 i
    _Float16* f1h = (_Float16*)(knn + 524288);       // 2097152 h
    _Float16* W2t = (_Float16*)((float*)f1h + 1048576); // 40960 h
    float* inp   = (float*)W2t + 20480;              // 4194304 f
    float* kkb   = inp + 4194304;                    // 4194304 f
    float* vvb   = kkb + 4194304;                    // 4194304 f
    float* slots = vvb + 4194304;                    // 4096 f
    float* qb    = slots + 4096;                     // 4096 f
    float* attn  = qb + 4096;                        // 65536 f
    float* asum  = attn + 65536;                     // 16 f
    float* updp  = asum + 16;                        // 65536 f
    float* spts  = updp + 65536;                     // 4608 f
    int*   fidx  = (int*)(spts + 4608);              // 512 i
    float* lacc  = (float*)(fidx + 512);             // 1 f
    unsigned* mnbuf = (unsigned*)(lacc + 1);         // 512 u

    float* out = (float*)d_out;

    prep_kernel<<<64, 256, 0, stream>>>(x, xyz, (float4*)xyzw);
    slots_init_kernel<<<8, 256, 0, stream>>>(mu, sg, slots);
    knn_kernel<<<NBATCH * NPTS / 4, 256, 0, stream>>>((const float4*)xyzw, knn);
    conv1_kernel<<<NBATCH * NPTS, 128, 0, stream>>>(xyz, knn, W1, b1, f1h);
    w2t_kernel<<<256, 160, 0, stream>>>(W2, W2t);
    conv2_mfma_kernel<<<NBATCH * NPTS / 2, 256, 0, stream>>>(xyz, f1h, knn, W2t, b2, g_in, b_in, inp);
    kv_kernel<<<NBATCH * NPTS / 16, 256, 0, stream>>>(inp, Wk, Wv, kkb, vvb);

    for (int it = 0; it < 3; ++it) {
        slotq_kernel<<<16, 256, 0, stream>>>(slots, g_sl, b_sl, Wq, qb, asum);
        attn_kernel<<<64, 256, 0, stream>>>(qb, kkb, attn, asum,
                                            (it == 2) ? (out + 1) : (float*)nullptr);
        updp_kernel<<<256, 256, 0, stream>>>(attn, vvb, updp);
        gru_mlp_kernel<<<16, 256, 0, stream>>>(updp, asum, slots, W_ih, W_hh, b_ih, b_hh,
                                               g_ff, b_ff, Wm1, bm1, Wm2, bm2);
    }

    recon_kernel<<<1, 320, 0, stream>>>(slots, Wr1, br1, g1, be1, Wr2, br2, g2, be2, Wr3, br3, spts);
    fps_kernel<<<4, 128, 0, stream>>>(spts, fidx, lacc, mnbuf);
    chamfer_sum2_kernel<<<64, 256, 0, stream>>>(spts, fidx, xyz, lacc);
    chamfer_min1_kernel<<<64, 128, 0, stream>>>(spts, fidx, xyz, mnbuf);
    chamfer_final_kernel<<<1, 512, 0, stream>>>(mnbuf, lacc, out);
}

// Round 9
// 782.236 us; speedup vs baseline: 2.9470x; 1.1070x over previous
//
#include <hip/hip_runtime.h>

#define NBATCH 4
#define NPTS   4096
#define KNNK   32
#define C1D    128
#define CD     256
#define KPAD   160   // conv2 K padded (131 -> 160, 5 mfma K-steps of 32)
#define ASTR   168   // conv2 LDS A row stride in halves
#define ASTR2  264   // kv LDS A row stride in halves (256 cols + 8 pad)

typedef _Float16 v8h __attribute__((ext_vector_type(8)));
typedef float    v4f __attribute__((ext_vector_type(4)));

// ---------------- helpers ----------------

__device__ __forceinline__ float block_sum256(float v, float* red) {
    #pragma unroll
    for (int o = 32; o; o >>= 1) v += __shfl_down(v, o);
    __syncthreads();
    if ((threadIdx.x & 63) == 0) red[threadIdx.x >> 6] = v;
    __syncthreads();
    return red[0] + red[1] + red[2] + red[3];
}

__device__ __forceinline__ unsigned rotl32(unsigned x, unsigned r) {
    return (x << r) | (x >> (32u - r));
}

// XLA f32 erf_inv (Giles polynomial)
__device__ float erfinv_f(float x) {
    float w = -log1pf(-x * x);
    float p;
    if (w < 5.0f) {
        w -= 2.5f;
        p = 2.81022636e-08f;
        p = fmaf(p, w, 3.43273939e-07f);
        p = fmaf(p, w, -3.5233877e-06f);
        p = fmaf(p, w, -4.39150654e-06f);
        p = fmaf(p, w, 0.00021858087f);
        p = fmaf(p, w, -0.00125372503f);
        p = fmaf(p, w, -0.00417768164f);
        p = fmaf(p, w, 0.246640727f);
        p = fmaf(p, w, 1.50140941f);
    } else {
        w = sqrtf(w) - 3.0f;
        p = -0.000200214257f;
        p = fmaf(p, w, 0.000100950558f);
        p = fmaf(p, w, 0.00134934322f);
        p = fmaf(p, w, -0.00367342844f);
        p = fmaf(p, w, 0.00573950773f);
        p = fmaf(p, w, -0.0076224613f);
        p = fmaf(p, w, 0.00943887047f);
        p = fmaf(p, w, 1.00167406f);
        p = fmaf(p, w, 2.83297682f);
    }
    return p * x;
}

__device__ __forceinline__ float bits_to_normal(unsigned bits) {
    unsigned fb = (bits >> 9) | 0x3f800000u;
    float f = __uint_as_float(fb) - 1.0f;
    const float lo = -0.99999994f;           // nextafterf(-1,0)
    float u = fmaf(f, 2.0f, lo);
    u = fmaxf(u, lo);
    return 1.41421356237f * erfinv_f(u);
}

// one level of wave64 lexicographic-min reduce via DPP (VALU-only)
template <int CTRL, int RM>
__device__ __forceinline__ void dpp_lexmin(float& v, int& ix) {
    int tv = __builtin_amdgcn_update_dpp(__float_as_int(v), __float_as_int(v), CTRL, RM, 0xf, false);
    int ti = __builtin_amdgcn_update_dpp(ix, ix, CTRL, RM, 0xf, false);
    float fv = __int_as_float(tv);
    bool take = (fv < v) || (fv == v && ti < ix);
    v  = take ? fv : v;
    ix = take ? ti : ix;
}

// lexicographic max (value desc, index asc on ties) — matches jnp.argmax
template <int CTRL, int RM>
__device__ __forceinline__ void dpp_lexmax(float& v, int& ix) {
    int tv = __builtin_amdgcn_update_dpp(__float_as_int(v), __float_as_int(v), CTRL, RM, 0xf, false);
    int ti = __builtin_amdgcn_update_dpp(ix, ix, CTRL, RM, 0xf, false);
    float fv = __int_as_float(tv);
    bool take = (fv > v) || (fv == v && ti < ix);
    v  = take ? fv : v;
    ix = take ? ti : ix;
}

// ---------------- kernels ----------------

// x [B,3,N] -> xyz [B,N,3], xyzw [B,N] (x,y,z,sq)
__global__ void prep_kernel(const float* __restrict__ x, float* __restrict__ xyz,
                            float4* __restrict__ xyzw) {
    int gid = blockIdx.x * 256 + threadIdx.x;
    if (gid >= NBATCH * NPTS) return;
    int b = gid >> 12, n = gid & (NPTS - 1);
    float a0 = x[(b * 3 + 0) * NPTS + n];
    float a1 = x[(b * 3 + 1) * NPTS + n];
    float a2 = x[(b * 3 + 2) * NPTS + n];
    xyz[gid * 3 + 0] = a0; xyz[gid * 3 + 1] = a1; xyz[gid * 3 + 2] = a2;
    float sq = a0 * a0 + a1 * a1 + a2 * a2;
    xyzw[gid] = make_float4(a0, a1, a2, sq);
}

// JAX threefry2x32, key(42) -> slots = mu + sigma * normal
__global__ void slots_init_kernel(const float* __restrict__ mu, const float* __restrict__ sg,
                                  float* __restrict__ slots) {
    int j = blockIdx.x * 256 + threadIdx.x;
    if (j >= 2048) return;
    unsigned ks0 = 0u, ks1 = 42u, ks2 = 0u ^ 42u ^ 0x1BD11BDAu;
    unsigned x0 = (unsigned)j + ks0;
    unsigned x1 = (unsigned)(j + 2048) + ks1;
    #define RND(r) { x0 += x1; x1 = rotl32(x1, r); x1 ^= x0; }
    RND(13u) RND(15u) RND(26u) RND(6u);  x0 += ks1; x1 += ks2 + 1u;
    RND(17u) RND(29u) RND(16u) RND(24u); x0 += ks2; x1 += ks0 + 2u;
    RND(13u) RND(15u) RND(26u) RND(6u);  x0 += ks0; x1 += ks1 + 3u;
    RND(17u) RND(29u) RND(16u) RND(24u); x0 += ks1; x1 += ks2 + 4u;
    RND(13u) RND(15u) RND(26u) RND(6u);  x0 += ks2; x1 += ks0 + 5u;
    #undef RND
    int c0 = j & 255, c1 = (j + 2048) & 255;
    slots[j]        = mu[c0] + sg[c0] * bits_to_normal(x0);
    slots[j + 2048] = mu[c1] + sg[c1] * bits_to_normal(x1);
}

// KNN: one wave per point, no barriers. 64 register-cached dists per lane in
// 8 groups of 8. Per round: DPP wave argmin + scalar owner rescan.
__global__ __launch_bounds__(256) void knn_kernel(const float4* __restrict__ xyzw,
                                                  int* __restrict__ knn_idx) {
    int wid = threadIdx.x >> 6, lane = threadIdx.x & 63;
    int pid = blockIdx.x * 4 + wid;
    int b = pid >> 12, n = pid & (NPTS - 1);
    const float4* xb = xyzw + (size_t)b * NPTS;
    float4 p = xb[n];
    float d[64];
    #pragma unroll
    for (int i = 0; i < 64; ++i) {
        float4 c = xb[i * 64 + lane];
        float dot = p.x * c.x + p.y * c.y + p.z * c.z;
        d[i] = p.w + c.w - 2.0f * dot;
    }
    float gv[8]; int gi[8];
    #pragma unroll
    for (int g = 0; g < 8; ++g) {
        float mv = d[g * 8]; int mi = g * 8;
        #pragma unroll
        for (int j = 1; j < 8; ++j)
            if (d[g * 8 + j] < mv) { mv = d[g * 8 + j]; mi = g * 8 + j; }
        gv[g] = mv; gi[g] = mi * 64 + lane;
    }
    int* out = knn_idx + (size_t)pid * KNNK;
    #pragma unroll 1
    for (int s = 0; s < KNNK; ++s) {
        float bv = gv[0]; int bi = gi[0];
        #pragma unroll
        for (int g = 1; g < 8; ++g)
            if (gv[g] < bv) { bv = gv[g]; bi = gi[g]; }
        dpp_lexmin<0x111, 0xf>(bv, bi);
        dpp_lexmin<0x112, 0xf>(bv, bi);
        dpp_lexmin<0x114, 0xf>(bv, bi);
        dpp_lexmin<0x118, 0xf>(bv, bi);
        dpp_lexmin<0x142, 0xa>(bv, bi);
        dpp_lexmin<0x143, 0xc>(bv, bi);
        int fm = __builtin_amdgcn_readlane(bi, 63);
        if (lane == 0) out[s] = fm;
        int flane = fm & 63;
        int slot  = fm >> 6;
        if (lane == flane) {
            int g = slot >> 3;
            #pragma unroll
            for (int g2 = 0; g2 < 8; ++g2) {
                if (g2 == g) {
                    #pragma unroll
                    for (int j = 0; j < 8; ++j)
                        if (g2 * 8 + j == slot) d[g2 * 8 + j] = 1e30f;
                    float mv = d[g2 * 8]; int mi = g2 * 8;
                    #pragma unroll
                    for (int j = 1; j < 8; ++j)
                        if (d[g2 * 8 + j] < mv) { mv = d[g2 * 8 + j]; mi = g2 * 8 + j; }
                    gv[g2] = mv; gi[g2] = mi * 64 + lane;
                }
            }
        }
    }
}

// conv1 -> fp16 features for the MFMA conv2
__global__ __launch_bounds__(128) void conv1_kernel(const float* __restrict__ xyz,
                                                    const int* __restrict__ knn_idx,
                                                    const float* __restrict__ W1,
                                                    const float* __restrict__ b1,
                                                    _Float16* __restrict__ f1h) {
    int pid = blockIdx.x;
    int b = pid >> 12, n = pid & (NPTS - 1);
    int d = threadIdx.x;
    const float* xb = xyz + (size_t)b * NPTS * 3;
    float w0 = W1[d], wx = W1[C1D + d], wy = W1[2 * C1D + d], wz = W1[3 * C1D + d];
    float bb = b1[d];
    float px = xb[n * 3], py = xb[n * 3 + 1], pz = xb[n * 3 + 2];
    const int* idx = knn_idx + (size_t)pid * KNNK;
    float m = -1e30f;
    for (int k = 0; k < KNNK; ++k) {
        int j = idx[k];
        float rx = xb[j * 3] - px, ry = xb[j * 3 + 1] - py, rz = xb[j * 3 + 2] - pz;
        float v = w0 + bb + rx * wx + ry * wy + rz * wz;
        m = fmaxf(m, v);
    }
    f1h[(size_t)pid * C1D + d] = (_Float16)fmaxf(m, 0.0f);
}

// W2 [131x256 fp32] -> W2t [256][160] fp16 (transposed, zero-padded)
__global__ void w2t_kernel(const float* __restrict__ W2, _Float16* __restrict__ W2t) {
    int n = blockIdx.x;          // 0..255
    int k = threadIdx.x;         // 0..159
    W2t[n * KPAD + k] = (k < 131) ? (_Float16)W2[k * CD + n] : (_Float16)0.0f;
}

// Wk/Wv [256x256 fp32] -> WkvT [512][256] fp16 (transposed, Wk rows then Wv rows)
__global__ void wkvt_kernel(const float* __restrict__ Wk, const float* __restrict__ Wv,
                            _Float16* __restrict__ WkvT) {
    int n = blockIdx.x;          // 0..511
    int c = threadIdx.x;         // 0..255
    float v = (n < 256) ? Wk[c * CD + n] : Wv[c * CD + (n - 256)];
    WkvT[n * CD + c] = (_Float16)v;
}

// conv2 via MFMA f16 + fused bias/relu/max-over-k/LayerNorm -> inph fp16
__global__ __launch_bounds__(256) void conv2_mfma_kernel(const float* __restrict__ xyz,
                                                         const _Float16* __restrict__ f1h,
                                                         const int* __restrict__ knn_idx,
                                                         const _Float16* __restrict__ W2t,
                                                         const float* __restrict__ b2,
                                                         const float* __restrict__ g_in,
                                                         const float* __restrict__ b_in,
                                                         _Float16* __restrict__ inph) {
    __shared__ _Float16 A[64 * ASTR];
    __shared__ float colmax[2 * CD];
    __shared__ float red[4];
    int pid2 = blockIdx.x;
    int gp0 = pid2 * 2;
    int b = gp0 >> 12, n0 = gp0 & (NPTS - 1);
    int tid = threadIdx.x;
    const int* idx = knn_idx + (size_t)pid2 * 64;   // [2][32]
    const float* xb = xyz + (size_t)b * NPTS * 3;

    {
        int r = tid & 63, seg = tid >> 6;
        int j = idx[r];
        const uint4* s4 = (const uint4*)(f1h + ((size_t)b * NPTS + j) * C1D);
        uint4* d4 = (uint4*)&A[r * ASTR];
        #pragma unroll
        for (int i = 0; i < 4; ++i) d4[seg * 4 + i] = s4[seg * 4 + i];
        unsigned* z = (unsigned*)&A[r * ASTR + 128];
        for (int i = seg; i < 20; i += 4) z[i] = 0u;
        int np_ = (r < 32) ? n0 : (n0 + 1);
        if (seg == 0) {
            A[r * ASTR + 128] = (_Float16)(xb[j * 3 + 0] - xb[np_ * 3 + 0]);
            A[r * ASTR + 129] = (_Float16)(xb[j * 3 + 1] - xb[np_ * 3 + 1]);
        } else if (seg == 1) {
            A[r * ASTR + 130] = (_Float16)(xb[j * 3 + 2] - xb[np_ * 3 + 2]);
        }
    }
    __syncthreads();

    int w = tid >> 6, lane = tid & 63, quad = lane >> 4, lr = lane & 15;
    v4f acc[4][4];
    #pragma unroll
    for (int rt = 0; rt < 4; ++rt)
        #pragma unroll
        for (int ct = 0; ct < 4; ++ct)
            acc[rt][ct] = (v4f){0.0f, 0.0f, 0.0f, 0.0f};

    #pragma unroll
    for (int kk = 0; kk < KPAD; kk += 32) {
        v8h af[4], bf[4];
        #pragma unroll
        for (int rt = 0; rt < 4; ++rt)
            af[rt] = *(const v8h*)&A[(rt * 16 + lr) * ASTR + kk + quad * 8];
        #pragma unroll
        for (int ct = 0; ct < 4; ++ct) {
            int ncol = w * 64 + ct * 16 + lr;
            bf[ct] = *(const v8h*)(W2t + (size_t)ncol * KPAD + kk + quad * 8);
        }
        #pragma unroll
        for (int rt = 0; rt < 4; ++rt)
            #pragma unroll
            for (int ct = 0; ct < 4; ++ct)
                acc[rt][ct] = __builtin_amdgcn_mfma_f32_16x16x32_f16(af[rt], bf[ct], acc[rt][ct], 0, 0, 0);
    }

    #pragma unroll
    for (int ct = 0; ct < 4; ++ct) {
        float tm[4];
        #pragma unroll
        for (int rt = 0; rt < 4; ++rt) {
            v4f a = acc[rt][ct];
            float v = fmaxf(fmaxf(a[0], a[1]), fmaxf(a[2], a[3]));
            v = fmaxf(v, __shfl_xor(v, 16));
            v = fmaxf(v, __shfl_xor(v, 32));
            tm[rt] = v;
        }
        float p0 = fmaxf(tm[0], tm[1]);
        float p1 = fmaxf(tm[2], tm[3]);
        if (quad == 0) {
            colmax[0 * CD + w * 64 + ct * 16 + lr] = p0;
            colmax[1 * CD + w * 64 + ct * 16 + lr] = p1;
        }
    }
    __syncthreads();

    int d = tid;
    #pragma unroll
    for (int p = 0; p < 2; ++p) {
        float v = fmaxf(colmax[p * CD + d] + b2[d], 0.0f);
        float s = block_sum256(v, red);
        float mean = s * (1.0f / 256.0f);
        float s2 = block_sum256(v * v, red);
        float var = s2 * (1.0f / 256.0f) - mean * mean;
        float iv = (v - mean) * rsqrtf(var + 1e-5f) * g_in[d] + b_in[d];
        inph[(size_t)(gp0 + p) * CD + d] = (_Float16)iv;
    }
}

// kv via MFMA fp16: block = 64 points x 256 cols; half 0 -> kk, half 1 -> vv.
__global__ __launch_bounds__(256) void kv_mfma_kernel(const _Float16* __restrict__ inph,
                                                      const _Float16* __restrict__ WkvT,
                                                      float* __restrict__ kk,
                                                      float* __restrict__ vv) {
    __shared__ _Float16 A[64 * ASTR2];
    int rb = blockIdx.x >> 1, half = blockIdx.x & 1;
    int row0 = rb * 64;
    int tid = threadIdx.x;
    {
        const uint4* src4 = (const uint4*)(inph + (size_t)row0 * CD);
        #pragma unroll
        for (int i = 0; i < 8; ++i) {
            int idx = i * 256 + tid;         // uint4 index, 32 per row
            int row = idx >> 5, c8 = idx & 31;
            *(uint4*)&A[row * ASTR2 + c8 * 8] = src4[idx];
        }
    }
    __syncthreads();
    int w = tid >> 6, lane = tid & 63, quad = lane >> 4, lr = lane & 15;
    v4f acc[4][4];
    #pragma unroll
    for (int rt = 0; rt < 4; ++rt)
        #pragma unroll
        for (int ct = 0; ct < 4; ++ct)
            acc[rt][ct] = (v4f){0.0f, 0.0f, 0.0f, 0.0f};
    #pragma unroll
    for (int ks = 0; ks < CD; ks += 32) {
        v8h af[4], bf[4];
        #pragma unroll
        for (int rt = 0; rt < 4; ++rt)
            af[rt] = *(const v8h*)&A[(rt * 16 + lr) * ASTR2 + ks + quad * 8];
        #pragma unroll
        for (int ct = 0; ct < 4; ++ct) {
            int ncol = half * 256 + w * 64 + ct * 16 + lr;
            bf[ct] = *(const v8h*)(WkvT + (size_t)ncol * CD + ks + quad * 8);
        }
        #pragma unroll
        for (int rt = 0; rt < 4; ++rt)
            #pragma unroll
            for (int ct = 0; ct < 4; ++ct)
                acc[rt][ct] = __builtin_amdgcn_mfma_f32_16x16x32_f16(af[rt], bf[ct], acc[rt][ct], 0, 0, 0);
    }
    float* dst = half ? vv : kk;
    #pragma unroll
    for (int rt = 0; rt < 4; ++rt)
        #pragma unroll
        for (int ct = 0; ct < 4; ++ct) {
            int col = w * 64 + ct * 16 + lr;
            #pragma unroll
            for (int r = 0; r < 4; ++r) {
                int row = rt * 16 + quad * 4 + r;
                dst[(size_t)(row0 + row) * CD + col] = acc[rt][ct][r];
            }
        }
}

// q = LN(slots) @ Wq, one block per row (b,k); block 0 zeroes attn_sum
__global__ __launch_bounds__(256) void slotq_kernel(const float* __restrict__ slots,
                                                    const float* __restrict__ g_sl,
                                                    const float* __restrict__ b_sl,
                                                    const float* __restrict__ Wq,
                                                    float* __restrict__ q,
                                                    float* __restrict__ asum) {
    int row = blockIdx.x;
    int d = threadIdx.x;
    __shared__ float sl[CD];
    __shared__ float red[4];
    float v = slots[row * CD + d];
    float s = block_sum256(v, red);
    float mean = s * (1.0f / 256.0f);
    float s2 = block_sum256(v * v, red);
    float var = s2 * (1.0f / 256.0f) - mean * mean;
    float ln = (v - mean) * rsqrtf(var + 1e-5f) * g_sl[d] + b_sl[d];
    sl[d] = ln;
    __syncthreads();
    float acc = 0.0f;
    const float4* sp = (const float4*)sl;
    for (int c4 = 0; c4 < 64; ++c4) {
        float4 x = sp[c4];
        int cb = c4 * 4;
        acc += x.x * Wq[cb * CD + d] + x.y * Wq[(cb + 1) * CD + d]
             + x.z * Wq[(cb + 2) * CD + d] + x.w * Wq[(cb + 3) * CD + d];
    }
    q[row * CD + d] = acc;
    if (row == 0 && d < 16) asum[d] = 0.0f;
}

// logits -> softmax over slots -> attn [B,4,N]; on last iter also writes out
__global__ __launch_bounds__(256) void attn_kernel(const float* __restrict__ q,
                                                   const float* __restrict__ kk,
                                                   float* __restrict__ attn,
                                                   float* __restrict__ asum,
                                                   float* __restrict__ out_attn) {
    int b = blockIdx.x >> 4;
    int nb = blockIdx.x & 15;
    int n = nb * 256 + threadIdx.x;
    __shared__ float qs[4 * CD];
    __shared__ float redk[16];
    for (int i = threadIdx.x; i < 4 * CD; i += 256) qs[i] = q[b * 4 * CD + i];
    __syncthreads();
    const float4* kp = (const float4*)(kk + ((size_t)b * NPTS + n) * CD);
    const float4* q0 = (const float4*)(qs);
    const float4* q1 = (const float4*)(qs + CD);
    const float4* q2 = (const float4*)(qs + 2 * CD);
    const float4* q3 = (const float4*)(qs + 3 * CD);
    float a0 = 0, a1 = 0, a2 = 0, a3 = 0;
    for (int c4 = 0; c4 < 64; ++c4) {
        float4 kv = kp[c4];
        float4 x;
        x = q0[c4]; a0 += kv.x * x.x + kv.y * x.y + kv.z * x.z + kv.w * x.w;
        x = q1[c4]; a1 += kv.x * x.x + kv.y * x.y + kv.z * x.z + kv.w * x.w;
        x = q2[c4]; a2 += kv.x * x.x + kv.y * x.y + kv.z * x.z + kv.w * x.w;
        x = q3[c4]; a3 += kv.x * x.x + kv.y * x.y + kv.z * x.z + kv.w * x.w;
    }
    const float scale = 0.0625f;   // 256^-0.5
    float l0 = scale * a0, l1 = scale * a1, l2 = scale * a2, l3 = scale * a3;
    float mx = fmaxf(fmaxf(l0, l1), fmaxf(l2, l3));
    float e0 = expf(l0 - mx), e1 = expf(l1 - mx), e2 = expf(l2 - mx), e3 = expf(l3 - mx);
    float inv = 1.0f / (e0 + e1 + e2 + e3);
    e0 *= inv; e1 *= inv; e2 *= inv; e3 *= inv;
    attn[((size_t)b * 4 + 0) * NPTS + n] = e0;
    attn[((size_t)b * 4 + 1) * NPTS + n] = e1;
    attn[((size_t)b * 4 + 2) * NPTS + n] = e2;
    attn[((size_t)b * 4 + 3) * NPTS + n] = e3;
    if (out_attn) {
        float* o = out_attn + ((size_t)b * NPTS + n) * 4;
        o[0] = e0; o[1] = e1; o[2] = e2; o[3] = e3;
    }
    float as[4] = {e0, e1, e2, e3};
    #pragma unroll
    for (int k = 0; k < 4; ++k) {
        float v = as[k];
        #pragma unroll
        for (int o = 32; o; o >>= 1) v += __shfl_down(v, o);
        if ((threadIdx.x & 63) == 0) redk[(threadIdx.x >> 6) * 4 + k] = v;
    }
    __syncthreads();
    if (threadIdx.x < 4) {
        float s = redk[threadIdx.x] + redk[4 + threadIdx.x] + redk[8 + threadIdx.x] + redk[12 + threadIdx.x];
        atomicAdd(&asum[b * 4 + threadIdx.x], s);
    }
}

// partial sums of attn*vv over 256-point chunks
__global__ __launch_bounds__(256) void updp_kernel(const float* __restrict__ attn,
                                                   const float* __restrict__ vv,
                                                   float* __restrict__ updp) {
    int row = blockIdx.x >> 4, chunk = blockIdx.x & 15;
    int b = row >> 2;
    int d = threadIdx.x;
    const float* arow = attn + (size_t)row * NPTS + chunk * 256;
    const float* vb = vv + ((size_t)b * NPTS + chunk * 256) * CD;
    float acc = 0.0f;
    for (int n = 0; n < 256; ++n) acc += arow[n] * vb[(size_t)n * CD + d];
    updp[((size_t)row * 16 + chunk) * CD + d] = acc;
}

// GRU gates: gi = su@W_ih + b_ih, gh = sp@W_hh + b_hh; one block per (row,gate)
__global__ __launch_bounds__(256) void gru_gates_kernel(const float* __restrict__ updp,
                                                        const float* __restrict__ asum,
                                                        const float* __restrict__ slots,
                                                        const float* __restrict__ W_ih,
                                                        const float* __restrict__ W_hh,
                                                        const float* __restrict__ b_ih,
                                                        const float* __restrict__ b_hh,
                                                        float* __restrict__ gi,
                                                        float* __restrict__ gh) {
    int row = blockIdx.x / 3, gate = blockIdx.x % 3;
    int d = threadIdx.x;
    __shared__ float su[CD], sp[CD];
    float f = 1.0f / (asum[row] + 1e-8f);
    float u = 0.0f;
    for (int p = 0; p < 16; ++p) u += updp[((size_t)row * 16 + p) * CD + d];
    u *= f;
    su[d] = u; sp[d] = slots[row * CD + d];
    __syncthreads();
    float acc_i = b_ih[gate * CD + d];
    float acc_h = b_hh[gate * CD + d];
    const float* wi = W_ih + gate * CD + d;
    const float* wh = W_hh + gate * CD + d;
    for (int c = 0; c < CD; ++c) {
        acc_i += su[c] * wi[c * 3 * CD];
        acc_h += sp[c] * wh[c * 3 * CD];
    }
    gi[row * 3 * CD + gate * CD + d] = acc_i;
    gh[row * 3 * CD + gate * CD + d] = acc_h;
}

// GRU update + LN_ff + MLP residual, one block per row (b,k)
__global__ __launch_bounds__(256) void gru_mlp_kernel(const float* __restrict__ gi,
                                                      const float* __restrict__ gh,
                                                      float* __restrict__ slots,
                                                      const float* __restrict__ g_ff,
                                                      const float* __restrict__ b_ff,
                                                      const float* __restrict__ Wm1,
                                                      const float* __restrict__ bm1,
                                                      const float* __restrict__ Wm2,
                                                      const float* __restrict__ bm2) {
    int row = blockIdx.x;
    int d = threadIdx.x;
    __shared__ float sh[CD];
    __shared__ float red[4];
    float prev = slots[row * CD + d];
    float gir = gi[row * 3 * CD + d], giz = gi[row * 3 * CD + CD + d], gin = gi[row * 3 * CD + 2 * CD + d];
    float ghr = gh[row * 3 * CD + d], ghz = gh[row * 3 * CD + CD + d], ghn = gh[row * 3 * CD + 2 * CD + d];
    float r = 1.0f / (1.0f + expf(-(gir + ghr)));
    float z = 1.0f / (1.0f + expf(-(giz + ghz)));
    float nn = tanhf(gin + r * ghn);
    float sNew = (1.0f - z) * nn + z * prev;
    float s = block_sum256(sNew, red);
    float mean = s * (1.0f / 256.0f);
    float s2 = block_sum256(sNew * sNew, red);
    float var = s2 * (1.0f / 256.0f) - mean * mean;
    float h = (sNew - mean) * rsqrtf(var + 1e-5f) * g_ff[d] + b_ff[d];
    __syncthreads();
    sh[d] = h;
    __syncthreads();
    float y = bm1[d];
    {
        const float4* hp = (const float4*)sh;
        for (int c4 = 0; c4 < 64; ++c4) {
            float4 x = hp[c4];
            int cb = c4 * 4;
            y += x.x * Wm1[cb * CD + d] + x.y * Wm1[(cb + 1) * CD + d]
               + x.z * Wm1[(cb + 2) * CD + d] + x.w * Wm1[(cb + 3) * CD + d];
        }
    }
    y = fmaxf(y, 0.0f);
    __syncthreads();
    sh[d] = y;
    __syncthreads();
    float o = bm2[d];
    {
        const float4* hp = (const float4*)sh;
        for (int c4 = 0; c4 < 64; ++c4) {
            float4 x = hp[c4];
            int cb = c4 * 4;
            o += x.x * Wm2[cb * CD + d] + x.y * Wm2[(cb + 1) * CD + d]
               + x.z * Wm2[(cb + 2) * CD + d] + x.w * Wm2[(cb + 3) * CD + d];
        }
    }
    slots[row * CD + d] = sNew + o;
}

// recon head, loop-interchanged: weights read once, 16 rows accumulated inner.
__global__ __launch_bounds__(320) void recon_kernel(const float* __restrict__ slots,
                                                    const float* __restrict__ Wr1, const float* __restrict__ br1,
                                                    const float* __restrict__ g1, const float* __restrict__ be1,
                                                    const float* __restrict__ Wr2, const float* __restrict__ br2,
                                                    const float* __restrict__ g2, const float* __restrict__ be2,
                                                    const float* __restrict__ Wr3, const float* __restrict__ br3,
                                                    float* __restrict__ spts) {
    __shared__ float sl[16 * CD];
    __shared__ float h1[16 * CD];
    __shared__ float h2[16 * CD];
    int d = threadIdx.x;
    if (d < CD) for (int r = 0; r < 16; ++r) sl[r * CD + d] = slots[r * CD + d];
    __syncthreads();
    if (d < CD) {
        float t[16];
        #pragma unroll
        for (int r = 0; r < 16; ++r) t[r] = br1[d];
        for (int c4 = 0; c4 < 64; ++c4) {
            int cb = c4 * 4;
            float w0 = Wr1[cb * CD + d], w1 = Wr1[(cb + 1) * CD + d];
            float w2 = Wr1[(cb + 2) * CD + d], w3 = Wr1[(cb + 3) * CD + d];
            #pragma unroll
            for (int r = 0; r < 16; ++r) {
                float4 x = *(const float4*)(sl + r * CD + cb);
                t[r] += x.x * w0 + x.y * w1 + x.z * w2 + x.w * w3;
            }
        }
        float mean = 0.0f;
        for (int r = 0; r < 16; ++r) mean += t[r];
        mean *= (1.0f / 16.0f);
        float var = 0.0f;
        for (int r = 0; r < 16; ++r) { float dd = t[r] - mean; var += dd * dd; }
        var *= (1.0f / 16.0f);
        float inv = rsqrtf(var + 1e-5f);
        for (int r = 0; r < 16; ++r)
            h1[r * CD + d] = fmaxf(0.0f, (t[r] - mean) * inv * g1[d] + be1[d]);
    }
    __syncthreads();
    if (d < CD) {
        float t[16];
        #pragma unroll
        for (int r = 0; r < 16; ++r) t[r] = br2[d];
        for (int c4 = 0; c4 < 64; ++c4) {
            int cb = c4 * 4;
            float w0 = Wr2[cb * CD + d], w1 = Wr2[(cb + 1) * CD + d];
            float w2 = Wr2[(cb + 2) * CD + d], w3 = Wr2[(cb + 3) * CD + d];
            #pragma unroll
            for (int r = 0; r < 16; ++r) {
                float4 x = *(const float4*)(h1 + r * CD + cb);
                t[r] += x.x * w0 + x.y * w1 + x.z * w2 + x.w * w3;
            }
        }
        float mean = 0.0f;
        for (int r = 0; r < 16; ++r) mean += t[r];
        mean *= (1.0f / 16.0f);
        float var = 0.0f;
        for (int r = 0; r < 16; ++r) { float dd = t[r] - mean; var += dd * dd; }
        var *= (1.0f / 16.0f);
        float inv = rsqrtf(var + 1e-5f);
        for (int r = 0; r < 16; ++r)
            h2[r * CD + d] = fmaxf(0.0f, (t[r] - mean) * inv * g2[d] + be2[d]);
    }
    __syncthreads();
    if (d < 288) {
        float t[16];
        #pragma unroll
        for (int r = 0; r < 16; ++r) t[r] = br3[d];
        for (int c4 = 0; c4 < 64; ++c4) {
            int cb = c4 * 4;
            float w0 = Wr3[cb * 288 + d], w1 = Wr3[(cb + 1) * 288 + d];
            float w2 = Wr3[(cb + 2) * 288 + d], w3 = Wr3[(cb + 3) * 288 + d];
            #pragma unroll
            for (int r = 0; r < 16; ++r) {
                float4 x = *(const float4*)(h2 + r * CD + cb);
                t[r] += x.x * w0 + x.y * w1 + x.z * w2 + x.w * w3;
            }
        }
        for (int r = 0; r < 16; ++r) spts[r * 288 + d] = t[r];
    }
}

// FPS: ONE WAVE per batch, zero barriers. 6 candidates per lane in registers;
// per round: DPP lexmax (value desc, index asc = jnp.argmax) + readlane coords.
__global__ __launch_bounds__(64) void fps_kernel(const float* __restrict__ spts,
                                                 int* __restrict__ fidx,
                                                 float* __restrict__ lacc,
                                                 unsigned* __restrict__ mnbuf) {
    int b = blockIdx.x;
    int lane = threadIdx.x;
    const float* pts = spts + (size_t)b * 384 * 3;
    int* out = fidx + b * 128;
    if (lane == 0) out[0] = 0;
    if (b == 0 && lane == 0) lacc[0] = 0.0f;
    mnbuf[b * 128 + lane] = 0x7F800000u;
    mnbuf[b * 128 + 64 + lane] = 0x7F800000u;
    float px[6], py[6], pz[6], dd[6];
    #pragma unroll
    for (int i = 0; i < 6; ++i) {
        int m = i * 64 + lane;
        px[i] = pts[m * 3]; py[i] = pts[m * 3 + 1]; pz[i] = pts[m * 3 + 2];
        dd[i] = 1e10f;
    }
    float lx = pts[0], ly = pts[1], lz = pts[2];
    #pragma unroll 1
    for (int s = 1; s < 128; ++s) {
        #pragma unroll
        for (int i = 0; i < 6; ++i) {
            float dx = px[i] - lx, dy = py[i] - ly, dz = pz[i] - lz;
            dd[i] = fminf(dd[i], dx * dx + dy * dy + dz * dz);
        }
        float bv = dd[0]; int bi = lane;
        #pragma unroll
        for (int i = 1; i < 6; ++i)
            if (dd[i] > bv) { bv = dd[i]; bi = i * 64 + lane; }
        dpp_lexmax<0x111, 0xf>(bv, bi);
        dpp_lexmax<0x112, 0xf>(bv, bi);
        dpp_lexmax<0x114, 0xf>(bv, bi);
        dpp_lexmax<0x118, 0xf>(bv, bi);
        dpp_lexmax<0x142, 0xa>(bv, bi);
        dpp_lexmax<0x143, 0xc>(bv, bi);
        int fm = __builtin_amdgcn_readlane(bi, 63);   // uniform winner
        if (lane == 0) out[s] = fm;
        int slot = fm >> 6, sl_lane = fm & 63;        // uniform
        float sx = px[0], sy = py[0], sz = pz[0];
        #pragma unroll
        for (int i = 1; i < 6; ++i)
            if (slot == i) { sx = px[i]; sy = py[i]; sz = pz[i]; }
        lx = __int_as_float(__builtin_amdgcn_readlane(__float_as_int(sx), sl_lane));
        ly = __int_as_float(__builtin_amdgcn_readlane(__float_as_int(sy), sl_lane));
        lz = __int_as_float(__builtin_amdgcn_readlane(__float_as_int(sz), sl_lane));
    }
}

// chamfer direction 2: per input point n, min over the 128 sampled ds points.
__global__ __launch_bounds__(256) void chamfer_sum2_kernel(const float* __restrict__ spts,
                                                           const int* __restrict__ fidx,
                                                           const float* __restrict__ xyz,
                                                           float* __restrict__ lacc) {
    int b = blockIdx.x >> 4, chunk = blockIdx.x & 15;
    int t = threadIdx.x;
    __shared__ float ds[128 * 3];
    __shared__ float red[4];
    const float* pts = spts + (size_t)b * 384 * 3;
    if (t < 128) {
        int j = fidx[b * 128 + t];
        ds[t * 3] = pts[j * 3]; ds[t * 3 + 1] = pts[j * 3 + 1]; ds[t * 3 + 2] = pts[j * 3 + 2];
    }
    __syncthreads();
    int n = chunk * 256 + t;
    const float* xb = xyz + (size_t)b * NPTS * 3;
    float px = xb[n * 3], py = xb[n * 3 + 1], pz = xb[n * 3 + 2];
    float mn = 1e30f;
    #pragma unroll 4
    for (int jj = 0; jj < 128; ++jj) {
        float dx = ds[jj * 3] - px, dy = ds[jj * 3 + 1] - py, dz = ds[jj * 3 + 2] - pz;
        mn = fminf(mn, dx * dx + dy * dy + dz * dz);
    }
    float total = block_sum256(mn * (1.0f / 4096.0f), red);
    if (t == 0) atomicAdd(lacc, total);
}

// chamfer direction 1: per sampled ds point j, exact min via uint atomicMin.
__global__ __launch_bounds__(128) void chamfer_min1_kernel(const float* __restrict__ spts,
                                                           const int* __restrict__ fidx,
                                                           const float* __restrict__ xyz,
                                                           unsigned* __restrict__ mnbuf) {
    int b = blockIdx.x >> 4, chunk = blockIdx.x & 15;
    int t = threadIdx.x;   // 128
    __shared__ float tile[256 * 3];
    const float* xb = xyz + ((size_t)b * NPTS + chunk * 256) * 3;
    for (int i = t; i < 768; i += 128) tile[i] = xb[i];
    __syncthreads();
    int j = fidx[b * 128 + t];
    const float* pts = spts + (size_t)b * 384 * 3;
    float px = pts[j * 3], py = pts[j * 3 + 1], pz = pts[j * 3 + 2];
    float mn = 1e30f;
    #pragma unroll 4
    for (int i = 0; i < 256; ++i) {
        float dx = tile[i * 3] - px, dy = tile[i * 3 + 1] - py, dz = tile[i * 3 + 2] - pz;
        mn = fminf(mn, dx * dx + dy * dy + dz * dz);
    }
    atomicMin(&mnbuf[b * 128 + t], __float_as_uint(mn));
}

// final: sum the 512 per-ds-point mins (/128 per batch), add lacc, write loss
__global__ __launch_bounds__(512) void chamfer_final_kernel(const unsigned* __restrict__ mnbuf,
                                                            const float* __restrict__ lacc,
                                                            float* __restrict__ out) {
    int t = threadIdx.x;   // 512
    __shared__ float r[8];
    float v = __uint_as_float(mnbuf[t]) * (1.0f / 128.0f);
    #pragma unroll
    for (int o = 32; o; o >>= 1) v += __shfl_down(v, o);
    if ((t & 63) == 0) r[t >> 6] = v;
    __syncthreads();
    if (t == 0) {
        float tot = 0.0f;
        #pragma unroll
        for (int i = 0; i < 8; ++i) tot += r[i];
        out[0] = (lacc[0] + tot) * 0.25f;
    }
}

// ---------------- launch ----------------

extern "C" void kernel_launch(void* const* d_in, const int* in_sizes, int n_in,
                              void* d_out, int out_size, void* d_ws, size_t ws_size,
                              hipStream_t stream) {
    (void)in_sizes; (void)n_in; (void)out_size; (void)ws_size;
    const float* x    = (const float*)d_in[0];
    const float* W1   = (const float*)d_in[2];
    const float* b1   = (const float*)d_in[3];
    const float* W2   = (const float*)d_in[4];
    const float* b2   = (const float*)d_in[5];
    const float* mu   = (const float*)d_in[6];
    const float* sg   = (const float*)d_in[7];
    const float* g_in = (const float*)d_in[8];
    const float* b_in = (const float*)d_in[9];
    const float* g_sl = (const float*)d_in[10];
    const float* b_sl = (const float*)d_in[11];
    const float* g_ff = (const float*)d_in[12];
    const float* b_ff = (const float*)d_in[13];
    const float* Wq   = (const float*)d_in[14];
    const float* Wk   = (const float*)d_in[15];
    const float* Wv   = (const float*)d_in[16];
    const float* W_ih = (const float*)d_in[17];
    const float* W_hh = (const float*)d_in[18];
    const float* b_ih = (const float*)d_in[19];
    const float* b_hh = (const float*)d_in[20];
    const float* Wm1  = (const float*)d_in[21];
    const float* bm1  = (const float*)d_in[22];
    const float* Wm2  = (const float*)d_in[23];
    const float* bm2  = (const float*)d_in[24];
    const float* Wr1  = (const float*)d_in[25];
    const float* br1  = (const float*)d_in[26];
    const float* g1   = (const float*)d_in[27];
    const float* be1  = (const float*)d_in[28];
    const float* Wr2  = (const float*)d_in[29];
    const float* br2  = (const float*)d_in[30];
    const float* g2   = (const float*)d_in[31];
    const float* be2  = (const float*)d_in[32];
    const float* Wr3  = (const float*)d_in[33];
    const float* br3  = (const float*)d_in[34];

    float* ws    = (float*)d_ws;
    float* xyz   = ws;                               // 49152 f
    float* xyzw  = xyz + 49152;                      // 65536 f (float4 [B*N])
    int*   knn   = (int*)(xyzw + 65536);             // 524288 i
    _Float16* f1h = (_Float16*)(knn + 524288);       // 2097152 h = 1048576 f
    _Float16* W2t = (_Float16*)((float*)f1h + 1048576);  // 40960 h -> 20480 f
    _Float16* WkvT = (_Float16*)((float*)W2t + 20480);   // 131072 h -> 65536 f
    _Float16* inph = (_Float16*)((float*)WkvT + 65536);  // 4194304 h -> 2097152 f
    float* kkb   = (float*)inph + 2097152;           // 4194304 f
    float* vvb   = kkb + 4194304;                    // 4194304 f
    float* slots = vvb + 4194304;                    // 4096 f
    float* qb    = slots + 4096;                     // 4096 f
    float* attn  = qb + 4096;                        // 65536 f
    float* asum  = attn + 65536;                     // 16 f
    float* updp  = asum + 16;                        // 65536 f
    float* gi    = updp + 65536;                     // 12288 f
    float* gh    = gi + 12288;                       // 12288 f
    float* spts  = gh + 12288;                       // 4608 f
    int*   fidx  = (int*)(spts + 4608);              // 512 i
    float* lacc  = (float*)(fidx + 512);             // 1 f
    unsigned* mnbuf = (unsigned*)(lacc + 1);         // 512 u

    float* out = (float*)d_out;

    prep_kernel<<<64, 256, 0, stream>>>(x, xyz, (float4*)xyzw);
    slots_init_kernel<<<8, 256, 0, stream>>>(mu, sg, slots);
    knn_kernel<<<NBATCH * NPTS / 4, 256, 0, stream>>>((const float4*)xyzw, knn);
    conv1_kernel<<<NBATCH * NPTS, 128, 0, stream>>>(xyz, knn, W1, b1, f1h);
    w2t_kernel<<<256, 160, 0, stream>>>(W2, W2t);
    wkvt_kernel<<<512, 256, 0, stream>>>(Wk, Wv, WkvT);
    conv2_mfma_kernel<<<NBATCH * NPTS / 2, 256, 0, stream>>>(xyz, f1h, knn, W2t, b2, g_in, b_in, inph);
    kv_mfma_kernel<<<NBATCH * NPTS / 64 * 2, 256, 0, stream>>>(inph, WkvT, kkb, vvb);

    for (int it = 0; it < 3; ++it) {
        slotq_kernel<<<16, 256, 0, stream>>>(slots, g_sl, b_sl, Wq, qb, asum);
        attn_kernel<<<64, 256, 0, stream>>>(qb, kkb, attn, asum,
                                            (it == 2) ? (out + 1) : (float*)nullptr);
        updp_kernel<<<256, 256, 0, stream>>>(attn, vvb, updp);
        gru_gates_kernel<<<48, 256, 0, stream>>>(updp, asum, slots, W_ih, W_hh, b_ih, b_hh, gi, gh);
        gru_mlp_kernel<<<16, 256, 0, stream>>>(gi, gh, slots, g_ff, b_ff, Wm1, bm1, Wm2, bm2);
    }

    recon_kernel<<<1, 320, 0, stream>>>(slots, Wr1, br1, g1, be1, Wr2, br2, g2, be2, Wr3, br3, spts);
    fps_kernel<<<4, 64, 0, stream>>>(spts, fidx, lacc, mnbuf);
    chamfer_sum2_kernel<<<64, 256, 0, stream>>>(spts, fidx, xyz, lacc);
    chamfer_min1_kernel<<<64, 128, 0, stream>>>(spts, fidx, xyz, mnbuf);
    chamfer_final_kernel<<<1, 512, 0, stream>>>(mnbuf, lacc, out);
}